// Round 8
// baseline (782.684 us; speedup 1.0000x reference)
//
#include <hip/hip_runtime.h>
#include <hip/hip_bf16.h>
#include <math.h>

#define S 1024
#define NLAYER 4

typedef __bf16 bf16x8 __attribute__((ext_vector_type(8)));
typedef float floatx4 __attribute__((ext_vector_type(4)));

__device__ __forceinline__ float wave_sum(float v) {
  #pragma unroll
  for (int off = 32; off > 0; off >>= 1) v += __shfl_xor(v, off, 64);
  return v;
}

// async global->LDS 16B per lane: LDS dest = base + lane*16 (wave-uniform base).
__device__ __forceinline__ void async16(const void* g, void* l) {
  __builtin_amdgcn_global_load_lds(
      (const __attribute__((address_space(1))) unsigned int*)g,
      (__attribute__((address_space(3))) unsigned int*)l, 16, 0, 0);
}

// ---------------- embed: h = [x, tf] @ Wp + bp (fp32) + fused LN(layer0) ----------------
__global__ __launch_bounds__(256) void embed_kernel(
    const float* __restrict__ x, const float* __restrict__ tf,
    const float* __restrict__ Wp, const float* __restrict__ bp,
    const float* __restrict__ g, const float* __restrict__ b,
    float* __restrict__ h, __bf16* __restrict__ hn) {
  int row = blockIdx.x;
  int n = threadIdx.x;
  float xv = x[row];
  const float* t4 = tf + (size_t)row * 4;
  float acc = bp[n] + xv * Wp[n];
  acc += t4[0] * Wp[256 + n];
  acc += t4[1] * Wp[512 + n];
  acc += t4[2] * Wp[768 + n];
  acc += t4[3] * Wp[1024 + n];
  h[(size_t)row * 256 + n] = acc;
  __shared__ float red[4];
  int wid = n >> 6, lane = n & 63;
  float s = wave_sum(acc);
  if (lane == 0) red[wid] = s;
  __syncthreads();
  float mu = (red[0] + red[1] + red[2] + red[3]) * (1.f / 256.f);
  __syncthreads();
  float d = acc - mu;
  float s2 = wave_sum(d * d);
  if (lane == 0) red[wid] = s2;
  __syncthreads();
  float var = (red[0] + red[1] + red[2] + red[3]) * (1.f / 256.f);
  float rs = rsqrtf(var + 1e-5f);
  hn[(size_t)row * 256 + n] = (__bf16)(d * rs * g[n] + b[n]);
}

// ---------------- weight transpose+cast: W[K][N] f32 -> WT[N][K] bf16 ----------------
__global__ __launch_bounds__(256) void wtrans_kernel(
    const float* __restrict__ Wup, const float* __restrict__ Wq,
    const float* __restrict__ Wk, const float* __restrict__ Wv,
    const float* __restrict__ Wdown,
    __bf16* __restrict__ WupT, __bf16* __restrict__ WqkT,
    __bf16* __restrict__ WvT, __bf16* __restrict__ WdownT) {
  __shared__ float T[32][33];
  int bid = blockIdx.x;
  int layer = bid / 1152, rr = bid % 1152;
  const float* src; __bf16* dst; int K, N, tile;
  if (rr < 256)       { src = Wup   + layer * 262144; dst = WupT  + layer * 262144;          K = 256; N = 1024; tile = rr; }
  else if (rr < 512)  { src = Wq    + layer * 262144; dst = WqkT  + layer * 524288;          K = 512; N = 512;  tile = rr - 256; }
  else if (rr < 768)  { src = Wk    + layer * 262144; dst = WqkT  + layer * 524288 + 262144; K = 512; N = 512;  tile = rr - 512; }
  else if (rr < 1024) { src = Wv    + layer * 262144; dst = WvT   + layer * 262144;          K = 512; N = 512;  tile = rr - 768; }
  else                { src = Wdown + layer * 131072; dst = WdownT + layer * 131072;         K = 512; N = 256;  tile = rr - 1024; }
  int ntn = N >> 5;
  int tk = tile / ntn, tn = tile % ntn;
  int tid = threadIdx.x;
  int r = tid >> 3, c4 = (tid & 7) * 4;
  float4 v = *(const float4*)(src + (size_t)(tk * 32 + r) * N + tn * 32 + c4);
  T[c4 + 0][r] = v.x; T[c4 + 1][r] = v.y; T[c4 + 2][r] = v.z; T[c4 + 3][r] = v.w;
  __syncthreads();
  __bf16 o[4];
  #pragma unroll
  for (int j = 0; j < 4; ++j) o[j] = (__bf16)T[r][c4 + j];
  *(uint2*)(dst + (size_t)(tn * 32 + r) * K + tk * 32 + c4) = *(uint2*)o;
}

// ---------------- Wg precompute (coalesced wave-per-row) ----------------
__global__ __launch_bounds__(256) void wgprep_kernel(
    const float* __restrict__ Wq, const float* __restrict__ Wk,
    const float* __restrict__ Wv, const float* __restrict__ Wif,
    float* __restrict__ wg) {
  int bid = blockIdx.x;
  int l = bid >> 8;
  int rem = bid & 255;
  int sel = rem >> 7;
  int kg = rem & 127;
  int tid = threadIdx.x;
  int wv = tid >> 6, lane = tid & 63;
  int k = kg * 4 + wv;
  const float* wif = Wif + (size_t)l * 1536 * 8;
  float part[8] = {0, 0, 0, 0, 0, 0, 0, 0};
  if (sel == 0) {
    const float* qr = Wq + (size_t)l * 262144 + (size_t)k * 512;
    const float* kr = Wk + (size_t)l * 262144 + (size_t)k * 512;
    #pragma unroll
    for (int i = 0; i < 8; ++i) {
      int n = lane + i * 64;
      float qv = qr[n], kv = kr[n];
      const float* wq8 = wif + (size_t)n * 8;
      const float* wk8 = wif + (size_t)(512 + n) * 8;
      #pragma unroll
      for (int j = 0; j < 8; ++j) part[j] += qv * wq8[j] + kv * wk8[j];
    }
  } else {
    const float* vr = Wv + (size_t)l * 262144 + (size_t)k * 512;
    #pragma unroll
    for (int i = 0; i < 8; ++i) {
      int n = lane + i * 64;
      float vv = vr[n];
      const float* wv8 = wif + (size_t)(1024 + n) * 8;
      #pragma unroll
      for (int j = 0; j < 8; ++j) part[j] += vv * wv8[j];
    }
  }
  #pragma unroll
  for (int j = 0; j < 8; ++j) part[j] = wave_sum(part[j]);
  if (lane < 8) wg[(size_t)l * 8192 + sel * 4096 + (size_t)k * 8 + lane] = part[lane];
}

// ---------------- LayerNorm over 256, fp32 in -> bf16 out ----------------
__global__ __launch_bounds__(256) void ln256_kernel(
    const float* __restrict__ x, const float* __restrict__ g,
    const float* __restrict__ b, __bf16* __restrict__ y) {
  int row = blockIdx.x, tid = threadIdx.x;
  __shared__ float red[4];
  float v = x[(size_t)row * 256 + tid];
  float s = wave_sum(v);
  int wid = tid >> 6, lane = tid & 63;
  if (lane == 0) red[wid] = s;
  __syncthreads();
  float mu = (red[0] + red[1] + red[2] + red[3]) * (1.f / 256.f);
  __syncthreads();
  float d = v - mu;
  float s2 = wave_sum(d * d);
  if (lane == 0) red[wid] = s2;
  __syncthreads();
  float var = (red[0] + red[1] + red[2] + red[3]) * (1.f / 256.f);
  float rs = rsqrtf(var + 1e-5f);
  y[(size_t)row * 256 + tid] = (__bf16)(d * rs * g[tid] + b[tid]);
}

// ---------------- bf16 MFMA GEMM, m97-style global_load_lds staging ----------------
// 128x128 tile, BK=32, 256 threads (4 waves 2x2). LDS unpadded [row][32] (DMA layout).
// MODE 0: f32 out (+ACC adds prev), MODE 1: bf16 row-major, MODE 2: bf16 scattered into vT.
template <int MODE, int ACC>
__global__ __launch_bounds__(256) void hgemm(
    const __bf16* __restrict__ A, int lda,
    const __bf16* __restrict__ BT, int Kdim,
    const float* __restrict__ bias,
    void* __restrict__ Cout, int ldc) {
  __shared__ __bf16 As[128][32];
  __shared__ __bf16 Bs[128][32];
  int tid = threadIdx.x;
  int bn = blockIdx.x * 128, bm = blockIdx.y * 128;
  int wid = tid >> 6, lane = tid & 63;
  int wr = wid >> 1, wc = wid & 1;
  int lg = lane >> 4, li = lane & 15;
  floatx4 acc[4][4];
  #pragma unroll
  for (int i = 0; i < 4; ++i)
    #pragma unroll
    for (int j = 0; j < 4; ++j) acc[i][j] = (floatx4)(0.f);

  // DMA staging: wave wid covers rows [wid*32, wid*32+32) of both tiles.
  // One global_load_lds(16B) per wave writes 16 rows (lane i -> row i/4, seg i%4).
  int srow = wid * 32 + (lane >> 2);
  int sseg = (lane & 3) * 8;
  const __bf16* agp0 = A + (size_t)(bm + srow) * lda + sseg;
  const __bf16* agp1 = A + (size_t)(bm + srow + 16) * lda + sseg;
  const __bf16* bgp0 = BT + (size_t)(bn + srow) * Kdim + sseg;
  const __bf16* bgp1 = BT + (size_t)(bn + srow + 16) * Kdim + sseg;
  __bf16* al0 = &As[wid * 32][0];
  __bf16* al1 = &As[wid * 32 + 16][0];
  __bf16* bl0 = &Bs[wid * 32][0];
  __bf16* bl1 = &Bs[wid * 32 + 16][0];

  for (int k0 = 0; k0 < Kdim; k0 += 32) {
    __syncthreads();
    async16(agp0 + k0, al0);
    async16(agp1 + k0, al1);
    async16(bgp0 + k0, bl0);
    async16(bgp1 + k0, bl1);
    __syncthreads();  // drains vmcnt (global_load_lds) before reads
    bf16x8 af[4], bfr[4];
    #pragma unroll
    for (int mi = 0; mi < 4; ++mi)
      af[mi] = *(const bf16x8*)&As[wr * 64 + mi * 16 + li][lg * 8];
    #pragma unroll
    for (int ni = 0; ni < 4; ++ni)
      bfr[ni] = *(const bf16x8*)&Bs[wc * 64 + ni * 16 + li][lg * 8];
    #pragma unroll
    for (int mi = 0; mi < 4; ++mi)
      #pragma unroll
      for (int ni = 0; ni < 4; ++ni)
        acc[mi][ni] = __builtin_amdgcn_mfma_f32_16x16x32_bf16(af[mi], bfr[ni], acc[mi][ni], 0, 0, 0);
  }
  #pragma unroll
  for (int mi = 0; mi < 4; ++mi) {
    int row = bm + wr * 64 + mi * 16 + lg * 4;
    #pragma unroll
    for (int ni = 0; ni < 4; ++ni) {
      int col = bn + wc * 64 + ni * 16 + li;
      if (MODE == 2) {
        __bf16 o4[4];
        #pragma unroll
        for (int r = 0; r < 4; ++r) o4[r] = (__bf16)acc[mi][ni][r];
        __bf16* vt = (__bf16*)Cout;
        size_t off = ((size_t)((row >> 10) * 4 + (col >> 7)) * 128 + (col & 127)) * 1024 + (row & 1023);
        *(uint2*)(vt + off) = *(uint2*)o4;
      } else {
        float bz = bias ? bias[col] : 0.f;
        if (MODE == 1) {
          __bf16* C = (__bf16*)Cout;
          #pragma unroll
          for (int r = 0; r < 4; ++r)
            C[(size_t)(row + r) * ldc + col] = (__bf16)(acc[mi][ni][r] + bz);
        } else {
          float* C = (float*)Cout;
          #pragma unroll
          for (int r = 0; r < 4; ++r) {
            float v = acc[mi][ni][r] + bz;
            if (ACC) v += C[(size_t)(row + r) * ldc + col];
            C[(size_t)(row + r) * ldc + col] = v;
          }
        }
      }
    }
  }
}

// ---------------- causal conv (K=4) + SiLU + fused gate projection ----------------
__global__ __launch_bounds__(256) void conv_silu_kernel(
    const __bf16* __restrict__ up, const float* __restrict__ cw,
    const float* __restrict__ cb, const float* __restrict__ wg,
    const float* __restrict__ bif, __bf16* __restrict__ xc,
    float* __restrict__ gates) {
  int tid = threadIdx.x;
  int wv = tid >> 6, lane = tid & 63;
  int row = blockIdx.x * 4 + wv;
  int c8 = lane * 8;
  int t = row & (S - 1);
  float acc[8];
  *(float4*)&acc[0] = *(const float4*)(cb + c8);
  *(float4*)&acc[4] = *(const float4*)(cb + c8 + 4);
  float xm[8];
  #pragma unroll
  for (int j = 0; j < 4; ++j) {
    int tt = t - 3 + j;
    if (tt >= 0) {
      bf16x8 xv = *(const bf16x8*)(up + (size_t)(row - 3 + j) * 1024 + c8);
      float4 w0 = *(const float4*)(cw + j * 512 + c8);
      float4 w1 = *(const float4*)(cw + j * 512 + c8 + 4);
      acc[0] += w0.x * (float)xv[0]; acc[1] += w0.y * (float)xv[1];
      acc[2] += w0.z * (float)xv[2]; acc[3] += w0.w * (float)xv[3];
      acc[4] += w1.x * (float)xv[4]; acc[5] += w1.y * (float)xv[5];
      acc[6] += w1.z * (float)xv[6]; acc[7] += w1.w * (float)xv[7];
      if (j == 3) {
        #pragma unroll
        for (int m = 0; m < 8; ++m) xm[m] = (float)xv[m];
      }
    }
  }
  bf16x8 o;
  float xcs[8];
  #pragma unroll
  for (int m = 0; m < 8; ++m) {
    float sg = 1.f / (1.f + __expf(-acc[m]));
    xcs[m] = acc[m] * sg;
    o[m] = (__bf16)xcs[m];
  }
  *(bf16x8*)(xc + (size_t)row * 512 + c8) = o;
  const float* w1 = wg + (size_t)c8 * 8;
  const float* w2 = wg + 4096 + (size_t)c8 * 8;
  float part[8] = {0, 0, 0, 0, 0, 0, 0, 0};
  #pragma unroll
  for (int m = 0; m < 8; ++m) {
    const float* a = w1 + m * 8;
    const float* b = w2 + m * 8;
    #pragma unroll
    for (int j = 0; j < 8; ++j) part[j] += xcs[m] * a[j] + xm[m] * b[j];
  }
  #pragma unroll
  for (int j = 0; j < 8; ++j) part[j] = wave_sum(part[j]);
  if (lane < 8) gates[(size_t)row * 8 + lane] = part[lane] + bif[lane];
}

// ---------------- per-(b,h) gate scan: one wave ----------------
__global__ __launch_bounds__(64) void scan_kernel(
    const float* __restrict__ gates, float* __restrict__ gout,
    float* __restrict__ Mout, float* __restrict__ NFout) {
  int bh = blockIdx.x;
  int bb = bh >> 2, hh = bh & 3;
  int lane = threadIdx.x;
  float ip[16], pf[16];
  #pragma unroll
  for (int i = 0; i < 16; ++i) {
    int t = lane * 16 + i;
    const float* grow = gates + ((size_t)(bb * S + t)) * 8;
    ip[i] = grow[hh];
    float fp = grow[4 + hh];
    float lf = fminf(fp, 0.f) - log1pf(__expf(-fabsf(fp)));
    pf[i] = (i == 0) ? lf : pf[i - 1] + lf;
  }
  float T = pf[15];
  float inc = T;
  #pragma unroll
  for (int off = 1; off < 64; off <<= 1) {
    float v = __shfl_up(inc, off, 64);
    if (lane >= off) inc += v;
  }
  float excl = inc - T;
  float F[16], g[16], pm[16];
  #pragma unroll
  for (int i = 0; i < 16; ++i) {
    F[i] = excl + pf[i];
    g[i] = ip[i] - F[i];
    pm[i] = (i == 0) ? g[0] : fmaxf(pm[i - 1], g[i]);
  }
  float Mx = pm[15];
  float incm = Mx;
  #pragma unroll
  for (int off = 1; off < 64; off <<= 1) {
    float v = __shfl_up(incm, off, 64);
    if (lane >= off) incm = fmaxf(incm, v);
  }
  float em = __shfl_up(incm, 1, 64);
  if (lane == 0) em = -3.4e38f;
  #pragma unroll
  for (int i = 0; i < 16; ++i) {
    int t = lane * 16 + i;
    size_t o = (size_t)bh * S + t;
    float M = fmaxf(em, pm[i]);
    gout[o] = g[i];
    Mout[o] = M;
    NFout[o] = __expf(-F[i] - M);
  }
}

// ---------------- MFMA mLSTM attention + fused GroupNorm/skip/silu-gate ----------------
__global__ __launch_bounds__(256, 1) void attn_kernel(
    const __bf16* __restrict__ qk, const __bf16* __restrict__ vT,
    const float* __restrict__ gbuf, const float* __restrict__ Mbuf,
    const float* __restrict__ NFbuf,
    const float* __restrict__ gn_g, const float* __restrict__ gn_b,
    const float* __restrict__ skip,
    const __bf16* __restrict__ xc, const __bf16* __restrict__ up,
    __bf16* __restrict__ hd) {
  __shared__ __bf16 Ks[64][136];
  __shared__ __bf16 Vs[128][72];
  __shared__ __bf16 plds[4][2][16][72];
  __shared__ float gls[64];
  __shared__ float glds[128], blds[128], slds[128];
  int px = blockIdx.x, bh = blockIdx.y;
  int tqA = px, tqB = 15 - px;
  int bb = bh >> 2, hh = bh & 3;
  int tid = threadIdx.x;
  int wv = tid >> 6, lane = tid & 63;
  int lg = lane >> 4, li = lane & 15;
  int tbA = tqA * 64 + wv * 16;
  int tbB = tqB * 64 + wv * 16;
  const float scale = 0.08838834764831845f;

  if (tid < 128) {
    glds[tid] = gn_g[hh * 128 + tid];
    blds[tid] = gn_b[hh * 128 + tid];
    slds[tid] = skip[hh * 128 + tid];
  }

  bf16x8 aqA[4], aqB[4];
  {
    const __bf16* qpA = qk + ((size_t)(bb * S + tbA + li)) * 1024 + hh * 128 + lg * 8;
    const __bf16* qpB = qk + ((size_t)(bb * S + tbB + li)) * 1024 + hh * 128 + lg * 8;
    #pragma unroll
    for (int cd = 0; cd < 4; ++cd) {
      aqA[cd] = *(const bf16x8*)(qpA + cd * 32);
      aqB[cd] = *(const bf16x8*)(qpB + cd * 32);
    }
  }
  float mlA[4], nfA[4], mlB[4], nfB[4];
  #pragma unroll
  for (int r = 0; r < 4; ++r) {
    mlA[r] = Mbuf[(size_t)bh * S + tbA + lg * 4 + r];
    nfA[r] = NFbuf[(size_t)bh * S + tbA + lg * 4 + r];
    mlB[r] = Mbuf[(size_t)bh * S + tbB + lg * 4 + r];
    nfB[r] = NFbuf[(size_t)bh * S + tbB + lg * 4 + r];
  }

  floatx4 oA[8], oB[8];
  #pragma unroll
  for (int df = 0; df < 8; ++df) { oA[df] = (floatx4)(0.f); oB[df] = (floatx4)(0.f); }
  float rsA[4] = {0, 0, 0, 0}, rsB[4] = {0, 0, 0, 0};

  int krow = tid >> 3, kcol = tid & 7;
  bf16x8 kreg[4], vreg[4];
  float greg = 0.f;
  auto preload = [&](int st) {
    int s0 = st * 64;
    const __bf16* kp = qk + ((size_t)(bb * S + s0 + krow)) * 1024 + 512 + hh * 128;
    kreg[0] = *(const bf16x8*)(kp + kcol * 8);
    kreg[1] = *(const bf16x8*)(kp + (size_t)32 * 1024 + kcol * 8);
    kreg[2] = *(const bf16x8*)(kp + 64 + kcol * 8);
    kreg[3] = *(const bf16x8*)(kp + (size_t)32 * 1024 + 64 + kcol * 8);
    #pragma unroll
    for (int i = 0; i < 4; ++i)
      vreg[i] = *(const bf16x8*)(vT + ((size_t)(bh * 128 + krow + i * 32)) * 1024 + s0 + kcol * 8);
    if (tid < 64) greg = gbuf[(size_t)bh * S + s0 + tid];
  };
  preload(0);

  for (int st = 0; st <= tqB; ++st) {
    __syncthreads();
    *(bf16x8*)&Ks[krow][kcol * 8] = kreg[0];
    *(bf16x8*)&Ks[krow + 32][kcol * 8] = kreg[1];
    *(bf16x8*)&Ks[krow][64 + kcol * 8] = kreg[2];
    *(bf16x8*)&Ks[krow + 32][64 + kcol * 8] = kreg[3];
    #pragma unroll
    for (int i = 0; i < 4; ++i) *(bf16x8*)&Vs[krow + i * 32][kcol * 8] = vreg[i];
    if (tid < 64) gls[tid] = greg;
    __syncthreads();
    if (st < tqB) preload(st + 1);

    int s0 = st * 64;
    bool actA = (st <= tqA);
    #pragma unroll
    for (int ns = 0; ns < 4; ++ns) {
      bf16x8 bk0 = *(const bf16x8*)&Ks[ns * 16 + li][lg * 8];
      bf16x8 bk1 = *(const bf16x8*)&Ks[ns * 16 + li][32 + lg * 8];
      bf16x8 bk2 = *(const bf16x8*)&Ks[ns * 16 + li][64 + lg * 8];
      bf16x8 bk3 = *(const bf16x8*)&Ks[ns * 16 + li][96 + lg * 8];
      int s = s0 + ns * 16 + li;
      float gv = gls[ns * 16 + li];
      if (actA) {
        floatx4 pa = (floatx4)(0.f);
        pa = __builtin_amdgcn_mfma_f32_16x16x32_bf16(aqA[0], bk0, pa, 0, 0, 0);
        pa = __builtin_amdgcn_mfma_f32_16x16x32_bf16(aqA[1], bk1, pa, 0, 0, 0);
        pa = __builtin_amdgcn_mfma_f32_16x16x32_bf16(aqA[2], bk2, pa, 0, 0, 0);
        pa = __builtin_amdgcn_mfma_f32_16x16x32_bf16(aqA[3], bk3, pa, 0, 0, 0);
        #pragma unroll
        for (int r = 0; r < 4; ++r) {
          int t = tbA + lg * 4 + r;
          float val = pa[r] * scale * __expf(gv - mlA[r]);
          float w = (s <= t) ? val : 0.f;
          rsA[r] += w;
          plds[wv][0][lg * 4 + r][ns * 16 + li] = (__bf16)w;
        }
      }
      {
        floatx4 pb = (floatx4)(0.f);
        pb = __builtin_amdgcn_mfma_f32_16x16x32_bf16(aqB[0], bk0, pb, 0, 0, 0);
        pb = __builtin_amdgcn_mfma_f32_16x16x32_bf16(aqB[1], bk1, pb, 0, 0, 0);
        pb = __builtin_amdgcn_mfma_f32_16x16x32_bf16(aqB[2], bk2, pb, 0, 0, 0);
        pb = __builtin_amdgcn_mfma_f32_16x16x32_bf16(aqB[3], bk3, pb, 0, 0, 0);
        #pragma unroll
        for (int r = 0; r < 4; ++r) {
          int t = tbB + lg * 4 + r;
          float val = pb[r] * scale * __expf(gv - mlB[r]);
          float w = (s <= t) ? val : 0.f;
          rsB[r] += w;
          plds[wv][1][lg * 4 + r][ns * 16 + li] = (__bf16)w;
        }
      }
    }
    bf16x8 apA0, apA1, apB0, apB1;
    if (actA) {
      apA0 = *(const bf16x8*)&plds[wv][0][li][lg * 8];
      apA1 = *(const bf16x8*)&plds[wv][0][li][32 + lg * 8];
    }
    apB0 = *(const bf16x8*)&plds[wv][1][li][lg * 8];
    apB1 = *(const bf16x8*)&plds[wv][1][li][32 + lg * 8];
    #pragma unroll
    for (int df = 0; df < 8; ++df) {
      bf16x8 bv0 = *(const bf16x8*)&Vs[df * 16 + li][lg * 8];
      bf16x8 bv1 = *(const bf16x8*)&Vs[df * 16 + li][32 + lg * 8];
      if (actA) {
        oA[df] = __builtin_amdgcn_mfma_f32_16x16x32_bf16(apA0, bv0, oA[df], 0, 0, 0);
        oA[df] = __builtin_amdgcn_mfma_f32_16x16x32_bf16(apA1, bv1, oA[df], 0, 0, 0);
      }
      oB[df] = __builtin_amdgcn_mfma_f32_16x16x32_bf16(apB0, bv0, oB[df], 0, 0, 0);
      oB[df] = __builtin_amdgcn_mfma_f32_16x16x32_bf16(apB1, bv1, oB[df], 0, 0, 0);
    }
  }
  #pragma unroll
  for (int r = 0; r < 4; ++r) {
    float a = rsA[r], b = rsB[r];
    a += __shfl_xor(a, 1, 64); a += __shfl_xor(a, 2, 64);
    a += __shfl_xor(a, 4, 64); a += __shfl_xor(a, 8, 64);
    b += __shfl_xor(b, 1, 64); b += __shfl_xor(b, 2, 64);
    b += __shfl_xor(b, 4, 64); b += __shfl_xor(b, 8, 64);
    rsA[r] = a; rsB[r] = b;
  }
  #pragma unroll
  for (int tile = 0; tile < 2; ++tile) {
    int tb = tile == 0 ? tbA : tbB;
    #pragma unroll
    for (int r = 0; r < 4; ++r) {
      float rs = tile == 0 ? rsA[r] : rsB[r];
      float nf = tile == 0 ? nfA[r] : nfB[r];
      float inv = 1.f / (fmaxf(fabsf(rs), nf) + 1e-6f);
      float v8[8], s1 = 0.f, s2 = 0.f;
      #pragma unroll
      for (int df = 0; df < 8; ++df) {
        float v = (tile == 0 ? oA[df][r] : oB[df][r]) * inv;
        v8[df] = v;
        s1 += v;
        s2 += v * v;
      }
      s1 += __shfl_xor(s1, 1, 64); s1 += __shfl_xor(s1, 2, 64);
      s1 += __shfl_xor(s1, 4, 64); s1 += __shfl_xor(s1, 8, 64);
      s2 += __shfl_xor(s2, 1, 64); s2 += __shfl_xor(s2, 2, 64);
      s2 += __shfl_xor(s2, 4, 64); s2 += __shfl_xor(s2, 8, 64);
      float mu = s1 * (1.f / 128.f);
      float var = s2 * (1.f / 128.f) - mu * mu;
      float rq = rsqrtf(var + 1e-5f);
      int t = tb + lg * 4 + r;
      const __bf16* xr = xc + ((size_t)(bb * S + t)) * 512 + hh * 128 + li;
      const __bf16* zr = up + ((size_t)(bb * S + t)) * 1024 + 512 + hh * 128 + li;
      __bf16* od = hd + ((size_t)(bb * S + t)) * 512 + hh * 128 + li;
      #pragma unroll
      for (int df = 0; df < 8; ++df) {
        int c = df * 16 + li;
        float ln = (v8[df] - mu) * rq * glds[c] + blds[c];
        float val = ln + slds[c] * (float)xr[df * 16];
        float z = (float)zr[df * 16];
        float sg = 1.f / (1.f + __expf(-z));
        od[df * 16] = (__bf16)(val * (z * sg));
      }
    }
  }
}

// ---------------- final LN + head ----------------
__global__ __launch_bounds__(256) void final_kernel(
    const float* __restrict__ h, const float* __restrict__ g,
    const float* __restrict__ b, const float* __restrict__ Wf,
    const float* __restrict__ bf, float* __restrict__ out) {
  int bb = blockIdx.x, tid = threadIdx.x;
  size_t row = (size_t)(bb * S + S - 1) * 256;
  __shared__ float red[4];
  float v = h[row + tid];
  float s = wave_sum(v);
  int wid = tid >> 6, lane = tid & 63;
  if (lane == 0) red[wid] = s;
  __syncthreads();
  float mu = (red[0] + red[1] + red[2] + red[3]) * (1.f / 256.f);
  __syncthreads();
  float d = v - mu;
  float s2 = wave_sum(d * d);
  if (lane == 0) red[wid] = s2;
  __syncthreads();
  float var = (red[0] + red[1] + red[2] + red[3]) * (1.f / 256.f);
  float rs = rsqrtf(var + 1e-5f);
  float ln = d * rs * g[tid] + b[tid];
  float p = ln * Wf[tid];
  float psum = wave_sum(p);
  __syncthreads();
  if (lane == 0) red[wid] = psum;
  __syncthreads();
  if (tid == 0) out[bb] = red[0] + red[1] + red[2] + red[3] + bf[0];
}

extern "C" void kernel_launch(void* const* d_in, const int* in_sizes, int n_in,
                              void* d_out, int out_size, void* d_ws, size_t ws_size,
                              hipStream_t stream) {
  const float* x      = (const float*)d_in[0];
  const float* tf     = (const float*)d_in[1];
  const float* Wp     = (const float*)d_in[2];
  const float* bp     = (const float*)d_in[3];
  const float* ln_g   = (const float*)d_in[4];
  const float* ln_b   = (const float*)d_in[5];
  const float* Wup    = (const float*)d_in[6];
  const float* bup    = (const float*)d_in[7];
  const float* conv_w = (const float*)d_in[8];
  const float* conv_b = (const float*)d_in[9];
  const float* Wq     = (const float*)d_in[10];
  const float* Wk     = (const float*)d_in[11];
  const float* Wv     = (const float*)d_in[12];
  const float* Wif    = (const float*)d_in[13];
  const float* bif    = (const float*)d_in[14];
  const float* gn_g   = (const float*)d_in[15];
  const float* gn_b   = (const float*)d_in[16];
  const float* skip   = (const float*)d_in[17];
  const float* Wdown  = (const float*)d_in[18];
  const float* bdown  = (const float*)d_in[19];
  const float* lnf_g  = (const float*)d_in[20];
  const float* lnf_b  = (const float*)d_in[21];
  const float* Wf     = (const float*)d_in[22];
  const float* bf     = (const float*)d_in[23];
  float* out = (float*)d_out;

  float* h     = (float*)d_ws;              // 2,097,152 f32
  float* gates = h + 2097152;               // 65,536 f32
  float* gbuf  = gates + 65536;             // 32,768
  float* Mbuf  = gbuf + 32768;              // 32,768
  float* NFbuf = Mbuf + 32768;              // 32,768
  float* wgbuf = NFbuf + 32768;             // 32,768
  __bf16* hn   = (__bf16*)(wgbuf + 32768);  // 2,097,152 bf16
  __bf16* up   = hn + 2097152;              // 8,388,608
  __bf16* xc   = up + 8388608;              // 4,194,304
  __bf16* qk   = xc + 4194304;              // 8,388,608
  __bf16* vT   = qk + 8388608;              // 4,194,304
  __bf16* hd   = vT + 4194304;              // 4,194,304
  __bf16* WupT   = hd + 4194304;            // 1,048,576
  __bf16* WqkT   = WupT + 1048576;          // 2,097,152
  __bf16* WvT    = WqkT + 2097152;          // 1,048,576
  __bf16* WdownT = WvT + 1048576;           // 524,288

  wtrans_kernel<<<4608, 256, 0, stream>>>(Wup, Wq, Wk, Wv, Wdown,
                                          WupT, WqkT, WvT, WdownT);
  wgprep_kernel<<<1024, 256, 0, stream>>>(Wq, Wk, Wv, Wif, wgbuf);
  embed_kernel<<<8192, 256, 0, stream>>>(x, tf, Wp, bp, ln_g, ln_b, h, hn);
  for (int l = 0; l < NLAYER; ++l) {
    if (l > 0)
      ln256_kernel<<<8192, 256, 0, stream>>>(h, ln_g + l * 256, ln_b + l * 256, hn);
    hgemm<1, 0><<<dim3(8, 64), 256, 0, stream>>>(
        hn, 256, WupT + (size_t)l * 262144, 256, bup + l * 1024, up, 1024);
    conv_silu_kernel<<<2048, 256, 0, stream>>>(up, conv_w + l * 2048, conv_b + l * 512,
                                               wgbuf + l * 8192, bif + l * 8, xc, gates);
    scan_kernel<<<32, 64, 0, stream>>>(gates, gbuf, Mbuf, NFbuf);
    hgemm<1, 0><<<dim3(8, 64), 256, 0, stream>>>(
        xc, 512, WqkT + (size_t)l * 524288, 512, nullptr, qk, 1024);
    hgemm<2, 0><<<dim3(4, 64), 256, 0, stream>>>(
        up, 1024, WvT + (size_t)l * 262144, 512, nullptr, vT, 0);
    attn_kernel<<<dim3(8, 32), 256, 0, stream>>>(
        qk, vT, gbuf, Mbuf, NFbuf, gn_g + l * 512, gn_b + l * 512, skip + l * 512,
        xc, up, hd);
    hgemm<0, 1><<<dim3(2, 64), 256, 0, stream>>>(
        hd, 512, WdownT + (size_t)l * 131072, 512, bdown + l * 256, h, 256);
  }
  final_kernel<<<8, 256, 0, stream>>>(h, lnf_g, lnf_b, Wf, bf, out);
}

// Round 9
// 770.837 us; speedup vs baseline: 1.0154x; 1.0154x over previous
//
#include <hip/hip_runtime.h>
#include <hip/hip_bf16.h>
#include <math.h>

#define S 1024
#define NLAYER 4

typedef __bf16 bf16x8 __attribute__((ext_vector_type(8)));
typedef float floatx4 __attribute__((ext_vector_type(4)));

__device__ __forceinline__ float wave_sum(float v) {
  #pragma unroll
  for (int off = 32; off > 0; off >>= 1) v += __shfl_xor(v, off, 64);
  return v;
}

// async global->LDS 16B per lane: LDS dest = base + lane*16 (wave-uniform base).
__device__ __forceinline__ void async16(const void* g, void* l) {
  __builtin_amdgcn_global_load_lds(
      (const __attribute__((address_space(1))) unsigned int*)g,
      (__attribute__((address_space(3))) unsigned int*)l, 16, 0, 0);
}

// ---------------- embed: h = [x, tf] @ Wp + bp (fp32) + fused LN(layer0) ----------------
__global__ __launch_bounds__(256) void embed_kernel(
    const float* __restrict__ x, const float* __restrict__ tf,
    const float* __restrict__ Wp, const float* __restrict__ bp,
    const float* __restrict__ g, const float* __restrict__ b,
    float* __restrict__ h, __bf16* __restrict__ hn) {
  int row = blockIdx.x;
  int n = threadIdx.x;
  float xv = x[row];
  const float* t4 = tf + (size_t)row * 4;
  float acc = bp[n] + xv * Wp[n];
  acc += t4[0] * Wp[256 + n];
  acc += t4[1] * Wp[512 + n];
  acc += t4[2] * Wp[768 + n];
  acc += t4[3] * Wp[1024 + n];
  h[(size_t)row * 256 + n] = acc;
  __shared__ float red[4];
  int wid = n >> 6, lane = n & 63;
  float s = wave_sum(acc);
  if (lane == 0) red[wid] = s;
  __syncthreads();
  float mu = (red[0] + red[1] + red[2] + red[3]) * (1.f / 256.f);
  __syncthreads();
  float d = acc - mu;
  float s2 = wave_sum(d * d);
  if (lane == 0) red[wid] = s2;
  __syncthreads();
  float var = (red[0] + red[1] + red[2] + red[3]) * (1.f / 256.f);
  float rs = rsqrtf(var + 1e-5f);
  hn[(size_t)row * 256 + n] = (__bf16)(d * rs * g[n] + b[n]);
}

// ---------------- weight transpose+cast: W[K][N] f32 -> WT[N][K] bf16 ----------------
__global__ __launch_bounds__(256) void wtrans_kernel(
    const float* __restrict__ Wup, const float* __restrict__ Wq,
    const float* __restrict__ Wk, const float* __restrict__ Wv,
    const float* __restrict__ Wdown,
    __bf16* __restrict__ WupT, __bf16* __restrict__ WqkT,
    __bf16* __restrict__ WvT, __bf16* __restrict__ WdownT) {
  __shared__ float T[32][33];
  int bid = blockIdx.x;
  int layer = bid / 1152, rr = bid % 1152;
  const float* src; __bf16* dst; int K, N, tile;
  if (rr < 256)       { src = Wup   + layer * 262144; dst = WupT  + layer * 262144;          K = 256; N = 1024; tile = rr; }
  else if (rr < 512)  { src = Wq    + layer * 262144; dst = WqkT  + layer * 524288;          K = 512; N = 512;  tile = rr - 256; }
  else if (rr < 768)  { src = Wk    + layer * 262144; dst = WqkT  + layer * 524288 + 262144; K = 512; N = 512;  tile = rr - 512; }
  else if (rr < 1024) { src = Wv    + layer * 262144; dst = WvT   + layer * 262144;          K = 512; N = 512;  tile = rr - 768; }
  else                { src = Wdown + layer * 131072; dst = WdownT + layer * 131072;         K = 512; N = 256;  tile = rr - 1024; }
  int ntn = N >> 5;
  int tk = tile / ntn, tn = tile % ntn;
  int tid = threadIdx.x;
  int r = tid >> 3, c4 = (tid & 7) * 4;
  float4 v = *(const float4*)(src + (size_t)(tk * 32 + r) * N + tn * 32 + c4);
  T[c4 + 0][r] = v.x; T[c4 + 1][r] = v.y; T[c4 + 2][r] = v.z; T[c4 + 3][r] = v.w;
  __syncthreads();
  __bf16 o[4];
  #pragma unroll
  for (int j = 0; j < 4; ++j) o[j] = (__bf16)T[r][c4 + j];
  *(uint2*)(dst + (size_t)(tn * 32 + r) * K + tk * 32 + c4) = *(uint2*)o;
}

// ---------------- Wg precompute (coalesced wave-per-row) ----------------
__global__ __launch_bounds__(256) void wgprep_kernel(
    const float* __restrict__ Wq, const float* __restrict__ Wk,
    const float* __restrict__ Wv, const float* __restrict__ Wif,
    float* __restrict__ wg) {
  int bid = blockIdx.x;
  int l = bid >> 8;
  int rem = bid & 255;
  int sel = rem >> 7;
  int kg = rem & 127;
  int tid = threadIdx.x;
  int wv = tid >> 6, lane = tid & 63;
  int k = kg * 4 + wv;
  const float* wif = Wif + (size_t)l * 1536 * 8;
  float part[8] = {0, 0, 0, 0, 0, 0, 0, 0};
  if (sel == 0) {
    const float* qr = Wq + (size_t)l * 262144 + (size_t)k * 512;
    const float* kr = Wk + (size_t)l * 262144 + (size_t)k * 512;
    #pragma unroll
    for (int i = 0; i < 8; ++i) {
      int n = lane + i * 64;
      float qv = qr[n], kv = kr[n];
      const float* wq8 = wif + (size_t)n * 8;
      const float* wk8 = wif + (size_t)(512 + n) * 8;
      #pragma unroll
      for (int j = 0; j < 8; ++j) part[j] += qv * wq8[j] + kv * wk8[j];
    }
  } else {
    const float* vr = Wv + (size_t)l * 262144 + (size_t)k * 512;
    #pragma unroll
    for (int i = 0; i < 8; ++i) {
      int n = lane + i * 64;
      float vv = vr[n];
      const float* wv8 = wif + (size_t)(1024 + n) * 8;
      #pragma unroll
      for (int j = 0; j < 8; ++j) part[j] += vv * wv8[j];
    }
  }
  #pragma unroll
  for (int j = 0; j < 8; ++j) part[j] = wave_sum(part[j]);
  if (lane < 8) wg[(size_t)l * 8192 + sel * 4096 + (size_t)k * 8 + lane] = part[lane];
}

// ---------------- LayerNorm over 256, fp32 in -> bf16 out ----------------
__global__ __launch_bounds__(256) void ln256_kernel(
    const float* __restrict__ x, const float* __restrict__ g,
    const float* __restrict__ b, __bf16* __restrict__ y) {
  int row = blockIdx.x, tid = threadIdx.x;
  __shared__ float red[4];
  float v = x[(size_t)row * 256 + tid];
  float s = wave_sum(v);
  int wid = tid >> 6, lane = tid & 63;
  if (lane == 0) red[wid] = s;
  __syncthreads();
  float mu = (red[0] + red[1] + red[2] + red[3]) * (1.f / 256.f);
  __syncthreads();
  float d = v - mu;
  float s2 = wave_sum(d * d);
  if (lane == 0) red[wid] = s2;
  __syncthreads();
  float var = (red[0] + red[1] + red[2] + red[3]) * (1.f / 256.f);
  float rs = rsqrtf(var + 1e-5f);
  y[(size_t)row * 256 + tid] = (__bf16)(d * rs * g[tid] + b[tid]);
}

// ---------------- bf16 MFMA GEMM: global_load_lds + double-buffered LDS ----------------
// 128x128 tile, BK=32, 256 threads (4 waves 2x2). One barrier/iter; loads for tile k+1
// issued right after the barrier and drained by the NEXT iteration's barrier -> latency
// overlaps the MFMA section (cp.async-style pipeline).
// MODE 0: f32 out (+ACC adds prev), MODE 1: bf16 row-major, MODE 2: bf16 scattered into vT.
template <int MODE, int ACC>
__global__ __launch_bounds__(256) void hgemm(
    const __bf16* __restrict__ A, int lda,
    const __bf16* __restrict__ BT, int Kdim,
    const float* __restrict__ bias,
    void* __restrict__ Cout, int ldc) {
  __shared__ __bf16 As[2][128][32];
  __shared__ __bf16 Bs[2][128][32];
  int tid = threadIdx.x;
  int bn = blockIdx.x * 128, bm = blockIdx.y * 128;
  int wid = tid >> 6, lane = tid & 63;
  int wr = wid >> 1, wc = wid & 1;
  int lg = lane >> 4, li = lane & 15;
  floatx4 acc[4][4];
  #pragma unroll
  for (int i = 0; i < 4; ++i)
    #pragma unroll
    for (int j = 0; j < 4; ++j) acc[i][j] = (floatx4)(0.f);

  // DMA staging: wave wid covers rows [wid*32, +32) of both tiles; lane i -> row i/4, seg i%4.
  int srow = wid * 32 + (lane >> 2);
  int sseg = (lane & 3) * 8;
  const __bf16* agp0 = A + (size_t)(bm + srow) * lda + sseg;
  const __bf16* agp1 = A + (size_t)(bm + srow + 16) * lda + sseg;
  const __bf16* bgp0 = BT + (size_t)(bn + srow) * Kdim + sseg;
  const __bf16* bgp1 = BT + (size_t)(bn + srow + 16) * Kdim + sseg;

  auto issue = [&](int k0, int buf) {
    async16(agp0 + k0, &As[buf][wid * 32][0]);
    async16(agp1 + k0, &As[buf][wid * 32 + 16][0]);
    async16(bgp0 + k0, &Bs[buf][wid * 32][0]);
    async16(bgp1 + k0, &Bs[buf][wid * 32 + 16][0]);
  };
  issue(0, 0);
  int cur = 0;
  for (int k0 = 0; k0 < Kdim; k0 += 32) {
    __syncthreads();  // drains the async loads targeting buffer `cur`
    if (k0 + 32 < Kdim) issue(k0 + 32, cur ^ 1);
    bf16x8 af[4], bfr[4];
    #pragma unroll
    for (int mi = 0; mi < 4; ++mi)
      af[mi] = *(const bf16x8*)&As[cur][wr * 64 + mi * 16 + li][lg * 8];
    #pragma unroll
    for (int ni = 0; ni < 4; ++ni)
      bfr[ni] = *(const bf16x8*)&Bs[cur][wc * 64 + ni * 16 + li][lg * 8];
    #pragma unroll
    for (int mi = 0; mi < 4; ++mi)
      #pragma unroll
      for (int ni = 0; ni < 4; ++ni)
        acc[mi][ni] = __builtin_amdgcn_mfma_f32_16x16x32_bf16(af[mi], bfr[ni], acc[mi][ni], 0, 0, 0);
    cur ^= 1;
  }
  #pragma unroll
  for (int mi = 0; mi < 4; ++mi) {
    int row = bm + wr * 64 + mi * 16 + lg * 4;
    #pragma unroll
    for (int ni = 0; ni < 4; ++ni) {
      int col = bn + wc * 64 + ni * 16 + li;
      if (MODE == 2) {
        __bf16 o4[4];
        #pragma unroll
        for (int r = 0; r < 4; ++r) o4[r] = (__bf16)acc[mi][ni][r];
        __bf16* vt = (__bf16*)Cout;
        size_t off = ((size_t)((row >> 10) * 4 + (col >> 7)) * 128 + (col & 127)) * 1024 + (row & 1023);
        *(uint2*)(vt + off) = *(uint2*)o4;
      } else {
        float bz = bias ? bias[col] : 0.f;
        if (MODE == 1) {
          __bf16* C = (__bf16*)Cout;
          #pragma unroll
          for (int r = 0; r < 4; ++r)
            C[(size_t)(row + r) * ldc + col] = (__bf16)(acc[mi][ni][r] + bz);
        } else {
          float* C = (float*)Cout;
          #pragma unroll
          for (int r = 0; r < 4; ++r) {
            float v = acc[mi][ni][r] + bz;
            if (ACC) v += C[(size_t)(row + r) * ldc + col];
            C[(size_t)(row + r) * ldc + col] = v;
          }
        }
      }
    }
  }
}

// ---------------- causal conv (K=4) + SiLU + fused gate projection ----------------
__global__ __launch_bounds__(256) void conv_silu_kernel(
    const __bf16* __restrict__ up, const float* __restrict__ cw,
    const float* __restrict__ cb, const float* __restrict__ wg,
    const float* __restrict__ bif, __bf16* __restrict__ xc,
    float* __restrict__ gates) {
  int tid = threadIdx.x;
  int wv = tid >> 6, lane = tid & 63;
  int row = blockIdx.x * 4 + wv;
  int c8 = lane * 8;
  int t = row & (S - 1);
  float acc[8];
  *(float4*)&acc[0] = *(const float4*)(cb + c8);
  *(float4*)&acc[4] = *(const float4*)(cb + c8 + 4);
  float xm[8];
  #pragma unroll
  for (int j = 0; j < 4; ++j) {
    int tt = t - 3 + j;
    if (tt >= 0) {
      bf16x8 xv = *(const bf16x8*)(up + (size_t)(row - 3 + j) * 1024 + c8);
      float4 w0 = *(const float4*)(cw + j * 512 + c8);
      float4 w1 = *(const float4*)(cw + j * 512 + c8 + 4);
      acc[0] += w0.x * (float)xv[0]; acc[1] += w0.y * (float)xv[1];
      acc[2] += w0.z * (float)xv[2]; acc[3] += w0.w * (float)xv[3];
      acc[4] += w1.x * (float)xv[4]; acc[5] += w1.y * (float)xv[5];
      acc[6] += w1.z * (float)xv[6]; acc[7] += w1.w * (float)xv[7];
      if (j == 3) {
        #pragma unroll
        for (int m = 0; m < 8; ++m) xm[m] = (float)xv[m];
      }
    }
  }
  bf16x8 o;
  float xcs[8];
  #pragma unroll
  for (int m = 0; m < 8; ++m) {
    float sg = 1.f / (1.f + __expf(-acc[m]));
    xcs[m] = acc[m] * sg;
    o[m] = (__bf16)xcs[m];
  }
  *(bf16x8*)(xc + (size_t)row * 512 + c8) = o;
  const float* w1 = wg + (size_t)c8 * 8;
  const float* w2 = wg + 4096 + (size_t)c8 * 8;
  float part[8] = {0, 0, 0, 0, 0, 0, 0, 0};
  #pragma unroll
  for (int m = 0; m < 8; ++m) {
    const float* a = w1 + m * 8;
    const float* b = w2 + m * 8;
    #pragma unroll
    for (int j = 0; j < 8; ++j) part[j] += xcs[m] * a[j] + xm[m] * b[j];
  }
  #pragma unroll
  for (int j = 0; j < 8; ++j) part[j] = wave_sum(part[j]);
  if (lane < 8) gates[(size_t)row * 8 + lane] = part[lane] + bif[lane];
}

// ---------------- per-(b,h) gate scan: one wave ----------------
__global__ __launch_bounds__(64) void scan_kernel(
    const float* __restrict__ gates, float* __restrict__ gout,
    float* __restrict__ Mout, float* __restrict__ NFout) {
  int bh = blockIdx.x;
  int bb = bh >> 2, hh = bh & 3;
  int lane = threadIdx.x;
  float ip[16], pf[16];
  #pragma unroll
  for (int i = 0; i < 16; ++i) {
    int t = lane * 16 + i;
    const float* grow = gates + ((size_t)(bb * S + t)) * 8;
    ip[i] = grow[hh];
    float fp = grow[4 + hh];
    float lf = fminf(fp, 0.f) - log1pf(__expf(-fabsf(fp)));
    pf[i] = (i == 0) ? lf : pf[i - 1] + lf;
  }
  float T = pf[15];
  float inc = T;
  #pragma unroll
  for (int off = 1; off < 64; off <<= 1) {
    float v = __shfl_up(inc, off, 64);
    if (lane >= off) inc += v;
  }
  float excl = inc - T;
  float F[16], g[16], pm[16];
  #pragma unroll
  for (int i = 0; i < 16; ++i) {
    F[i] = excl + pf[i];
    g[i] = ip[i] - F[i];
    pm[i] = (i == 0) ? g[0] : fmaxf(pm[i - 1], g[i]);
  }
  float Mx = pm[15];
  float incm = Mx;
  #pragma unroll
  for (int off = 1; off < 64; off <<= 1) {
    float v = __shfl_up(incm, off, 64);
    if (lane >= off) incm = fmaxf(incm, v);
  }
  float em = __shfl_up(incm, 1, 64);
  if (lane == 0) em = -3.4e38f;
  #pragma unroll
  for (int i = 0; i < 16; ++i) {
    int t = lane * 16 + i;
    size_t o = (size_t)bh * S + t;
    float M = fmaxf(em, pm[i]);
    gout[o] = g[i];
    Mout[o] = M;
    NFout[o] = __expf(-F[i] - M);
  }
}

// ---------------- MFMA mLSTM attention + fused GroupNorm/skip/silu-gate ----------------
__global__ __launch_bounds__(256, 1) void attn_kernel(
    const __bf16* __restrict__ qk, const __bf16* __restrict__ vT,
    const float* __restrict__ gbuf, const float* __restrict__ Mbuf,
    const float* __restrict__ NFbuf,
    const float* __restrict__ gn_g, const float* __restrict__ gn_b,
    const float* __restrict__ skip,
    const __bf16* __restrict__ xc, const __bf16* __restrict__ up,
    __bf16* __restrict__ hd) {
  __shared__ __bf16 Ks[64][136];
  __shared__ __bf16 Vs[128][72];
  __shared__ __bf16 plds[4][2][16][72];
  __shared__ float gls[64];
  __shared__ float glds[128], blds[128], slds[128];
  int px = blockIdx.x, bh = blockIdx.y;
  int tqA = px, tqB = 15 - px;
  int bb = bh >> 2, hh = bh & 3;
  int tid = threadIdx.x;
  int wv = tid >> 6, lane = tid & 63;
  int lg = lane >> 4, li = lane & 15;
  int tbA = tqA * 64 + wv * 16;
  int tbB = tqB * 64 + wv * 16;
  const float scale = 0.08838834764831845f;

  if (tid < 128) {
    glds[tid] = gn_g[hh * 128 + tid];
    blds[tid] = gn_b[hh * 128 + tid];
    slds[tid] = skip[hh * 128 + tid];
  }

  bf16x8 aqA[4], aqB[4];
  {
    const __bf16* qpA = qk + ((size_t)(bb * S + tbA + li)) * 1024 + hh * 128 + lg * 8;
    const __bf16* qpB = qk + ((size_t)(bb * S + tbB + li)) * 1024 + hh * 128 + lg * 8;
    #pragma unroll
    for (int cd = 0; cd < 4; ++cd) {
      aqA[cd] = *(const bf16x8*)(qpA + cd * 32);
      aqB[cd] = *(const bf16x8*)(qpB + cd * 32);
    }
  }
  float mlA[4], nfA[4], mlB[4], nfB[4];
  #pragma unroll
  for (int r = 0; r < 4; ++r) {
    mlA[r] = Mbuf[(size_t)bh * S + tbA + lg * 4 + r];
    nfA[r] = NFbuf[(size_t)bh * S + tbA + lg * 4 + r];
    mlB[r] = Mbuf[(size_t)bh * S + tbB + lg * 4 + r];
    nfB[r] = NFbuf[(size_t)bh * S + tbB + lg * 4 + r];
  }

  floatx4 oA[8], oB[8];
  #pragma unroll
  for (int df = 0; df < 8; ++df) { oA[df] = (floatx4)(0.f); oB[df] = (floatx4)(0.f); }
  float rsA[4] = {0, 0, 0, 0}, rsB[4] = {0, 0, 0, 0};

  int krow = tid >> 3, kcol = tid & 7;
  bf16x8 kreg[4], vreg[4];
  float greg = 0.f;
  auto preload = [&](int st) {
    int s0 = st * 64;
    const __bf16* kp = qk + ((size_t)(bb * S + s0 + krow)) * 1024 + 512 + hh * 128;
    kreg[0] = *(const bf16x8*)(kp + kcol * 8);
    kreg[1] = *(const bf16x8*)(kp + (size_t)32 * 1024 + kcol * 8);
    kreg[2] = *(const bf16x8*)(kp + 64 + kcol * 8);
    kreg[3] = *(const bf16x8*)(kp + (size_t)32 * 1024 + 64 + kcol * 8);
    #pragma unroll
    for (int i = 0; i < 4; ++i)
      vreg[i] = *(const bf16x8*)(vT + ((size_t)(bh * 128 + krow + i * 32)) * 1024 + s0 + kcol * 8);
    if (tid < 64) greg = gbuf[(size_t)bh * S + s0 + tid];
  };
  preload(0);

  for (int st = 0; st <= tqB; ++st) {
    __syncthreads();
    *(bf16x8*)&Ks[krow][kcol * 8] = kreg[0];
    *(bf16x8*)&Ks[krow + 32][kcol * 8] = kreg[1];
    *(bf16x8*)&Ks[krow][64 + kcol * 8] = kreg[2];
    *(bf16x8*)&Ks[krow + 32][64 + kcol * 8] = kreg[3];
    #pragma unroll
    for (int i = 0; i < 4; ++i) *(bf16x8*)&Vs[krow + i * 32][kcol * 8] = vreg[i];
    if (tid < 64) gls[tid] = greg;
    __syncthreads();
    if (st < tqB) preload(st + 1);

    int s0 = st * 64;
    bool actA = (st <= tqA);
    #pragma unroll
    for (int ns = 0; ns < 4; ++ns) {
      bf16x8 bk0 = *(const bf16x8*)&Ks[ns * 16 + li][lg * 8];
      bf16x8 bk1 = *(const bf16x8*)&Ks[ns * 16 + li][32 + lg * 8];
      bf16x8 bk2 = *(const bf16x8*)&Ks[ns * 16 + li][64 + lg * 8];
      bf16x8 bk3 = *(const bf16x8*)&Ks[ns * 16 + li][96 + lg * 8];
      int s = s0 + ns * 16 + li;
      float gv = gls[ns * 16 + li];
      if (actA) {
        floatx4 pa = (floatx4)(0.f);
        pa = __builtin_amdgcn_mfma_f32_16x16x32_bf16(aqA[0], bk0, pa, 0, 0, 0);
        pa = __builtin_amdgcn_mfma_f32_16x16x32_bf16(aqA[1], bk1, pa, 0, 0, 0);
        pa = __builtin_amdgcn_mfma_f32_16x16x32_bf16(aqA[2], bk2, pa, 0, 0, 0);
        pa = __builtin_amdgcn_mfma_f32_16x16x32_bf16(aqA[3], bk3, pa, 0, 0, 0);
        #pragma unroll
        for (int r = 0; r < 4; ++r) {
          int t = tbA + lg * 4 + r;
          float val = pa[r] * scale * __expf(gv - mlA[r]);
          float w = (s <= t) ? val : 0.f;
          rsA[r] += w;
          plds[wv][0][lg * 4 + r][ns * 16 + li] = (__bf16)w;
        }
      }
      {
        floatx4 pb = (floatx4)(0.f);
        pb = __builtin_amdgcn_mfma_f32_16x16x32_bf16(aqB[0], bk0, pb, 0, 0, 0);
        pb = __builtin_amdgcn_mfma_f32_16x16x32_bf16(aqB[1], bk1, pb, 0, 0, 0);
        pb = __builtin_amdgcn_mfma_f32_16x16x32_bf16(aqB[2], bk2, pb, 0, 0, 0);
        pb = __builtin_amdgcn_mfma_f32_16x16x32_bf16(aqB[3], bk3, pb, 0, 0, 0);
        #pragma unroll
        for (int r = 0; r < 4; ++r) {
          int t = tbB + lg * 4 + r;
          float val = pb[r] * scale * __expf(gv - mlB[r]);
          float w = (s <= t) ? val : 0.f;
          rsB[r] += w;
          plds[wv][1][lg * 4 + r][ns * 16 + li] = (__bf16)w;
        }
      }
    }
    bf16x8 apA0, apA1, apB0, apB1;
    if (actA) {
      apA0 = *(const bf16x8*)&plds[wv][0][li][lg * 8];
      apA1 = *(const bf16x8*)&plds[wv][0][li][32 + lg * 8];
    }
    apB0 = *(const bf16x8*)&plds[wv][1][li][lg * 8];
    apB1 = *(const bf16x8*)&plds[wv][1][li][32 + lg * 8];
    #pragma unroll
    for (int df = 0; df < 8; ++df) {
      bf16x8 bv0 = *(const bf16x8*)&Vs[df * 16 + li][lg * 8];
      bf16x8 bv1 = *(const bf16x8*)&Vs[df * 16 + li][32 + lg * 8];
      if (actA) {
        oA[df] = __builtin_amdgcn_mfma_f32_16x16x32_bf16(apA0, bv0, oA[df], 0, 0, 0);
        oA[df] = __builtin_amdgcn_mfma_f32_16x16x32_bf16(apA1, bv1, oA[df], 0, 0, 0);
      }
      oB[df] = __builtin_amdgcn_mfma_f32_16x16x32_bf16(apB0, bv0, oB[df], 0, 0, 0);
      oB[df] = __builtin_amdgcn_mfma_f32_16x16x32_bf16(apB1, bv1, oB[df], 0, 0, 0);
    }
  }
  #pragma unroll
  for (int r = 0; r < 4; ++r) {
    float a = rsA[r], b = rsB[r];
    a += __shfl_xor(a, 1, 64); a += __shfl_xor(a, 2, 64);
    a += __shfl_xor(a, 4, 64); a += __shfl_xor(a, 8, 64);
    b += __shfl_xor(b, 1, 64); b += __shfl_xor(b, 2, 64);
    b += __shfl_xor(b, 4, 64); b += __shfl_xor(b, 8, 64);
    rsA[r] = a; rsB[r] = b;
  }
  #pragma unroll
  for (int tile = 0; tile < 2; ++tile) {
    int tb = tile == 0 ? tbA : tbB;
    #pragma unroll
    for (int r = 0; r < 4; ++r) {
      float rs = tile == 0 ? rsA[r] : rsB[r];
      float nf = tile == 0 ? nfA[r] : nfB[r];
      float inv = 1.f / (fmaxf(fabsf(rs), nf) + 1e-6f);
      float v8[8], s1 = 0.f, s2 = 0.f;
      #pragma unroll
      for (int df = 0; df < 8; ++df) {
        float v = (tile == 0 ? oA[df][r] : oB[df][r]) * inv;
        v8[df] = v;
        s1 += v;
        s2 += v * v;
      }
      s1 += __shfl_xor(s1, 1, 64); s1 += __shfl_xor(s1, 2, 64);
      s1 += __shfl_xor(s1, 4, 64); s1 += __shfl_xor(s1, 8, 64);
      s2 += __shfl_xor(s2, 1, 64); s2 += __shfl_xor(s2, 2, 64);
      s2 += __shfl_xor(s2, 4, 64); s2 += __shfl_xor(s2, 8, 64);
      float mu = s1 * (1.f / 128.f);
      float var = s2 * (1.f / 128.f) - mu * mu;
      float rq = rsqrtf(var + 1e-5f);
      int t = tb + lg * 4 + r;
      const __bf16* xr = xc + ((size_t)(bb * S + t)) * 512 + hh * 128 + li;
      const __bf16* zr = up + ((size_t)(bb * S + t)) * 1024 + 512 + hh * 128 + li;
      __bf16* od = hd + ((size_t)(bb * S + t)) * 512 + hh * 128 + li;
      #pragma unroll
      for (int df = 0; df < 8; ++df) {
        int c = df * 16 + li;
        float ln = (v8[df] - mu) * rq * glds[c] + blds[c];
        float val = ln + slds[c] * (float)xr[df * 16];
        float z = (float)zr[df * 16];
        float sg = 1.f / (1.f + __expf(-z));
        od[df * 16] = (__bf16)(val * (z * sg));
      }
    }
  }
}

// ---------------- final LN + head ----------------
__global__ __launch_bounds__(256) void final_kernel(
    const float* __restrict__ h, const float* __restrict__ g,
    const float* __restrict__ b, const float* __restrict__ Wf,
    const float* __restrict__ bf, float* __restrict__ out) {
  int bb = blockIdx.x, tid = threadIdx.x;
  size_t row = (size_t)(bb * S + S - 1) * 256;
  __shared__ float red[4];
  float v = h[row + tid];
  float s = wave_sum(v);
  int wid = tid >> 6, lane = tid & 63;
  if (lane == 0) red[wid] = s;
  __syncthreads();
  float mu = (red[0] + red[1] + red[2] + red[3]) * (1.f / 256.f);
  __syncthreads();
  float d = v - mu;
  float s2 = wave_sum(d * d);
  if (lane == 0) red[wid] = s2;
  __syncthreads();
  float var = (red[0] + red[1] + red[2] + red[3]) * (1.f / 256.f);
  float rs = rsqrtf(var + 1e-5f);
  float ln = d * rs * g[tid] + b[tid];
  float p = ln * Wf[tid];
  float psum = wave_sum(p);
  __syncthreads();
  if (lane == 0) red[wid] = psum;
  __syncthreads();
  if (tid == 0) out[bb] = red[0] + red[1] + red[2] + red[3] + bf[0];
}

extern "C" void kernel_launch(void* const* d_in, const int* in_sizes, int n_in,
                              void* d_out, int out_size, void* d_ws, size_t ws_size,
                              hipStream_t stream) {
  const float* x      = (const float*)d_in[0];
  const float* tf     = (const float*)d_in[1];
  const float* Wp     = (const float*)d_in[2];
  const float* bp     = (const float*)d_in[3];
  const float* ln_g   = (const float*)d_in[4];
  const float* ln_b   = (const float*)d_in[5];
  const float* Wup    = (const float*)d_in[6];
  const float* bup    = (const float*)d_in[7];
  const float* conv_w = (const float*)d_in[8];
  const float* conv_b = (const float*)d_in[9];
  const float* Wq     = (const float*)d_in[10];
  const float* Wk     = (const float*)d_in[11];
  const float* Wv     = (const float*)d_in[12];
  const float* Wif    = (const float*)d_in[13];
  const float* bif    = (const float*)d_in[14];
  const float* gn_g   = (const float*)d_in[15];
  const float* gn_b   = (const float*)d_in[16];
  const float* skip   = (const float*)d_in[17];
  const float* Wdown  = (const float*)d_in[18];
  const float* bdown  = (const float*)d_in[19];
  const float* lnf_g  = (const float*)d_in[20];
  const float* lnf_b  = (const float*)d_in[21];
  const float* Wf     = (const float*)d_in[22];
  const float* bf     = (const float*)d_in[23];
  float* out = (float*)d_out;

  float* h     = (float*)d_ws;              // 2,097,152 f32
  float* gates = h + 2097152;               // 65,536 f32
  float* gbuf  = gates + 65536;             // 32,768
  float* Mbuf  = gbuf + 32768;              // 32,768
  float* NFbuf = Mbuf + 32768;              // 32,768
  float* wgbuf = NFbuf + 32768;             // 32,768
  __bf16* hn   = (__bf16*)(wgbuf + 32768);  // 2,097,152 bf16
  __bf16* up   = hn + 2097152;              // 8,388,608
  __bf16* xc   = up + 8388608;              // 4,194,304
  __bf16* qk   = xc + 4194304;              // 8,388,608
  __bf16* vT   = qk + 8388608;              // 4,194,304
  __bf16* hd   = vT + 4194304;              // 4,194,304
  __bf16* WupT   = hd + 4194304;            // 1,048,576
  __bf16* WqkT   = WupT + 1048576;          // 2,097,152
  __bf16* WvT    = WqkT + 2097152;          // 1,048,576
  __bf16* WdownT = WvT + 1048576;           // 524,288

  wtrans_kernel<<<4608, 256, 0, stream>>>(Wup, Wq, Wk, Wv, Wdown,
                                          WupT, WqkT, WvT, WdownT);
  wgprep_kernel<<<1024, 256, 0, stream>>>(Wq, Wk, Wv, Wif, wgbuf);
  embed_kernel<<<8192, 256, 0, stream>>>(x, tf, Wp, bp, ln_g, ln_b, h, hn);
  for (int l = 0; l < NLAYER; ++l) {
    if (l > 0)
      ln256_kernel<<<8192, 256, 0, stream>>>(h, ln_g + l * 256, ln_b + l * 256, hn);
    hgemm<1, 0><<<dim3(8, 64), 256, 0, stream>>>(
        hn, 256, WupT + (size_t)l * 262144, 256, bup + l * 1024, up, 1024);
    conv_silu_kernel<<<2048, 256, 0, stream>>>(up, conv_w + l * 2048, conv_b + l * 512,
                                               wgbuf + l * 8192, bif + l * 8, xc, gates);
    scan_kernel<<<32, 64, 0, stream>>>(gates, gbuf, Mbuf, NFbuf);
    hgemm<1, 0><<<dim3(8, 64), 256, 0, stream>>>(
        xc, 512, WqkT + (size_t)l * 524288, 512, nullptr, qk, 1024);
    hgemm<2, 0><<<dim3(4, 64), 256, 0, stream>>>(
        up, 1024, WvT + (size_t)l * 262144, 512, nullptr, vT, 0);
    attn_kernel<<<dim3(8, 32), 256, 0, stream>>>(
        qk, vT, gbuf, Mbuf, NFbuf, gn_g + l * 512, gn_b + l * 512, skip + l * 512,
        xc, up, hd);
    hgemm<0, 1><<<dim3(2, 64), 256, 0, stream>>>(
        hd, 512, WdownT + (size_t)l * 131072, 512, bdown + l * 256, h, 256);
  }
  final_kernel<<<8, 256, 0, stream>>>(h, lnf_g, lnf_b, Wf, bf, out);
}

// Round 10
// 744.524 us; speedup vs baseline: 1.0513x; 1.0353x over previous
//
#include <hip/hip_runtime.h>
#include <hip/hip_bf16.h>
#include <math.h>

#define S 1024
#define NLAYER 4

typedef __bf16 bf16x8 __attribute__((ext_vector_type(8)));
typedef float floatx4 __attribute__((ext_vector_type(4)));

__device__ __forceinline__ float wave_sum(float v) {
  #pragma unroll
  for (int off = 32; off > 0; off >>= 1) v += __shfl_xor(v, off, 64);
  return v;
}

// ---------------- embed: h = [x, tf] @ Wp + bp (fp32) + fused LN(layer0) ----------------
__global__ __launch_bounds__(256) void embed_kernel(
    const float* __restrict__ x, const float* __restrict__ tf,
    const float* __restrict__ Wp, const float* __restrict__ bp,
    const float* __restrict__ g, const float* __restrict__ b,
    float* __restrict__ h, __bf16* __restrict__ hn) {
  int row = blockIdx.x;
  int n = threadIdx.x;
  float xv = x[row];
  const float* t4 = tf + (size_t)row * 4;
  float acc = bp[n] + xv * Wp[n];
  acc += t4[0] * Wp[256 + n];
  acc += t4[1] * Wp[512 + n];
  acc += t4[2] * Wp[768 + n];
  acc += t4[3] * Wp[1024 + n];
  h[(size_t)row * 256 + n] = acc;
  __shared__ float red[4];
  int wid = n >> 6, lane = n & 63;
  float s = wave_sum(acc);
  if (lane == 0) red[wid] = s;
  __syncthreads();
  float mu = (red[0] + red[1] + red[2] + red[3]) * (1.f / 256.f);
  __syncthreads();
  float d = acc - mu;
  float s2 = wave_sum(d * d);
  if (lane == 0) red[wid] = s2;
  __syncthreads();
  float var = (red[0] + red[1] + red[2] + red[3]) * (1.f / 256.f);
  float rs = rsqrtf(var + 1e-5f);
  hn[(size_t)row * 256 + n] = (__bf16)(d * rs * g[n] + b[n]);
}

// ---------------- weight transpose+cast: W[K][N] f32 -> WT[N][K] bf16 ----------------
__global__ __launch_bounds__(256) void wtrans_kernel(
    const float* __restrict__ Wup, const float* __restrict__ Wq,
    const float* __restrict__ Wk, const float* __restrict__ Wv,
    const float* __restrict__ Wdown,
    __bf16* __restrict__ WupT, __bf16* __restrict__ WqkT,
    __bf16* __restrict__ WvT, __bf16* __restrict__ WdownT) {
  __shared__ float T[32][33];
  int bid = blockIdx.x;
  int layer = bid / 1152, rr = bid % 1152;
  const float* src; __bf16* dst; int K, N, tile;
  if (rr < 256)       { src = Wup   + layer * 262144; dst = WupT  + layer * 262144;          K = 256; N = 1024; tile = rr; }
  else if (rr < 512)  { src = Wq    + layer * 262144; dst = WqkT  + layer * 524288;          K = 512; N = 512;  tile = rr - 256; }
  else if (rr < 768)  { src = Wk    + layer * 262144; dst = WqkT  + layer * 524288 + 262144; K = 512; N = 512;  tile = rr - 512; }
  else if (rr < 1024) { src = Wv    + layer * 262144; dst = WvT   + layer * 262144;          K = 512; N = 512;  tile = rr - 768; }
  else                { src = Wdown + layer * 131072; dst = WdownT + layer * 131072;         K = 512; N = 256;  tile = rr - 1024; }
  int ntn = N >> 5;
  int tk = tile / ntn, tn = tile % ntn;
  int tid = threadIdx.x;
  int r = tid >> 3, c4 = (tid & 7) * 4;
  float4 v = *(const float4*)(src + (size_t)(tk * 32 + r) * N + tn * 32 + c4);
  T[c4 + 0][r] = v.x; T[c4 + 1][r] = v.y; T[c4 + 2][r] = v.z; T[c4 + 3][r] = v.w;
  __syncthreads();
  __bf16 o[4];
  #pragma unroll
  for (int j = 0; j < 4; ++j) o[j] = (__bf16)T[r][c4 + j];
  *(uint2*)(dst + (size_t)(tn * 32 + r) * K + tk * 32 + c4) = *(uint2*)o;
}

// ---------------- Wg precompute (coalesced wave-per-row) ----------------
__global__ __launch_bounds__(256) void wgprep_kernel(
    const float* __restrict__ Wq, const float* __restrict__ Wk,
    const float* __restrict__ Wv, const float* __restrict__ Wif,
    float* __restrict__ wg) {
  int bid = blockIdx.x;
  int l = bid >> 8;
  int rem = bid & 255;
  int sel = rem >> 7;
  int kg = rem & 127;
  int tid = threadIdx.x;
  int wv = tid >> 6, lane = tid & 63;
  int k = kg * 4 + wv;
  const float* wif = Wif + (size_t)l * 1536 * 8;
  float part[8] = {0, 0, 0, 0, 0, 0, 0, 0};
  if (sel == 0) {
    const float* qr = Wq + (size_t)l * 262144 + (size_t)k * 512;
    const float* kr = Wk + (size_t)l * 262144 + (size_t)k * 512;
    #pragma unroll
    for (int i = 0; i < 8; ++i) {
      int n = lane + i * 64;
      float qv = qr[n], kv = kr[n];
      const float* wq8 = wif + (size_t)n * 8;
      const float* wk8 = wif + (size_t)(512 + n) * 8;
      #pragma unroll
      for (int j = 0; j < 8; ++j) part[j] += qv * wq8[j] + kv * wk8[j];
    }
  } else {
    const float* vr = Wv + (size_t)l * 262144 + (size_t)k * 512;
    #pragma unroll
    for (int i = 0; i < 8; ++i) {
      int n = lane + i * 64;
      float vv = vr[n];
      const float* wv8 = wif + (size_t)(1024 + n) * 8;
      #pragma unroll
      for (int j = 0; j < 8; ++j) part[j] += vv * wv8[j];
    }
  }
  #pragma unroll
  for (int j = 0; j < 8; ++j) part[j] = wave_sum(part[j]);
  if (lane < 8) wg[(size_t)l * 8192 + sel * 4096 + (size_t)k * 8 + lane] = part[lane];
}

// ---------------- LayerNorm over 256, fp32 in -> bf16 out ----------------
__global__ __launch_bounds__(256) void ln256_kernel(
    const float* __restrict__ x, const float* __restrict__ g,
    const float* __restrict__ b, __bf16* __restrict__ y) {
  int row = blockIdx.x, tid = threadIdx.x;
  __shared__ float red[4];
  float v = x[(size_t)row * 256 + tid];
  float s = wave_sum(v);
  int wid = tid >> 6, lane = tid & 63;
  if (lane == 0) red[wid] = s;
  __syncthreads();
  float mu = (red[0] + red[1] + red[2] + red[3]) * (1.f / 256.f);
  __syncthreads();
  float d = v - mu;
  float s2 = wave_sum(d * d);
  if (lane == 0) red[wid] = s2;
  __syncthreads();
  float var = (red[0] + red[1] + red[2] + red[3]) * (1.f / 256.f);
  float rs = rsqrtf(var + 1e-5f);
  y[(size_t)row * 256 + tid] = (__bf16)(d * rs * g[tid] + b[tid]);
}

// ---------------- bf16 MFMA GEMM with register prefetch (R7 variant — best measured) ----------------
// MODE 0: f32 out (+ACC adds prev), MODE 1: bf16 row-major, MODE 2: bf16 scattered into vT.
template <int MODE, int ACC>
__global__ __launch_bounds__(256) void hgemm(
    const __bf16* __restrict__ A, int lda,
    const __bf16* __restrict__ BT, int Kdim,
    const float* __restrict__ bias,
    void* __restrict__ Cout, int ldc) {
  __shared__ __bf16 As[128][40];
  __shared__ __bf16 Bs[128][40];
  int tid = threadIdx.x;
  int bn = blockIdx.x * 128, bm = blockIdx.y * 128;
  int wid = tid >> 6, lane = tid & 63;
  int wr = wid >> 1, wc = wid & 1;
  int lg = lane >> 4, li = lane & 15;
  floatx4 acc[4][4];
  #pragma unroll
  for (int i = 0; i < 4; ++i)
    #pragma unroll
    for (int j = 0; j < 4; ++j) acc[i][j] = (floatx4)(0.f);

  int arow = tid >> 2, aseg = tid & 3;
  bf16x8 pa0, pa1, pb0, pb1;
  auto pre = [&](int k0) {
    pa0 = *(const bf16x8*)(A + (size_t)(bm + arow) * lda + k0 + aseg * 8);
    pa1 = *(const bf16x8*)(A + (size_t)(bm + arow + 64) * lda + k0 + aseg * 8);
    pb0 = *(const bf16x8*)(BT + (size_t)(bn + arow) * Kdim + k0 + aseg * 8);
    pb1 = *(const bf16x8*)(BT + (size_t)(bn + arow + 64) * Kdim + k0 + aseg * 8);
  };
  pre(0);
  for (int k0 = 0; k0 < Kdim; k0 += 32) {
    __syncthreads();
    *(bf16x8*)&As[arow][aseg * 8] = pa0;
    *(bf16x8*)&As[arow + 64][aseg * 8] = pa1;
    *(bf16x8*)&Bs[arow][aseg * 8] = pb0;
    *(bf16x8*)&Bs[arow + 64][aseg * 8] = pb1;
    __syncthreads();
    if (k0 + 32 < Kdim) pre(k0 + 32);
    bf16x8 af[4], bfr[4];
    #pragma unroll
    for (int mi = 0; mi < 4; ++mi)
      af[mi] = *(const bf16x8*)&As[wr * 64 + mi * 16 + li][lg * 8];
    #pragma unroll
    for (int ni = 0; ni < 4; ++ni)
      bfr[ni] = *(const bf16x8*)&Bs[wc * 64 + ni * 16 + li][lg * 8];
    #pragma unroll
    for (int mi = 0; mi < 4; ++mi)
      #pragma unroll
      for (int ni = 0; ni < 4; ++ni)
        acc[mi][ni] = __builtin_amdgcn_mfma_f32_16x16x32_bf16(af[mi], bfr[ni], acc[mi][ni], 0, 0, 0);
  }
  #pragma unroll
  for (int mi = 0; mi < 4; ++mi) {
    int row = bm + wr * 64 + mi * 16 + lg * 4;
    #pragma unroll
    for (int ni = 0; ni < 4; ++ni) {
      int col = bn + wc * 64 + ni * 16 + li;
      if (MODE == 2) {
        __bf16 o4[4];
        #pragma unroll
        for (int r = 0; r < 4; ++r) o4[r] = (__bf16)acc[mi][ni][r];
        __bf16* vt = (__bf16*)Cout;
        size_t off = ((size_t)((row >> 10) * 4 + (col >> 7)) * 128 + (col & 127)) * 1024 + (row & 1023);
        *(uint2*)(vt + off) = *(uint2*)o4;
      } else {
        float bz = bias ? bias[col] : 0.f;
        if (MODE == 1) {
          __bf16* C = (__bf16*)Cout;
          #pragma unroll
          for (int r = 0; r < 4; ++r)
            C[(size_t)(row + r) * ldc + col] = (__bf16)(acc[mi][ni][r] + bz);
        } else {
          float* C = (float*)Cout;
          #pragma unroll
          for (int r = 0; r < 4; ++r) {
            float v = acc[mi][ni][r] + bz;
            if (ACC) v += C[(size_t)(row + r) * ldc + col];
            C[(size_t)(row + r) * ldc + col] = v;
          }
        }
      }
    }
  }
}

// ---------------- causal conv (K=4) + SiLU + fused gate projection ----------------
__global__ __launch_bounds__(256) void conv_silu_kernel(
    const __bf16* __restrict__ up, const float* __restrict__ cw,
    const float* __restrict__ cb, const float* __restrict__ wg,
    const float* __restrict__ bif, __bf16* __restrict__ xc,
    float* __restrict__ gates) {
  int tid = threadIdx.x;
  int wv = tid >> 6, lane = tid & 63;
  int row = blockIdx.x * 4 + wv;
  int c8 = lane * 8;
  int t = row & (S - 1);
  float acc[8];
  *(float4*)&acc[0] = *(const float4*)(cb + c8);
  *(float4*)&acc[4] = *(const float4*)(cb + c8 + 4);
  float xm[8];
  #pragma unroll
  for (int j = 0; j < 4; ++j) {
    int tt = t - 3 + j;
    if (tt >= 0) {
      bf16x8 xv = *(const bf16x8*)(up + (size_t)(row - 3 + j) * 1024 + c8);
      float4 w0 = *(const float4*)(cw + j * 512 + c8);
      float4 w1 = *(const float4*)(cw + j * 512 + c8 + 4);
      acc[0] += w0.x * (float)xv[0]; acc[1] += w0.y * (float)xv[1];
      acc[2] += w0.z * (float)xv[2]; acc[3] += w0.w * (float)xv[3];
      acc[4] += w1.x * (float)xv[4]; acc[5] += w1.y * (float)xv[5];
      acc[6] += w1.z * (float)xv[6]; acc[7] += w1.w * (float)xv[7];
      if (j == 3) {
        #pragma unroll
        for (int m = 0; m < 8; ++m) xm[m] = (float)xv[m];
      }
    }
  }
  bf16x8 o;
  float xcs[8];
  #pragma unroll
  for (int m = 0; m < 8; ++m) {
    float sg = 1.f / (1.f + __expf(-acc[m]));
    xcs[m] = acc[m] * sg;
    o[m] = (__bf16)xcs[m];
  }
  *(bf16x8*)(xc + (size_t)row * 512 + c8) = o;
  const float* w1 = wg + (size_t)c8 * 8;
  const float* w2 = wg + 4096 + (size_t)c8 * 8;
  float part[8] = {0, 0, 0, 0, 0, 0, 0, 0};
  #pragma unroll
  for (int m = 0; m < 8; ++m) {
    const float* a = w1 + m * 8;
    const float* b = w2 + m * 8;
    #pragma unroll
    for (int j = 0; j < 8; ++j) part[j] += xcs[m] * a[j] + xm[m] * b[j];
  }
  #pragma unroll
  for (int j = 0; j < 8; ++j) part[j] = wave_sum(part[j]);
  if (lane < 8) gates[(size_t)row * 8 + lane] = part[lane] + bif[lane];
}

// ---------------- per-(b,h) gate scan: one wave ----------------
__global__ __launch_bounds__(64) void scan_kernel(
    const float* __restrict__ gates, float* __restrict__ gout,
    float* __restrict__ Mout, float* __restrict__ NFout) {
  int bh = blockIdx.x;
  int bb = bh >> 2, hh = bh & 3;
  int lane = threadIdx.x;
  float ip[16], pf[16];
  #pragma unroll
  for (int i = 0; i < 16; ++i) {
    int t = lane * 16 + i;
    const float* grow = gates + ((size_t)(bb * S + t)) * 8;
    ip[i] = grow[hh];
    float fp = grow[4 + hh];
    float lf = fminf(fp, 0.f) - log1pf(__expf(-fabsf(fp)));
    pf[i] = (i == 0) ? lf : pf[i - 1] + lf;
  }
  float T = pf[15];
  float inc = T;
  #pragma unroll
  for (int off = 1; off < 64; off <<= 1) {
    float v = __shfl_up(inc, off, 64);
    if (lane >= off) inc += v;
  }
  float excl = inc - T;
  float F[16], g[16], pm[16];
  #pragma unroll
  for (int i = 0; i < 16; ++i) {
    F[i] = excl + pf[i];
    g[i] = ip[i] - F[i];
    pm[i] = (i == 0) ? g[0] : fmaxf(pm[i - 1], g[i]);
  }
  float Mx = pm[15];
  float incm = Mx;
  #pragma unroll
  for (int off = 1; off < 64; off <<= 1) {
    float v = __shfl_up(incm, off, 64);
    if (lane >= off) incm = fmaxf(incm, v);
  }
  float em = __shfl_up(incm, 1, 64);
  if (lane == 0) em = -3.4e38f;
  #pragma unroll
  for (int i = 0; i < 16; ++i) {
    int t = lane * 16 + i;
    size_t o = (size_t)bh * S + t;
    float M = fmaxf(em, pm[i]);
    gout[o] = g[i];
    Mout[o] = M;
    NFout[o] = __expf(-F[i] - M);
  }
}

// ---------------- MFMA mLSTM attention + fused GroupNorm/skip/silu-gate ----------------
// grid (bh=32, px=8): linear id = px*32+bh -> id%8 = bh%8, so all px-blocks sharing one
// (b,h)'s K/V stream land on ONE XCD -> K/V L2-resident there (fetched once, reused 8x).
__global__ __launch_bounds__(256, 1) void attn_kernel(
    const __bf16* __restrict__ qk, const __bf16* __restrict__ vT,
    const float* __restrict__ gbuf, const float* __restrict__ Mbuf,
    const float* __restrict__ NFbuf,
    const float* __restrict__ gn_g, const float* __restrict__ gn_b,
    const float* __restrict__ skip,
    const __bf16* __restrict__ xc, const __bf16* __restrict__ up,
    __bf16* __restrict__ hd) {
  __shared__ __bf16 Ks[64][136];
  __shared__ __bf16 Vs[128][72];
  __shared__ __bf16 plds[4][2][16][72];
  __shared__ float gls[64];
  __shared__ float glds[128], blds[128], slds[128];
  int px = blockIdx.y, bh = blockIdx.x;   // XCD swizzle: bh fastest
  int tqA = px, tqB = 15 - px;
  int bb = bh >> 2, hh = bh & 3;
  int tid = threadIdx.x;
  int wv = tid >> 6, lane = tid & 63;
  int lg = lane >> 4, li = lane & 15;
  int tbA = tqA * 64 + wv * 16;
  int tbB = tqB * 64 + wv * 16;
  const float scale = 0.08838834764831845f;

  if (tid < 128) {
    glds[tid] = gn_g[hh * 128 + tid];
    blds[tid] = gn_b[hh * 128 + tid];
    slds[tid] = skip[hh * 128 + tid];
  }

  bf16x8 aqA[4], aqB[4];
  {
    const __bf16* qpA = qk + ((size_t)(bb * S + tbA + li)) * 1024 + hh * 128 + lg * 8;
    const __bf16* qpB = qk + ((size_t)(bb * S + tbB + li)) * 1024 + hh * 128 + lg * 8;
    #pragma unroll
    for (int cd = 0; cd < 4; ++cd) {
      aqA[cd] = *(const bf16x8*)(qpA + cd * 32);
      aqB[cd] = *(const bf16x8*)(qpB + cd * 32);
    }
  }
  float mlA[4], nfA[4], mlB[4], nfB[4];
  #pragma unroll
  for (int r = 0; r < 4; ++r) {
    mlA[r] = Mbuf[(size_t)bh * S + tbA + lg * 4 + r];
    nfA[r] = NFbuf[(size_t)bh * S + tbA + lg * 4 + r];
    mlB[r] = Mbuf[(size_t)bh * S + tbB + lg * 4 + r];
    nfB[r] = NFbuf[(size_t)bh * S + tbB + lg * 4 + r];
  }

  floatx4 oA[8], oB[8];
  #pragma unroll
  for (int df = 0; df < 8; ++df) { oA[df] = (floatx4)(0.f); oB[df] = (floatx4)(0.f); }
  float rsA[4] = {0, 0, 0, 0}, rsB[4] = {0, 0, 0, 0};

  int krow = tid >> 3, kcol = tid & 7;
  bf16x8 kreg[4], vreg[4];
  float greg = 0.f;
  auto preload = [&](int st) {
    int s0 = st * 64;
    const __bf16* kp = qk + ((size_t)(bb * S + s0 + krow)) * 1024 + 512 + hh * 128;
    kreg[0] = *(const bf16x8*)(kp + kcol * 8);
    kreg[1] = *(const bf16x8*)(kp + (size_t)32 * 1024 + kcol * 8);
    kreg[2] = *(const bf16x8*)(kp + 64 + kcol * 8);
    kreg[3] = *(const bf16x8*)(kp + (size_t)32 * 1024 + 64 + kcol * 8);
    #pragma unroll
    for (int i = 0; i < 4; ++i)
      vreg[i] = *(const bf16x8*)(vT + ((size_t)(bh * 128 + krow + i * 32)) * 1024 + s0 + kcol * 8);
    if (tid < 64) greg = gbuf[(size_t)bh * S + s0 + tid];
  };
  preload(0);

  for (int st = 0; st <= tqB; ++st) {
    __syncthreads();
    *(bf16x8*)&Ks[krow][kcol * 8] = kreg[0];
    *(bf16x8*)&Ks[krow + 32][kcol * 8] = kreg[1];
    *(bf16x8*)&Ks[krow][64 + kcol * 8] = kreg[2];
    *(bf16x8*)&Ks[krow + 32][64 + kcol * 8] = kreg[3];
    #pragma unroll
    for (int i = 0; i < 4; ++i) *(bf16x8*)&Vs[krow + i * 32][kcol * 8] = vreg[i];
    if (tid < 64) gls[tid] = greg;
    __syncthreads();
    if (st < tqB) preload(st + 1);

    int s0 = st * 64;
    bool actA = (st <= tqA);
    #pragma unroll
    for (int ns = 0; ns < 4; ++ns) {
      bf16x8 bk0 = *(const bf16x8*)&Ks[ns * 16 + li][lg * 8];
      bf16x8 bk1 = *(const bf16x8*)&Ks[ns * 16 + li][32 + lg * 8];
      bf16x8 bk2 = *(const bf16x8*)&Ks[ns * 16 + li][64 + lg * 8];
      bf16x8 bk3 = *(const bf16x8*)&Ks[ns * 16 + li][96 + lg * 8];
      int s = s0 + ns * 16 + li;
      float gv = gls[ns * 16 + li];
      if (actA) {
        floatx4 pa = (floatx4)(0.f);
        pa = __builtin_amdgcn_mfma_f32_16x16x32_bf16(aqA[0], bk0, pa, 0, 0, 0);
        pa = __builtin_amdgcn_mfma_f32_16x16x32_bf16(aqA[1], bk1, pa, 0, 0, 0);
        pa = __builtin_amdgcn_mfma_f32_16x16x32_bf16(aqA[2], bk2, pa, 0, 0, 0);
        pa = __builtin_amdgcn_mfma_f32_16x16x32_bf16(aqA[3], bk3, pa, 0, 0, 0);
        #pragma unroll
        for (int r = 0; r < 4; ++r) {
          int t = tbA + lg * 4 + r;
          float val = pa[r] * scale * __expf(gv - mlA[r]);
          float w = (s <= t) ? val : 0.f;
          rsA[r] += w;
          plds[wv][0][lg * 4 + r][ns * 16 + li] = (__bf16)w;
        }
      }
      {
        floatx4 pb = (floatx4)(0.f);
        pb = __builtin_amdgcn_mfma_f32_16x16x32_bf16(aqB[0], bk0, pb, 0, 0, 0);
        pb = __builtin_amdgcn_mfma_f32_16x16x32_bf16(aqB[1], bk1, pb, 0, 0, 0);
        pb = __builtin_amdgcn_mfma_f32_16x16x32_bf16(aqB[2], bk2, pb, 0, 0, 0);
        pb = __builtin_amdgcn_mfma_f32_16x16x32_bf16(aqB[3], bk3, pb, 0, 0, 0);
        #pragma unroll
        for (int r = 0; r < 4; ++r) {
          int t = tbB + lg * 4 + r;
          float val = pb[r] * scale * __expf(gv - mlB[r]);
          float w = (s <= t) ? val : 0.f;
          rsB[r] += w;
          plds[wv][1][lg * 4 + r][ns * 16 + li] = (__bf16)w;
        }
      }
    }
    bf16x8 apA0, apA1, apB0, apB1;
    if (actA) {
      apA0 = *(const bf16x8*)&plds[wv][0][li][lg * 8];
      apA1 = *(const bf16x8*)&plds[wv][0][li][32 + lg * 8];
    }
    apB0 = *(const bf16x8*)&plds[wv][1][li][lg * 8];
    apB1 = *(const bf16x8*)&plds[wv][1][li][32 + lg * 8];
    #pragma unroll
    for (int df = 0; df < 8; ++df) {
      bf16x8 bv0 = *(const bf16x8*)&Vs[df * 16 + li][lg * 8];
      bf16x8 bv1 = *(const bf16x8*)&Vs[df * 16 + li][32 + lg * 8];
      if (actA) {
        oA[df] = __builtin_amdgcn_mfma_f32_16x16x32_bf16(apA0, bv0, oA[df], 0, 0, 0);
        oA[df] = __builtin_amdgcn_mfma_f32_16x16x32_bf16(apA1, bv1, oA[df], 0, 0, 0);
      }
      oB[df] = __builtin_amdgcn_mfma_f32_16x16x32_bf16(apB0, bv0, oB[df], 0, 0, 0);
      oB[df] = __builtin_amdgcn_mfma_f32_16x16x32_bf16(apB1, bv1, oB[df], 0, 0, 0);
    }
  }
  #pragma unroll
  for (int r = 0; r < 4; ++r) {
    float a = rsA[r], b = rsB[r];
    a += __shfl_xor(a, 1, 64); a += __shfl_xor(a, 2, 64);
    a += __shfl_xor(a, 4, 64); a += __shfl_xor(a, 8, 64);
    b += __shfl_xor(b, 1, 64); b += __shfl_xor(b, 2, 64);
    b += __shfl_xor(b, 4, 64); b += __shfl_xor(b, 8, 64);
    rsA[r] = a; rsB[r] = b;
  }
  #pragma unroll
  for (int tile = 0; tile < 2; ++tile) {
    int tb = tile == 0 ? tbA : tbB;
    #pragma unroll
    for (int r = 0; r < 4; ++r) {
      float rs = tile == 0 ? rsA[r] : rsB[r];
      float nf = tile == 0 ? nfA[r] : nfB[r];
      float inv = 1.f / (fmaxf(fabsf(rs), nf) + 1e-6f);
      float v8[8], s1 = 0.f, s2 = 0.f;
      #pragma unroll
      for (int df = 0; df < 8; ++df) {
        float v = (tile == 0 ? oA[df][r] : oB[df][r]) * inv;
        v8[df] = v;
        s1 += v;
        s2 += v * v;
      }
      s1 += __shfl_xor(s1, 1, 64); s1 += __shfl_xor(s1, 2, 64);
      s1 += __shfl_xor(s1, 4, 64); s1 += __shfl_xor(s1, 8, 64);
      s2 += __shfl_xor(s2, 1, 64); s2 += __shfl_xor(s2, 2, 64);
      s2 += __shfl_xor(s2, 4, 64); s2 += __shfl_xor(s2, 8, 64);
      float mu = s1 * (1.f / 128.f);
      float var = s2 * (1.f / 128.f) - mu * mu;
      float rq = rsqrtf(var + 1e-5f);
      int t = tb + lg * 4 + r;
      const __bf16* xr = xc + ((size_t)(bb * S + t)) * 512 + hh * 128 + li;
      const __bf16* zr = up + ((size_t)(bb * S + t)) * 1024 + 512 + hh * 128 + li;
      __bf16* od = hd + ((size_t)(bb * S + t)) * 512 + hh * 128 + li;
      #pragma unroll
      for (int df = 0; df < 8; ++df) {
        int c = df * 16 + li;
        float ln = (v8[df] - mu) * rq * glds[c] + blds[c];
        float val = ln + slds[c] * (float)xr[df * 16];
        float z = (float)zr[df * 16];
        float sg = 1.f / (1.f + __expf(-z));
        od[df * 16] = (__bf16)(val * (z * sg));
      }
    }
  }
}

// ---------------- final LN + head ----------------
__global__ __launch_bounds__(256) void final_kernel(
    const float* __restrict__ h, const float* __restrict__ g,
    const float* __restrict__ b, const float* __restrict__ Wf,
    const float* __restrict__ bf, float* __restrict__ out) {
  int bb = blockIdx.x, tid = threadIdx.x;
  size_t row = (size_t)(bb * S + S - 1) * 256;
  __shared__ float red[4];
  float v = h[row + tid];
  float s = wave_sum(v);
  int wid = tid >> 6, lane = tid & 63;
  if (lane == 0) red[wid] = s;
  __syncthreads();
  float mu = (red[0] + red[1] + red[2] + red[3]) * (1.f / 256.f);
  __syncthreads();
  float d = v - mu;
  float s2 = wave_sum(d * d);
  if (lane == 0) red[wid] = s2;
  __syncthreads();
  float var = (red[0] + red[1] + red[2] + red[3]) * (1.f / 256.f);
  float rs = rsqrtf(var + 1e-5f);
  float ln = d * rs * g[tid] + b[tid];
  float p = ln * Wf[tid];
  float psum = wave_sum(p);
  __syncthreads();
  if (lane == 0) red[wid] = psum;
  __syncthreads();
  if (tid == 0) out[bb] = red[0] + red[1] + red[2] + red[3] + bf[0];
}

extern "C" void kernel_launch(void* const* d_in, const int* in_sizes, int n_in,
                              void* d_out, int out_size, void* d_ws, size_t ws_size,
                              hipStream_t stream) {
  const float* x      = (const float*)d_in[0];
  const float* tf     = (const float*)d_in[1];
  const float* Wp     = (const float*)d_in[2];
  const float* bp     = (const float*)d_in[3];
  const float* ln_g   = (const float*)d_in[4];
  const float* ln_b   = (const float*)d_in[5];
  const float* Wup    = (const float*)d_in[6];
  const float* bup    = (const float*)d_in[7];
  const float* conv_w = (const float*)d_in[8];
  const float* conv_b = (const float*)d_in[9];
  const float* Wq     = (const float*)d_in[10];
  const float* Wk     = (const float*)d_in[11];
  const float* Wv     = (const float*)d_in[12];
  const float* Wif    = (const float*)d_in[13];
  const float* bif    = (const float*)d_in[14];
  const float* gn_g   = (const float*)d_in[15];
  const float* gn_b   = (const float*)d_in[16];
  const float* skip   = (const float*)d_in[17];
  const float* Wdown  = (const float*)d_in[18];
  const float* bdown  = (const float*)d_in[19];
  const float* lnf_g  = (const float*)d_in[20];
  const float* lnf_b  = (const float*)d_in[21];
  const float* Wf     = (const float*)d_in[22];
  const float* bf     = (const float*)d_in[23];
  float* out = (float*)d_out;

  float* h     = (float*)d_ws;              // 2,097,152 f32
  float* gates = h + 2097152;               // 65,536 f32
  float* gbuf  = gates + 65536;             // 32,768
  float* Mbuf  = gbuf + 32768;              // 32,768
  float* NFbuf = Mbuf + 32768;              // 32,768
  float* wgbuf = NFbuf + 32768;             // 32,768
  __bf16* hn   = (__bf16*)(wgbuf + 32768);  // 2,097,152 bf16
  __bf16* up   = hn + 2097152;              // 8,388,608
  __bf16* xc   = up + 8388608;              // 4,194,304
  __bf16* qk   = xc + 4194304;              // 8,388,608
  __bf16* vT   = qk + 8388608;              // 4,194,304
  __bf16* hd   = vT + 4194304;              // 4,194,304
  __bf16* WupT   = hd + 4194304;            // 1,048,576
  __bf16* WqkT   = WupT + 1048576;          // 2,097,152
  __bf16* WvT    = WqkT + 2097152;          // 1,048,576
  __bf16* WdownT = WvT + 1048576;           // 524,288

  wtrans_kernel<<<4608, 256, 0, stream>>>(Wup, Wq, Wk, Wv, Wdown,
                                          WupT, WqkT, WvT, WdownT);
  wgprep_kernel<<<1024, 256, 0, stream>>>(Wq, Wk, Wv, Wif, wgbuf);
  embed_kernel<<<8192, 256, 0, stream>>>(x, tf, Wp, bp, ln_g, ln_b, h, hn);
  for (int l = 0; l < NLAYER; ++l) {
    if (l > 0)
      ln256_kernel<<<8192, 256, 0, stream>>>(h, ln_g + l * 256, ln_b + l * 256, hn);
    hgemm<1, 0><<<dim3(8, 64), 256, 0, stream>>>(
        hn, 256, WupT + (size_t)l * 262144, 256, bup + l * 1024, up, 1024);
    conv_silu_kernel<<<2048, 256, 0, stream>>>(up, conv_w + l * 2048, conv_b + l * 512,
                                               wgbuf + l * 8192, bif + l * 8, xc, gates);
    scan_kernel<<<32, 64, 0, stream>>>(gates, gbuf, Mbuf, NFbuf);
    hgemm<1, 0><<<dim3(8, 64), 256, 0, stream>>>(
        xc, 512, WqkT + (size_t)l * 524288, 512, nullptr, qk, 1024);
    hgemm<2, 0><<<dim3(4, 64), 256, 0, stream>>>(
        up, 1024, WvT + (size_t)l * 262144, 512, nullptr, vT, 0);
    attn_kernel<<<dim3(32, 8), 256, 0, stream>>>(
        qk, vT, gbuf, Mbuf, NFbuf, gn_g + l * 512, gn_b + l * 512, skip + l * 512,
        xc, up, hd);
    hgemm<0, 1><<<dim3(2, 64), 256, 0, stream>>>(
        hd, 512, WdownT + (size_t)l * 131072, 512, bdown + l * 256, h, 256);
  }
  final_kernel<<<8, 256, 0, stream>>>(h, lnf_g, lnf_b, Wf, bf, out);
}

// Round 11
// 728.407 us; speedup vs baseline: 1.0745x; 1.0221x over previous
//
#include <hip/hip_runtime.h>
#include <hip/hip_bf16.h>
#include <math.h>

#define S 1024
#define NLAYER 4

typedef __bf16 bf16x8 __attribute__((ext_vector_type(8)));
typedef float floatx4 __attribute__((ext_vector_type(4)));

__device__ __forceinline__ float wave_sum(float v) {
  #pragma unroll
  for (int off = 32; off > 0; off >>= 1) v += __shfl_xor(v, off, 64);
  return v;
}

// ---------------- embed: h = [x, tf] @ Wp + bp (fp32) + fused LN(layer0) ----------------
__global__ __launch_bounds__(256) void embed_kernel(
    const float* __restrict__ x, const float* __restrict__ tf,
    const float* __restrict__ Wp, const float* __restrict__ bp,
    const float* __restrict__ g, const float* __restrict__ b,
    float* __restrict__ h, __bf16* __restrict__ hn) {
  int row = blockIdx.x;
  int n = threadIdx.x;
  float xv = x[row];
  const float* t4 = tf + (size_t)row * 4;
  float acc = bp[n] + xv * Wp[n];
  acc += t4[0] * Wp[256 + n];
  acc += t4[1] * Wp[512 + n];
  acc += t4[2] * Wp[768 + n];
  acc += t4[3] * Wp[1024 + n];
  h[(size_t)row * 256 + n] = acc;
  __shared__ float red[4];
  int wid = n >> 6, lane = n & 63;
  float s = wave_sum(acc);
  if (lane == 0) red[wid] = s;
  __syncthreads();
  float mu = (red[0] + red[1] + red[2] + red[3]) * (1.f / 256.f);
  __syncthreads();
  float d = acc - mu;
  float s2 = wave_sum(d * d);
  if (lane == 0) red[wid] = s2;
  __syncthreads();
  float var = (red[0] + red[1] + red[2] + red[3]) * (1.f / 256.f);
  float rs = rsqrtf(var + 1e-5f);
  hn[(size_t)row * 256 + n] = (__bf16)(d * rs * g[n] + b[n]);
}

// ---------------- weight transpose+cast: W[K][N] f32 -> WT[N][K] bf16 ----------------
__global__ __launch_bounds__(256) void wtrans_kernel(
    const float* __restrict__ Wup, const float* __restrict__ Wq,
    const float* __restrict__ Wk, const float* __restrict__ Wv,
    const float* __restrict__ Wdown,
    __bf16* __restrict__ WupT, __bf16* __restrict__ WqkT,
    __bf16* __restrict__ WvT, __bf16* __restrict__ WdownT) {
  __shared__ float T[32][33];
  int bid = blockIdx.x;
  int layer = bid / 1152, rr = bid % 1152;
  const float* src; __bf16* dst; int K, N, tile;
  if (rr < 256)       { src = Wup   + layer * 262144; dst = WupT  + layer * 262144;          K = 256; N = 1024; tile = rr; }
  else if (rr < 512)  { src = Wq    + layer * 262144; dst = WqkT  + layer * 524288;          K = 512; N = 512;  tile = rr - 256; }
  else if (rr < 768)  { src = Wk    + layer * 262144; dst = WqkT  + layer * 524288 + 262144; K = 512; N = 512;  tile = rr - 512; }
  else if (rr < 1024) { src = Wv    + layer * 262144; dst = WvT   + layer * 262144;          K = 512; N = 512;  tile = rr - 768; }
  else                { src = Wdown + layer * 131072; dst = WdownT + layer * 131072;         K = 512; N = 256;  tile = rr - 1024; }
  int ntn = N >> 5;
  int tk = tile / ntn, tn = tile % ntn;
  int tid = threadIdx.x;
  int r = tid >> 3, c4 = (tid & 7) * 4;
  float4 v = *(const float4*)(src + (size_t)(tk * 32 + r) * N + tn * 32 + c4);
  T[c4 + 0][r] = v.x; T[c4 + 1][r] = v.y; T[c4 + 2][r] = v.z; T[c4 + 3][r] = v.w;
  __syncthreads();
  __bf16 o[4];
  #pragma unroll
  for (int j = 0; j < 4; ++j) o[j] = (__bf16)T[r][c4 + j];
  *(uint2*)(dst + (size_t)(tn * 32 + r) * K + tk * 32 + c4) = *(uint2*)o;
}

// ---------------- Wg precompute (coalesced wave-per-row) ----------------
__global__ __launch_bounds__(256) void wgprep_kernel(
    const float* __restrict__ Wq, const float* __restrict__ Wk,
    const float* __restrict__ Wv, const float* __restrict__ Wif,
    float* __restrict__ wg) {
  int bid = blockIdx.x;
  int l = bid >> 8;
  int rem = bid & 255;
  int sel = rem >> 7;
  int kg = rem & 127;
  int tid = threadIdx.x;
  int wv = tid >> 6, lane = tid & 63;
  int k = kg * 4 + wv;
  const float* wif = Wif + (size_t)l * 1536 * 8;
  float part[8] = {0, 0, 0, 0, 0, 0, 0, 0};
  if (sel == 0) {
    const float* qr = Wq + (size_t)l * 262144 + (size_t)k * 512;
    const float* kr = Wk + (size_t)l * 262144 + (size_t)k * 512;
    #pragma unroll
    for (int i = 0; i < 8; ++i) {
      int n = lane + i * 64;
      float qv = qr[n], kv = kr[n];
      const float* wq8 = wif + (size_t)n * 8;
      const float* wk8 = wif + (size_t)(512 + n) * 8;
      #pragma unroll
      for (int j = 0; j < 8; ++j) part[j] += qv * wq8[j] + kv * wk8[j];
    }
  } else {
    const float* vr = Wv + (size_t)l * 262144 + (size_t)k * 512;
    #pragma unroll
    for (int i = 0; i < 8; ++i) {
      int n = lane + i * 64;
      float vv = vr[n];
      const float* wv8 = wif + (size_t)(1024 + n) * 8;
      #pragma unroll
      for (int j = 0; j < 8; ++j) part[j] += vv * wv8[j];
    }
  }
  #pragma unroll
  for (int j = 0; j < 8; ++j) part[j] = wave_sum(part[j]);
  if (lane < 8) wg[(size_t)l * 8192 + sel * 4096 + (size_t)k * 8 + lane] = part[lane];
}

// ---------------- LayerNorm over 256, fp32 in -> bf16 out ----------------
__global__ __launch_bounds__(256) void ln256_kernel(
    const float* __restrict__ x, const float* __restrict__ g,
    const float* __restrict__ b, __bf16* __restrict__ y) {
  int row = blockIdx.x, tid = threadIdx.x;
  __shared__ float red[4];
  float v = x[(size_t)row * 256 + tid];
  float s = wave_sum(v);
  int wid = tid >> 6, lane = tid & 63;
  if (lane == 0) red[wid] = s;
  __syncthreads();
  float mu = (red[0] + red[1] + red[2] + red[3]) * (1.f / 256.f);
  __syncthreads();
  float d = v - mu;
  float s2 = wave_sum(d * d);
  if (lane == 0) red[wid] = s2;
  __syncthreads();
  float var = (red[0] + red[1] + red[2] + red[3]) * (1.f / 256.f);
  float rs = rsqrtf(var + 1e-5f);
  y[(size_t)row * 256 + tid] = (__bf16)(d * rs * g[tid] + b[tid]);
}

// ---------------- bf16 MFMA GEMM, register prefetch, XCD-local grid, coalesced epilogue --
// grid (M/128, N/128): row-tile = blockIdx.x (fast) -> col-blocks sharing an A-slice land
// on the SAME XCD (id%8 = row%8) -> A fetched once per XCD L2 instead of 8x from HBM.
// MODE 0: f32 out (+ACC adds prev), MODE 1: bf16 row-major via LDS-transposed coalesced
// stores, MODE 2: bf16 scattered into vT.
template <int MODE, int ACC>
__global__ __launch_bounds__(256) void hgemm(
    const __bf16* __restrict__ A, int lda,
    const __bf16* __restrict__ BT, int Kdim,
    const float* __restrict__ bias,
    void* __restrict__ Cout, int ldc) {
  __shared__ __bf16 As[128][40];
  __shared__ __bf16 Bs[128][40];
  int tid = threadIdx.x;
  int bm = blockIdx.x * 128, bn = blockIdx.y * 128;
  int wid = tid >> 6, lane = tid & 63;
  int wr = wid >> 1, wc = wid & 1;
  int lg = lane >> 4, li = lane & 15;
  floatx4 acc[4][4];
  #pragma unroll
  for (int i = 0; i < 4; ++i)
    #pragma unroll
    for (int j = 0; j < 4; ++j) acc[i][j] = (floatx4)(0.f);

  int arow = tid >> 2, aseg = tid & 3;
  bf16x8 pa0, pa1, pb0, pb1;
  auto pre = [&](int k0) {
    pa0 = *(const bf16x8*)(A + (size_t)(bm + arow) * lda + k0 + aseg * 8);
    pa1 = *(const bf16x8*)(A + (size_t)(bm + arow + 64) * lda + k0 + aseg * 8);
    pb0 = *(const bf16x8*)(BT + (size_t)(bn + arow) * Kdim + k0 + aseg * 8);
    pb1 = *(const bf16x8*)(BT + (size_t)(bn + arow + 64) * Kdim + k0 + aseg * 8);
  };
  pre(0);
  for (int k0 = 0; k0 < Kdim; k0 += 32) {
    __syncthreads();
    *(bf16x8*)&As[arow][aseg * 8] = pa0;
    *(bf16x8*)&As[arow + 64][aseg * 8] = pa1;
    *(bf16x8*)&Bs[arow][aseg * 8] = pb0;
    *(bf16x8*)&Bs[arow + 64][aseg * 8] = pb1;
    __syncthreads();
    if (k0 + 32 < Kdim) pre(k0 + 32);
    bf16x8 af[4], bfr[4];
    #pragma unroll
    for (int mi = 0; mi < 4; ++mi)
      af[mi] = *(const bf16x8*)&As[wr * 64 + mi * 16 + li][lg * 8];
    #pragma unroll
    for (int ni = 0; ni < 4; ++ni)
      bfr[ni] = *(const bf16x8*)&Bs[wc * 64 + ni * 16 + li][lg * 8];
    #pragma unroll
    for (int mi = 0; mi < 4; ++mi)
      #pragma unroll
      for (int ni = 0; ni < 4; ++ni)
        acc[mi][ni] = __builtin_amdgcn_mfma_f32_16x16x32_bf16(af[mi], bfr[ni], acc[mi][ni], 0, 0, 0);
  }
  if (MODE == 1) {
    // LDS-transposed epilogue: 32x128 chunks staged into (reused) As, then 16B stores.
    __bf16* eb = &As[0][0];
    const int PITCH = 136;
    __bf16* C = (__bf16*)Cout;
    #pragma unroll
    for (int mi = 0; mi < 4; ++mi) {
      __syncthreads();
      #pragma unroll
      for (int ni = 0; ni < 4; ++ni) {
        int col = wc * 64 + ni * 16 + li;
        float bz = bias ? bias[bn + col] : 0.f;
        #pragma unroll
        for (int r = 0; r < 4; ++r) {
          int lr = wr * 16 + lg * 4 + r;
          eb[lr * PITCH + col] = (__bf16)(acc[mi][ni][r] + bz);
        }
      }
      __syncthreads();
      #pragma unroll
      for (int i = 0; i < 2; ++i) {
        int lr = (tid >> 4) + i * 16;
        int c8 = (tid & 15) * 8;
        bf16x8 v = *(const bf16x8*)&eb[lr * PITCH + c8];
        int row_g = bm + (lr >> 4) * 64 + mi * 16 + (lr & 15);
        *(bf16x8*)(C + (size_t)row_g * ldc + bn + c8) = v;
      }
    }
  } else {
    #pragma unroll
    for (int mi = 0; mi < 4; ++mi) {
      int row = bm + wr * 64 + mi * 16 + lg * 4;
      #pragma unroll
      for (int ni = 0; ni < 4; ++ni) {
        int col = bn + wc * 64 + ni * 16 + li;
        if (MODE == 2) {
          __bf16 o4[4];
          #pragma unroll
          for (int r = 0; r < 4; ++r) o4[r] = (__bf16)acc[mi][ni][r];
          __bf16* vt = (__bf16*)Cout;
          size_t off = ((size_t)((row >> 10) * 4 + (col >> 7)) * 128 + (col & 127)) * 1024 + (row & 1023);
          *(uint2*)(vt + off) = *(uint2*)o4;
        } else {
          float bz = bias ? bias[col] : 0.f;
          float* C = (float*)Cout;
          #pragma unroll
          for (int r = 0; r < 4; ++r) {
            float v = acc[mi][ni][r] + bz;
            if (ACC) v += C[(size_t)(row + r) * ldc + col];
            C[(size_t)(row + r) * ldc + col] = v;
          }
        }
      }
    }
  }
}

// ---------------- causal conv (K=4) + SiLU + fused gate projection ----------------
__global__ __launch_bounds__(256) void conv_silu_kernel(
    const __bf16* __restrict__ up, const float* __restrict__ cw,
    const float* __restrict__ cb, const float* __restrict__ wg,
    const float* __restrict__ bif, __bf16* __restrict__ xc,
    float* __restrict__ gates) {
  int tid = threadIdx.x;
  int wv = tid >> 6, lane = tid & 63;
  int row = blockIdx.x * 4 + wv;
  int c8 = lane * 8;
  int t = row & (S - 1);
  float acc[8];
  *(float4*)&acc[0] = *(const float4*)(cb + c8);
  *(float4*)&acc[4] = *(const float4*)(cb + c8 + 4);
  float xm[8];
  #pragma unroll
  for (int j = 0; j < 4; ++j) {
    int tt = t - 3 + j;
    if (tt >= 0) {
      bf16x8 xv = *(const bf16x8*)(up + (size_t)(row - 3 + j) * 1024 + c8);
      float4 w0 = *(const float4*)(cw + j * 512 + c8);
      float4 w1 = *(const float4*)(cw + j * 512 + c8 + 4);
      acc[0] += w0.x * (float)xv[0]; acc[1] += w0.y * (float)xv[1];
      acc[2] += w0.z * (float)xv[2]; acc[3] += w0.w * (float)xv[3];
      acc[4] += w1.x * (float)xv[4]; acc[5] += w1.y * (float)xv[5];
      acc[6] += w1.z * (float)xv[6]; acc[7] += w1.w * (float)xv[7];
      if (j == 3) {
        #pragma unroll
        for (int m = 0; m < 8; ++m) xm[m] = (float)xv[m];
      }
    }
  }
  bf16x8 o;
  float xcs[8];
  #pragma unroll
  for (int m = 0; m < 8; ++m) {
    float sg = 1.f / (1.f + __expf(-acc[m]));
    xcs[m] = acc[m] * sg;
    o[m] = (__bf16)xcs[m];
  }
  *(bf16x8*)(xc + (size_t)row * 512 + c8) = o;
  const float* w1 = wg + (size_t)c8 * 8;
  const float* w2 = wg + 4096 + (size_t)c8 * 8;
  float part[8] = {0, 0, 0, 0, 0, 0, 0, 0};
  #pragma unroll
  for (int m = 0; m < 8; ++m) {
    const float* a = w1 + m * 8;
    const float* b = w2 + m * 8;
    #pragma unroll
    for (int j = 0; j < 8; ++j) part[j] += xcs[m] * a[j] + xm[m] * b[j];
  }
  #pragma unroll
  for (int j = 0; j < 8; ++j) part[j] = wave_sum(part[j]);
  if (lane < 8) gates[(size_t)row * 8 + lane] = part[lane] + bif[lane];
}

// ---------------- per-(b,h) gate scan: one wave ----------------
__global__ __launch_bounds__(64) void scan_kernel(
    const float* __restrict__ gates, float* __restrict__ gout,
    float* __restrict__ Mout, float* __restrict__ NFout) {
  int bh = blockIdx.x;
  int bb = bh >> 2, hh = bh & 3;
  int lane = threadIdx.x;
  float ip[16], pf[16];
  #pragma unroll
  for (int i = 0; i < 16; ++i) {
    int t = lane * 16 + i;
    const float* grow = gates + ((size_t)(bb * S + t)) * 8;
    ip[i] = grow[hh];
    float fp = grow[4 + hh];
    float lf = fminf(fp, 0.f) - log1pf(__expf(-fabsf(fp)));
    pf[i] = (i == 0) ? lf : pf[i - 1] + lf;
  }
  float T = pf[15];
  float inc = T;
  #pragma unroll
  for (int off = 1; off < 64; off <<= 1) {
    float v = __shfl_up(inc, off, 64);
    if (lane >= off) inc += v;
  }
  float excl = inc - T;
  float F[16], g[16], pm[16];
  #pragma unroll
  for (int i = 0; i < 16; ++i) {
    F[i] = excl + pf[i];
    g[i] = ip[i] - F[i];
    pm[i] = (i == 0) ? g[0] : fmaxf(pm[i - 1], g[i]);
  }
  float Mx = pm[15];
  float incm = Mx;
  #pragma unroll
  for (int off = 1; off < 64; off <<= 1) {
    float v = __shfl_up(incm, off, 64);
    if (lane >= off) incm = fmaxf(incm, v);
  }
  float em = __shfl_up(incm, 1, 64);
  if (lane == 0) em = -3.4e38f;
  #pragma unroll
  for (int i = 0; i < 16; ++i) {
    int t = lane * 16 + i;
    size_t o = (size_t)bh * S + t;
    float M = fmaxf(em, pm[i]);
    gout[o] = g[i];
    Mout[o] = M;
    NFout[o] = __expf(-F[i] - M);
  }
}

// ---------------- MFMA mLSTM attention + fused GroupNorm/skip/silu-gate ----------------
// grid (bh=32, px=8): all px-blocks sharing one (b,h)'s K/V stream land on ONE XCD.
__global__ __launch_bounds__(256, 1) void attn_kernel(
    const __bf16* __restrict__ qk, const __bf16* __restrict__ vT,
    const float* __restrict__ gbuf, const float* __restrict__ Mbuf,
    const float* __restrict__ NFbuf,
    const float* __restrict__ gn_g, const float* __restrict__ gn_b,
    const float* __restrict__ skip,
    const __bf16* __restrict__ xc, const __bf16* __restrict__ up,
    __bf16* __restrict__ hd) {
  __shared__ __bf16 Ks[64][136];
  __shared__ __bf16 Vs[128][72];
  __shared__ __bf16 plds[4][2][16][72];
  __shared__ float gls[64];
  __shared__ float glds[128], blds[128], slds[128];
  int px = blockIdx.y, bh = blockIdx.x;
  int tqA = px, tqB = 15 - px;
  int bb = bh >> 2, hh = bh & 3;
  int tid = threadIdx.x;
  int wv = tid >> 6, lane = tid & 63;
  int lg = lane >> 4, li = lane & 15;
  int tbA = tqA * 64 + wv * 16;
  int tbB = tqB * 64 + wv * 16;
  const float scale = 0.08838834764831845f;

  if (tid < 128) {
    glds[tid] = gn_g[hh * 128 + tid];
    blds[tid] = gn_b[hh * 128 + tid];
    slds[tid] = skip[hh * 128 + tid];
  }

  bf16x8 aqA[4], aqB[4];
  {
    const __bf16* qpA = qk + ((size_t)(bb * S + tbA + li)) * 1024 + hh * 128 + lg * 8;
    const __bf16* qpB = qk + ((size_t)(bb * S + tbB + li)) * 1024 + hh * 128 + lg * 8;
    #pragma unroll
    for (int cd = 0; cd < 4; ++cd) {
      aqA[cd] = *(const bf16x8*)(qpA + cd * 32);
      aqB[cd] = *(const bf16x8*)(qpB + cd * 32);
    }
  }
  float mlA[4], nfA[4], mlB[4], nfB[4];
  #pragma unroll
  for (int r = 0; r < 4; ++r) {
    mlA[r] = Mbuf[(size_t)bh * S + tbA + lg * 4 + r];
    nfA[r] = NFbuf[(size_t)bh * S + tbA + lg * 4 + r];
    mlB[r] = Mbuf[(size_t)bh * S + tbB + lg * 4 + r];
    nfB[r] = NFbuf[(size_t)bh * S + tbB + lg * 4 + r];
  }

  floatx4 oA[8], oB[8];
  #pragma unroll
  for (int df = 0; df < 8; ++df) { oA[df] = (floatx4)(0.f); oB[df] = (floatx4)(0.f); }
  float rsA[4] = {0, 0, 0, 0}, rsB[4] = {0, 0, 0, 0};

  int krow = tid >> 3, kcol = tid & 7;
  bf16x8 kreg[4], vreg[4];
  float greg = 0.f;
  auto preload = [&](int st) {
    int s0 = st * 64;
    const __bf16* kp = qk + ((size_t)(bb * S + s0 + krow)) * 1024 + 512 + hh * 128;
    kreg[0] = *(const bf16x8*)(kp + kcol * 8);
    kreg[1] = *(const bf16x8*)(kp + (size_t)32 * 1024 + kcol * 8);
    kreg[2] = *(const bf16x8*)(kp + 64 + kcol * 8);
    kreg[3] = *(const bf16x8*)(kp + (size_t)32 * 1024 + 64 + kcol * 8);
    #pragma unroll
    for (int i = 0; i < 4; ++i)
      vreg[i] = *(const bf16x8*)(vT + ((size_t)(bh * 128 + krow + i * 32)) * 1024 + s0 + kcol * 8);
    if (tid < 64) greg = gbuf[(size_t)bh * S + s0 + tid];
  };
  preload(0);

  for (int st = 0; st <= tqB; ++st) {
    __syncthreads();
    *(bf16x8*)&Ks[krow][kcol * 8] = kreg[0];
    *(bf16x8*)&Ks[krow + 32][kcol * 8] = kreg[1];
    *(bf16x8*)&Ks[krow][64 + kcol * 8] = kreg[2];
    *(bf16x8*)&Ks[krow + 32][64 + kcol * 8] = kreg[3];
    #pragma unroll
    for (int i = 0; i < 4; ++i) *(bf16x8*)&Vs[krow + i * 32][kcol * 8] = vreg[i];
    if (tid < 64) gls[tid] = greg;
    __syncthreads();
    if (st < tqB) preload(st + 1);

    int s0 = st * 64;
    bool actA = (st <= tqA);
    #pragma unroll
    for (int ns = 0; ns < 4; ++ns) {
      bf16x8 bk0 = *(const bf16x8*)&Ks[ns * 16 + li][lg * 8];
      bf16x8 bk1 = *(const bf16x8*)&Ks[ns * 16 + li][32 + lg * 8];
      bf16x8 bk2 = *(const bf16x8*)&Ks[ns * 16 + li][64 + lg * 8];
      bf16x8 bk3 = *(const bf16x8*)&Ks[ns * 16 + li][96 + lg * 8];
      int s = s0 + ns * 16 + li;
      float gv = gls[ns * 16 + li];
      if (actA) {
        floatx4 pa = (floatx4)(0.f);
        pa = __builtin_amdgcn_mfma_f32_16x16x32_bf16(aqA[0], bk0, pa, 0, 0, 0);
        pa = __builtin_amdgcn_mfma_f32_16x16x32_bf16(aqA[1], bk1, pa, 0, 0, 0);
        pa = __builtin_amdgcn_mfma_f32_16x16x32_bf16(aqA[2], bk2, pa, 0, 0, 0);
        pa = __builtin_amdgcn_mfma_f32_16x16x32_bf16(aqA[3], bk3, pa, 0, 0, 0);
        #pragma unroll
        for (int r = 0; r < 4; ++r) {
          int t = tbA + lg * 4 + r;
          float val = pa[r] * scale * __expf(gv - mlA[r]);
          float w = (s <= t) ? val : 0.f;
          rsA[r] += w;
          plds[wv][0][lg * 4 + r][ns * 16 + li] = (__bf16)w;
        }
      }
      {
        floatx4 pb = (floatx4)(0.f);
        pb = __builtin_amdgcn_mfma_f32_16x16x32_bf16(aqB[0], bk0, pb, 0, 0, 0);
        pb = __builtin_amdgcn_mfma_f32_16x16x32_bf16(aqB[1], bk1, pb, 0, 0, 0);
        pb = __builtin_amdgcn_mfma_f32_16x16x32_bf16(aqB[2], bk2, pb, 0, 0, 0);
        pb = __builtin_amdgcn_mfma_f32_16x16x32_bf16(aqB[3], bk3, pb, 0, 0, 0);
        #pragma unroll
        for (int r = 0; r < 4; ++r) {
          int t = tbB + lg * 4 + r;
          float val = pb[r] * scale * __expf(gv - mlB[r]);
          float w = (s <= t) ? val : 0.f;
          rsB[r] += w;
          plds[wv][1][lg * 4 + r][ns * 16 + li] = (__bf16)w;
        }
      }
    }
    bf16x8 apA0, apA1, apB0, apB1;
    if (actA) {
      apA0 = *(const bf16x8*)&plds[wv][0][li][lg * 8];
      apA1 = *(const bf16x8*)&plds[wv][0][li][32 + lg * 8];
    }
    apB0 = *(const bf16x8*)&plds[wv][1][li][lg * 8];
    apB1 = *(const bf16x8*)&plds[wv][1][li][32 + lg * 8];
    #pragma unroll
    for (int df = 0; df < 8; ++df) {
      bf16x8 bv0 = *(const bf16x8*)&Vs[df * 16 + li][lg * 8];
      bf16x8 bv1 = *(const bf16x8*)&Vs[df * 16 + li][32 + lg * 8];
      if (actA) {
        oA[df] = __builtin_amdgcn_mfma_f32_16x16x32_bf16(apA0, bv0, oA[df], 0, 0, 0);
        oA[df] = __builtin_amdgcn_mfma_f32_16x16x32_bf16(apA1, bv1, oA[df], 0, 0, 0);
      }
      oB[df] = __builtin_amdgcn_mfma_f32_16x16x32_bf16(apB0, bv0, oB[df], 0, 0, 0);
      oB[df] = __builtin_amdgcn_mfma_f32_16x16x32_bf16(apB1, bv1, oB[df], 0, 0, 0);
    }
  }
  #pragma unroll
  for (int r = 0; r < 4; ++r) {
    float a = rsA[r], b = rsB[r];
    a += __shfl_xor(a, 1, 64); a += __shfl_xor(a, 2, 64);
    a += __shfl_xor(a, 4, 64); a += __shfl_xor(a, 8, 64);
    b += __shfl_xor(b, 1, 64); b += __shfl_xor(b, 2, 64);
    b += __shfl_xor(b, 4, 64); b += __shfl_xor(b, 8, 64);
    rsA[r] = a; rsB[r] = b;
  }
  #pragma unroll
  for (int tile = 0; tile < 2; ++tile) {
    int tb = tile == 0 ? tbA : tbB;
    #pragma unroll
    for (int r = 0; r < 4; ++r) {
      float rs = tile == 0 ? rsA[r] : rsB[r];
      float nf = tile == 0 ? nfA[r] : nfB[r];
      float inv = 1.f / (fmaxf(fabsf(rs), nf) + 1e-6f);
      float v8[8], s1 = 0.f, s2 = 0.f;
      #pragma unroll
      for (int df = 0; df < 8; ++df) {
        float v = (tile == 0 ? oA[df][r] : oB[df][r]) * inv;
        v8[df] = v;
        s1 += v;
        s2 += v * v;
      }
      s1 += __shfl_xor(s1, 1, 64); s1 += __shfl_xor(s1, 2, 64);
      s1 += __shfl_xor(s1, 4, 64); s1 += __shfl_xor(s1, 8, 64);
      s2 += __shfl_xor(s2, 1, 64); s2 += __shfl_xor(s2, 2, 64);
      s2 += __shfl_xor(s2, 4, 64); s2 += __shfl_xor(s2, 8, 64);
      float mu = s1 * (1.f / 128.f);
      float var = s2 * (1.f / 128.f) - mu * mu;
      float rq = rsqrtf(var + 1e-5f);
      int t = tb + lg * 4 + r;
      const __bf16* xr = xc + ((size_t)(bb * S + t)) * 512 + hh * 128 + li;
      const __bf16* zr = up + ((size_t)(bb * S + t)) * 1024 + 512 + hh * 128 + li;
      __bf16* od = hd + ((size_t)(bb * S + t)) * 512 + hh * 128 + li;
      #pragma unroll
      for (int df = 0; df < 8; ++df) {
        int c = df * 16 + li;
        float ln = (v8[df] - mu) * rq * glds[c] + blds[c];
        float val = ln + slds[c] * (float)xr[df * 16];
        float z = (float)zr[df * 16];
        float sg = 1.f / (1.f + __expf(-z));
        od[df * 16] = (__bf16)(val * (z * sg));
      }
    }
  }
}

// ---------------- final LN + head ----------------
__global__ __launch_bounds__(256) void final_kernel(
    const float* __restrict__ h, const float* __restrict__ g,
    const float* __restrict__ b, const float* __restrict__ Wf,
    const float* __restrict__ bf, float* __restrict__ out) {
  int bb = blockIdx.x, tid = threadIdx.x;
  size_t row = (size_t)(bb * S + S - 1) * 256;
  __shared__ float red[4];
  float v = h[row + tid];
  float s = wave_sum(v);
  int wid = tid >> 6, lane = tid & 63;
  if (lane == 0) red[wid] = s;
  __syncthreads();
  float mu = (red[0] + red[1] + red[2] + red[3]) * (1.f / 256.f);
  __syncthreads();
  float d = v - mu;
  float s2 = wave_sum(d * d);
  if (lane == 0) red[wid] = s2;
  __syncthreads();
  float var = (red[0] + red[1] + red[2] + red[3]) * (1.f / 256.f);
  float rs = rsqrtf(var + 1e-5f);
  float ln = d * rs * g[tid] + b[tid];
  float p = ln * Wf[tid];
  float psum = wave_sum(p);
  __syncthreads();
  if (lane == 0) red[wid] = psum;
  __syncthreads();
  if (tid == 0) out[bb] = red[0] + red[1] + red[2] + red[3] + bf[0];
}

extern "C" void kernel_launch(void* const* d_in, const int* in_sizes, int n_in,
                              void* d_out, int out_size, void* d_ws, size_t ws_size,
                              hipStream_t stream) {
  const float* x      = (const float*)d_in[0];
  const float* tf     = (const float*)d_in[1];
  const float* Wp     = (const float*)d_in[2];
  const float* bp     = (const float*)d_in[3];
  const float* ln_g   = (const float*)d_in[4];
  const float* ln_b   = (const float*)d_in[5];
  const float* Wup    = (const float*)d_in[6];
  const float* bup    = (const float*)d_in[7];
  const float* conv_w = (const float*)d_in[8];
  const float* conv_b = (const float*)d_in[9];
  const float* Wq     = (const float*)d_in[10];
  const float* Wk     = (const float*)d_in[11];
  const float* Wv     = (const float*)d_in[12];
  const float* Wif    = (const float*)d_in[13];
  const float* bif    = (const float*)d_in[14];
  const float* gn_g   = (const float*)d_in[15];
  const float* gn_b   = (const float*)d_in[16];
  const float* skip   = (const float*)d_in[17];
  const float* Wdown  = (const float*)d_in[18];
  const float* bdown  = (const float*)d_in[19];
  const float* lnf_g  = (const float*)d_in[20];
  const float* lnf_b  = (const float*)d_in[21];
  const float* Wf     = (const float*)d_in[22];
  const float* bf     = (const float*)d_in[23];
  float* out = (float*)d_out;

  float* h     = (float*)d_ws;              // 2,097,152 f32
  float* gates = h + 2097152;               // 65,536 f32
  float* gbuf  = gates + 65536;             // 32,768
  float* Mbuf  = gbuf + 32768;              // 32,768
  float* NFbuf = Mbuf + 32768;              // 32,768
  float* wgbuf = NFbuf + 32768;             // 32,768
  __bf16* hn   = (__bf16*)(wgbuf + 32768);  // 2,097,152 bf16
  __bf16* up   = hn + 2097152;              // 8,388,608
  __bf16* xc   = up + 8388608;              // 4,194,304
  __bf16* qk   = xc + 4194304;              // 8,388,608
  __bf16* vT   = qk + 8388608;              // 4,194,304
  __bf16* hd   = vT + 4194304;              // 4,194,304
  __bf16* WupT   = hd + 4194304;            // 1,048,576
  __bf16* WqkT   = WupT + 1048576;          // 2,097,152
  __bf16* WvT    = WqkT + 2097152;          // 1,048,576
  __bf16* WdownT = WvT + 1048576;           // 524,288

  wtrans_kernel<<<4608, 256, 0, stream>>>(Wup, Wq, Wk, Wv, Wdown,
                                          WupT, WqkT, WvT, WdownT);
  wgprep_kernel<<<1024, 256, 0, stream>>>(Wq, Wk, Wv, Wif, wgbuf);
  embed_kernel<<<8192, 256, 0, stream>>>(x, tf, Wp, bp, ln_g, ln_b, h, hn);
  for (int l = 0; l < NLAYER; ++l) {
    if (l > 0)
      ln256_kernel<<<8192, 256, 0, stream>>>(h, ln_g + l * 256, ln_b + l * 256, hn);
    hgemm<1, 0><<<dim3(64, 8), 256, 0, stream>>>(
        hn, 256, WupT + (size_t)l * 262144, 256, bup + l * 1024, up, 1024);
    conv_silu_kernel<<<2048, 256, 0, stream>>>(up, conv_w + l * 2048, conv_b + l * 512,
                                               wgbuf + l * 8192, bif + l * 8, xc, gates);
    scan_kernel<<<32, 64, 0, stream>>>(gates, gbuf, Mbuf, NFbuf);
    hgemm<1, 0><<<dim3(64, 8), 256, 0, stream>>>(
        xc, 512, WqkT + (size_t)l * 524288, 512, nullptr, qk, 1024);
    hgemm<2, 0><<<dim3(64, 4), 256, 0, stream>>>(
        up, 1024, WvT + (size_t)l * 262144, 512, nullptr, vT, 0);
    attn_kernel<<<dim3(32, 8), 256, 0, stream>>>(
        qk, vT, gbuf, Mbuf, NFbuf, gn_g + l * 512, gn_b + l * 512, skip + l * 512,
        xc, up, hd);
    hgemm<0, 1><<<dim3(64, 2), 256, 0, stream>>>(
        hd, 512, WdownT + (size_t)l * 131072, 512, bdown + l * 256, h, 256);
  }
  final_kernel<<<8, 256, 0, stream>>>(h, lnf_g, lnf_b, Wf, bf, out);
}

// Round 12
// 674.126 us; speedup vs baseline: 1.1610x; 1.0805x over previous
//
#include <hip/hip_runtime.h>
#include <hip/hip_bf16.h>
#include <math.h>

#define S 1024
#define NLAYER 4

typedef __bf16 bf16x8 __attribute__((ext_vector_type(8)));
typedef float floatx4 __attribute__((ext_vector_type(4)));

__device__ __forceinline__ float wave_sum(float v) {
  #pragma unroll
  for (int off = 32; off > 0; off >>= 1) v += __shfl_xor(v, off, 64);
  return v;
}

// ---------------- combined prep: weight transpose + Wg precompute + embed/LN ----------------
__device__ __forceinline__ void wtrans_body(
    int bid, const float* Wup, const float* Wq, const float* Wk, const float* Wv,
    const float* Wdown, __bf16* WupT, __bf16* WqkT, __bf16* WvT, __bf16* WdownT) {
  __shared__ float T[32][33];
  int layer = bid / 1152, rr = bid % 1152;
  const float* src; __bf16* dst; int K, N, tile;
  if (rr < 256)       { src = Wup   + layer * 262144; dst = WupT  + layer * 262144;          K = 256; N = 1024; tile = rr; }
  else if (rr < 512)  { src = Wq    + layer * 262144; dst = WqkT  + layer * 524288;          K = 512; N = 512;  tile = rr - 256; }
  else if (rr < 768)  { src = Wk    + layer * 262144; dst = WqkT  + layer * 524288 + 262144; K = 512; N = 512;  tile = rr - 512; }
  else if (rr < 1024) { src = Wv    + layer * 262144; dst = WvT   + layer * 262144;          K = 512; N = 512;  tile = rr - 768; }
  else                { src = Wdown + layer * 131072; dst = WdownT + layer * 131072;         K = 512; N = 256;  tile = rr - 1024; }
  int ntn = N >> 5;
  int tk = tile / ntn, tn = tile % ntn;
  int tid = threadIdx.x;
  int r = tid >> 3, c4 = (tid & 7) * 4;
  float4 v = *(const float4*)(src + (size_t)(tk * 32 + r) * N + tn * 32 + c4);
  T[c4 + 0][r] = v.x; T[c4 + 1][r] = v.y; T[c4 + 2][r] = v.z; T[c4 + 3][r] = v.w;
  __syncthreads();
  __bf16 o[4];
  #pragma unroll
  for (int j = 0; j < 4; ++j) o[j] = (__bf16)T[r][c4 + j];
  *(uint2*)(dst + (size_t)(tn * 32 + r) * K + tk * 32 + c4) = *(uint2*)o;
}

__device__ __forceinline__ void wgprep_body(
    int bid, const float* Wq, const float* Wk, const float* Wv,
    const float* Wif, float* wg) {
  int l = bid >> 8;
  int rem = bid & 255;
  int sel = rem >> 7;
  int kg = rem & 127;
  int tid = threadIdx.x;
  int wv = tid >> 6, lane = tid & 63;
  int k = kg * 4 + wv;
  const float* wif = Wif + (size_t)l * 1536 * 8;
  float part[8] = {0, 0, 0, 0, 0, 0, 0, 0};
  if (sel == 0) {
    const float* qr = Wq + (size_t)l * 262144 + (size_t)k * 512;
    const float* kr = Wk + (size_t)l * 262144 + (size_t)k * 512;
    #pragma unroll
    for (int i = 0; i < 8; ++i) {
      int n = lane + i * 64;
      float qv = qr[n], kv = kr[n];
      const float* wq8 = wif + (size_t)n * 8;
      const float* wk8 = wif + (size_t)(512 + n) * 8;
      #pragma unroll
      for (int j = 0; j < 8; ++j) part[j] += qv * wq8[j] + kv * wk8[j];
    }
  } else {
    const float* vr = Wv + (size_t)l * 262144 + (size_t)k * 512;
    #pragma unroll
    for (int i = 0; i < 8; ++i) {
      int n = lane + i * 64;
      float vv = vr[n];
      const float* wv8 = wif + (size_t)(1024 + n) * 8;
      #pragma unroll
      for (int j = 0; j < 8; ++j) part[j] += vv * wv8[j];
    }
  }
  #pragma unroll
  for (int j = 0; j < 8; ++j) part[j] = wave_sum(part[j]);
  if (lane < 8) wg[(size_t)l * 8192 + sel * 4096 + (size_t)k * 8 + lane] = part[lane];
}

__device__ __forceinline__ void embed_body(
    int row, const float* x, const float* tf, const float* Wp, const float* bp,
    const float* g, const float* b, float* h, __bf16* hn) {
  int n = threadIdx.x;
  float xv = x[row];
  const float* t4 = tf + (size_t)row * 4;
  float acc = bp[n] + xv * Wp[n];
  acc += t4[0] * Wp[256 + n];
  acc += t4[1] * Wp[512 + n];
  acc += t4[2] * Wp[768 + n];
  acc += t4[3] * Wp[1024 + n];
  h[(size_t)row * 256 + n] = acc;
  __shared__ float red[4];
  int wid = n >> 6, lane = n & 63;
  float s = wave_sum(acc);
  if (lane == 0) red[wid] = s;
  __syncthreads();
  float mu = (red[0] + red[1] + red[2] + red[3]) * (1.f / 256.f);
  __syncthreads();
  float d = acc - mu;
  float s2 = wave_sum(d * d);
  if (lane == 0) red[wid] = s2;
  __syncthreads();
  float var = (red[0] + red[1] + red[2] + red[3]) * (1.f / 256.f);
  float rs = rsqrtf(var + 1e-5f);
  hn[(size_t)row * 256 + n] = (__bf16)(d * rs * g[n] + b[n]);
}

__global__ __launch_bounds__(256) void prep_kernel(
    const float* __restrict__ x, const float* __restrict__ tf,
    const float* __restrict__ Wp, const float* __restrict__ bp,
    const float* __restrict__ ln_g, const float* __restrict__ ln_b,
    const float* __restrict__ Wup, const float* __restrict__ Wq,
    const float* __restrict__ Wk, const float* __restrict__ Wv,
    const float* __restrict__ Wdown, const float* __restrict__ Wif,
    __bf16* __restrict__ WupT, __bf16* __restrict__ WqkT,
    __bf16* __restrict__ WvT, __bf16* __restrict__ WdownT,
    float* __restrict__ wg, float* __restrict__ h, __bf16* __restrict__ hn) {
  int bid = blockIdx.x;
  if (bid < 4608) {
    wtrans_body(bid, Wup, Wq, Wk, Wv, Wdown, WupT, WqkT, WvT, WdownT);
  } else if (bid < 4608 + 1024) {
    wgprep_body(bid - 4608, Wq, Wk, Wv, Wif, wg);
  } else {
    embed_body(bid - 5632, x, tf, Wp, bp, ln_g, ln_b, h, hn);
  }
}

// ---------------- LayerNorm over 256, fp32 in -> bf16 out ----------------
__global__ __launch_bounds__(256) void ln256_kernel(
    const float* __restrict__ x, const float* __restrict__ g,
    const float* __restrict__ b, __bf16* __restrict__ y) {
  int row = blockIdx.x, tid = threadIdx.x;
  __shared__ float red[4];
  float v = x[(size_t)row * 256 + tid];
  float s = wave_sum(v);
  int wid = tid >> 6, lane = tid & 63;
  if (lane == 0) red[wid] = s;
  __syncthreads();
  float mu = (red[0] + red[1] + red[2] + red[3]) * (1.f / 256.f);
  __syncthreads();
  float d = v - mu;
  float s2 = wave_sum(d * d);
  if (lane == 0) red[wid] = s2;
  __syncthreads();
  float var = (red[0] + red[1] + red[2] + red[3]) * (1.f / 256.f);
  float rs = rsqrtf(var + 1e-5f);
  y[(size_t)row * 256 + tid] = (__bf16)(d * rs * g[tid] + b[tid]);
}

// ---------------- bf16 MFMA GEMM body: TM x 128 tile, register prefetch ----------------
// TM in {128, 64}. MODE 0: f32 out (+ACC), MODE 1: bf16 via LDS coalesced (TM=128 only),
// MODE 2: bf16 scattered into vT.
template <int TM, int MODE, int ACC>
__device__ __forceinline__ void hgemm_body(
    char* smem_raw,
    const __bf16* __restrict__ A, int lda,
    const __bf16* __restrict__ BT, int Kdim,
    const float* __restrict__ bias,
    void* __restrict__ Cout, int ldc, int bxi, int byi) {
  auto As = (__bf16(*)[40])smem_raw;
  auto Bs = (__bf16(*)[40])(smem_raw + (size_t)TM * 80);
  int tid = threadIdx.x;
  int bm = bxi * TM, bn = byi * 128;
  int wid = tid >> 6, lane = tid & 63;
  int wr = wid >> 1, wc = wid & 1;
  int lg = lane >> 4, li = lane & 15;
  constexpr int MI = TM / 32;        // row-fragments per wave
  constexpr int WROW = TM / 2;       // rows per wave-row-group
  floatx4 acc[MI][4];
  #pragma unroll
  for (int i = 0; i < MI; ++i)
    #pragma unroll
    for (int j = 0; j < 4; ++j) acc[i][j] = (floatx4)(0.f);

  int arow = tid >> 2, aseg = tid & 3;
  bf16x8 pa0, pa1, pb0, pb1;
  auto pre = [&](int k0) {
    pa0 = *(const bf16x8*)(A + (size_t)(bm + arow) * lda + k0 + aseg * 8);
    if constexpr (TM == 128)
      pa1 = *(const bf16x8*)(A + (size_t)(bm + arow + 64) * lda + k0 + aseg * 8);
    pb0 = *(const bf16x8*)(BT + (size_t)(bn + arow) * Kdim + k0 + aseg * 8);
    pb1 = *(const bf16x8*)(BT + (size_t)(bn + arow + 64) * Kdim + k0 + aseg * 8);
  };
  pre(0);
  for (int k0 = 0; k0 < Kdim; k0 += 32) {
    __syncthreads();
    if constexpr (TM == 128) {
      *(bf16x8*)&As[arow][aseg * 8] = pa0;
      *(bf16x8*)&As[arow + 64][aseg * 8] = pa1;
    } else {
      *(bf16x8*)&As[arow][aseg * 8] = pa0;
    }
    *(bf16x8*)&Bs[arow][aseg * 8] = pb0;
    *(bf16x8*)&Bs[arow + 64][aseg * 8] = pb1;
    __syncthreads();
    if (k0 + 32 < Kdim) pre(k0 + 32);
    bf16x8 af[MI], bfr[4];
    #pragma unroll
    for (int mi = 0; mi < MI; ++mi)
      af[mi] = *(const bf16x8*)&As[wr * WROW + mi * 16 + li][lg * 8];
    #pragma unroll
    for (int ni = 0; ni < 4; ++ni)
      bfr[ni] = *(const bf16x8*)&Bs[wc * 64 + ni * 16 + li][lg * 8];
    #pragma unroll
    for (int mi = 0; mi < MI; ++mi)
      #pragma unroll
      for (int ni = 0; ni < 4; ++ni)
        acc[mi][ni] = __builtin_amdgcn_mfma_f32_16x16x32_bf16(af[mi], bfr[ni], acc[mi][ni], 0, 0, 0);
  }
  if constexpr (MODE == 1) {
    // LDS-transposed epilogue (TM=128): 32x128 chunks, then 16B coalesced stores.
    __bf16* eb = (__bf16*)smem_raw;
    const int PITCH = 136;
    __bf16* C = (__bf16*)Cout;
    #pragma unroll
    for (int mi = 0; mi < MI; ++mi) {
      __syncthreads();
      #pragma unroll
      for (int ni = 0; ni < 4; ++ni) {
        int col = wc * 64 + ni * 16 + li;
        float bz = bias ? bias[bn + col] : 0.f;
        #pragma unroll
        for (int r = 0; r < 4; ++r) {
          int lr = wr * 16 + lg * 4 + r;
          eb[lr * PITCH + col] = (__bf16)(acc[mi][ni][r] + bz);
        }
      }
      __syncthreads();
      #pragma unroll
      for (int i = 0; i < 2; ++i) {
        int lr = (tid >> 4) + i * 16;
        int c8 = (tid & 15) * 8;
        bf16x8 v = *(const bf16x8*)&eb[lr * PITCH + c8];
        int row_g = bm + (lr >> 4) * 64 + mi * 16 + (lr & 15);
        *(bf16x8*)(C + (size_t)row_g * ldc + bn + c8) = v;
      }
    }
  } else {
    #pragma unroll
    for (int mi = 0; mi < MI; ++mi) {
      int row = bm + wr * WROW + mi * 16 + lg * 4;
      #pragma unroll
      for (int ni = 0; ni < 4; ++ni) {
        int col = bn + wc * 64 + ni * 16 + li;
        if constexpr (MODE == 2) {
          __bf16 o4[4];
          #pragma unroll
          for (int r = 0; r < 4; ++r) o4[r] = (__bf16)acc[mi][ni][r];
          __bf16* vt = (__bf16*)Cout;
          size_t off = ((size_t)((row >> 10) * 4 + (col >> 7)) * 128 + (col & 127)) * 1024 + (row & 1023);
          *(uint2*)(vt + off) = *(uint2*)o4;
        } else {
          float bz = bias ? bias[col] : 0.f;
          float* C = (float*)Cout;
          #pragma unroll
          for (int r = 0; r < 4; ++r) {
            float v = acc[mi][ni][r] + bz;
            if (ACC) v += C[(size_t)(row + r) * ldc + col];
            C[(size_t)(row + r) * ldc + col] = v;
          }
        }
      }
    }
  }
}

template <int TM, int MODE, int ACC>
__global__ __launch_bounds__(256) void hgemm(
    const __bf16* __restrict__ A, int lda,
    const __bf16* __restrict__ BT, int Kdim,
    const float* __restrict__ bias,
    void* __restrict__ Cout, int ldc) {
  extern __shared__ char smem[];
  hgemm_body<TM, MODE, ACC>(smem, A, lda, BT, Kdim, bias, Cout, ldc,
                            blockIdx.x, blockIdx.y);
}

// Merged QK + V GEMM: grid (64, 16). by<8 -> qk (128-tile); by>=8 -> vT (64-tile).
__global__ __launch_bounds__(256) void qkv_kernel(
    const __bf16* __restrict__ xc, const __bf16* __restrict__ WqkT,
    __bf16* __restrict__ qk, const __bf16* __restrict__ up,
    const __bf16* __restrict__ WvT, __bf16* __restrict__ vT) {
  extern __shared__ char smem[];
  if (blockIdx.y < 8) {
    hgemm_body<128, 1, 0>(smem, xc, 512, WqkT, 512, nullptr, qk, 1024,
                          blockIdx.x, blockIdx.y);
  } else {
    int j = blockIdx.y - 8;
    hgemm_body<64, 2, 0>(smem, up, 1024, WvT, 512, nullptr, vT, 0,
                         blockIdx.x * 2 + (j & 1), j >> 1);
  }
}

// ---------------- causal conv (K=4) + SiLU + fused gate projection ----------------
__global__ __launch_bounds__(256) void conv_silu_kernel(
    const __bf16* __restrict__ up, const float* __restrict__ cw,
    const float* __restrict__ cb, const float* __restrict__ wg,
    const float* __restrict__ bif, __bf16* __restrict__ xc,
    float* __restrict__ gates) {
  int tid = threadIdx.x;
  int wv = tid >> 6, lane = tid & 63;
  int row = blockIdx.x * 4 + wv;
  int c8 = lane * 8;
  int t = row & (S - 1);
  float acc[8];
  *(float4*)&acc[0] = *(const float4*)(cb + c8);
  *(float4*)&acc[4] = *(const float4*)(cb + c8 + 4);
  float xm[8];
  #pragma unroll
  for (int j = 0; j < 4; ++j) {
    int tt = t - 3 + j;
    if (tt >= 0) {
      bf16x8 xv = *(const bf16x8*)(up + (size_t)(row - 3 + j) * 1024 + c8);
      float4 w0 = *(const float4*)(cw + j * 512 + c8);
      float4 w1 = *(const float4*)(cw + j * 512 + c8 + 4);
      acc[0] += w0.x * (float)xv[0]; acc[1] += w0.y * (float)xv[1];
      acc[2] += w0.z * (float)xv[2]; acc[3] += w0.w * (float)xv[3];
      acc[4] += w1.x * (float)xv[4]; acc[5] += w1.y * (float)xv[5];
      acc[6] += w1.z * (float)xv[6]; acc[7] += w1.w * (float)xv[7];
      if (j == 3) {
        #pragma unroll
        for (int m = 0; m < 8; ++m) xm[m] = (float)xv[m];
      }
    }
  }
  bf16x8 o;
  float xcs[8];
  #pragma unroll
  for (int m = 0; m < 8; ++m) {
    float sg = 1.f / (1.f + __expf(-acc[m]));
    xcs[m] = acc[m] * sg;
    o[m] = (__bf16)xcs[m];
  }
  *(bf16x8*)(xc + (size_t)row * 512 + c8) = o;
  const float* w1 = wg + (size_t)c8 * 8;
  const float* w2 = wg + 4096 + (size_t)c8 * 8;
  float part[8] = {0, 0, 0, 0, 0, 0, 0, 0};
  #pragma unroll
  for (int m = 0; m < 8; ++m) {
    const float* a = w1 + m * 8;
    const float* b = w2 + m * 8;
    #pragma unroll
    for (int j = 0; j < 8; ++j) part[j] += xcs[m] * a[j] + xm[m] * b[j];
  }
  #pragma unroll
  for (int j = 0; j < 8; ++j) part[j] = wave_sum(part[j]);
  if (lane < 8) gates[(size_t)row * 8 + lane] = part[lane] + bif[lane];
}

// ---------------- per-(b,h) gate scan: one wave ----------------
__global__ __launch_bounds__(64) void scan_kernel(
    const float* __restrict__ gates, float* __restrict__ gout,
    float* __restrict__ Mout, float* __restrict__ NFout) {
  int bh = blockIdx.x;
  int bb = bh >> 2, hh = bh & 3;
  int lane = threadIdx.x;
  float ip[16], pf[16];
  #pragma unroll
  for (int i = 0; i < 16; ++i) {
    int t = lane * 16 + i;
    const float* grow = gates + ((size_t)(bb * S + t)) * 8;
    ip[i] = grow[hh];
    float fp = grow[4 + hh];
    float lf = fminf(fp, 0.f) - log1pf(__expf(-fabsf(fp)));
    pf[i] = (i == 0) ? lf : pf[i - 1] + lf;
  }
  float T = pf[15];
  float inc = T;
  #pragma unroll
  for (int off = 1; off < 64; off <<= 1) {
    float v = __shfl_up(inc, off, 64);
    if (lane >= off) inc += v;
  }
  float excl = inc - T;
  float F[16], g[16], pm[16];
  #pragma unroll
  for (int i = 0; i < 16; ++i) {
    F[i] = excl + pf[i];
    g[i] = ip[i] - F[i];
    pm[i] = (i == 0) ? g[0] : fmaxf(pm[i - 1], g[i]);
  }
  float Mx = pm[15];
  float incm = Mx;
  #pragma unroll
  for (int off = 1; off < 64; off <<= 1) {
    float v = __shfl_up(incm, off, 64);
    if (lane >= off) incm = fmaxf(incm, v);
  }
  float em = __shfl_up(incm, 1, 64);
  if (lane == 0) em = -3.4e38f;
  #pragma unroll
  for (int i = 0; i < 16; ++i) {
    int t = lane * 16 + i;
    size_t o = (size_t)bh * S + t;
    float M = fmaxf(em, pm[i]);
    gout[o] = g[i];
    Mout[o] = M;
    NFout[o] = __expf(-F[i] - M);
  }
}

// ---------------- MFMA mLSTM attention + fused GroupNorm/skip/silu-gate ----------------
// grid (bh=32, px=8): all px-blocks sharing one (b,h)'s K/V stream land on ONE XCD.
__global__ __launch_bounds__(256, 1) void attn_kernel(
    const __bf16* __restrict__ qk, const __bf16* __restrict__ vT,
    const float* __restrict__ gbuf, const float* __restrict__ Mbuf,
    const float* __restrict__ NFbuf,
    const float* __restrict__ gn_g, const float* __restrict__ gn_b,
    const float* __restrict__ skip,
    const __bf16* __restrict__ xc, const __bf16* __restrict__ up,
    __bf16* __restrict__ hd) {
  __shared__ __bf16 Ks[64][136];
  __shared__ __bf16 Vs[128][72];
  __shared__ __bf16 plds[4][2][16][72];
  __shared__ float gls[64];
  __shared__ float glds[128], blds[128], slds[128];
  int px = blockIdx.y, bh = blockIdx.x;
  int tqA = px, tqB = 15 - px;
  int bb = bh >> 2, hh = bh & 3;
  int tid = threadIdx.x;
  int wv = tid >> 6, lane = tid & 63;
  int lg = lane >> 4, li = lane & 15;
  int tbA = tqA * 64 + wv * 16;
  int tbB = tqB * 64 + wv * 16;
  const float scale = 0.08838834764831845f;

  if (tid < 128) {
    glds[tid] = gn_g[hh * 128 + tid];
    blds[tid] = gn_b[hh * 128 + tid];
    slds[tid] = skip[hh * 128 + tid];
  }

  bf16x8 aqA[4], aqB[4];
  {
    const __bf16* qpA = qk + ((size_t)(bb * S + tbA + li)) * 1024 + hh * 128 + lg * 8;
    const __bf16* qpB = qk + ((size_t)(bb * S + tbB + li)) * 1024 + hh * 128 + lg * 8;
    #pragma unroll
    for (int cd = 0; cd < 4; ++cd) {
      aqA[cd] = *(const bf16x8*)(qpA + cd * 32);
      aqB[cd] = *(const bf16x8*)(qpB + cd * 32);
    }
  }
  float mlA[4], nfA[4], mlB[4], nfB[4];
  #pragma unroll
  for (int r = 0; r < 4; ++r) {
    mlA[r] = Mbuf[(size_t)bh * S + tbA + lg * 4 + r];
    nfA[r] = NFbuf[(size_t)bh * S + tbA + lg * 4 + r];
    mlB[r] = Mbuf[(size_t)bh * S + tbB + lg * 4 + r];
    nfB[r] = NFbuf[(size_t)bh * S + tbB + lg * 4 + r];
  }

  floatx4 oA[8], oB[8];
  #pragma unroll
  for (int df = 0; df < 8; ++df) { oA[df] = (floatx4)(0.f); oB[df] = (floatx4)(0.f); }
  float rsA[4] = {0, 0, 0, 0}, rsB[4] = {0, 0, 0, 0};

  int krow = tid >> 3, kcol = tid & 7;
  bf16x8 kreg[4], vreg[4];
  float greg = 0.f;
  auto preload = [&](int st) {
    int s0 = st * 64;
    const __bf16* kp = qk + ((size_t)(bb * S + s0 + krow)) * 1024 + 512 + hh * 128;
    kreg[0] = *(const bf16x8*)(kp + kcol * 8);
    kreg[1] = *(const bf16x8*)(kp + (size_t)32 * 1024 + kcol * 8);
    kreg[2] = *(const bf16x8*)(kp + 64 + kcol * 8);
    kreg[3] = *(const bf16x8*)(kp + (size_t)32 * 1024 + 64 + kcol * 8);
    #pragma unroll
    for (int i = 0; i < 4; ++i)
      vreg[i] = *(const bf16x8*)(vT + ((size_t)(bh * 128 + krow + i * 32)) * 1024 + s0 + kcol * 8);
    if (tid < 64) greg = gbuf[(size_t)bh * S + s0 + tid];
  };
  preload(0);

  for (int st = 0; st <= tqB; ++st) {
    __syncthreads();
    *(bf16x8*)&Ks[krow][kcol * 8] = kreg[0];
    *(bf16x8*)&Ks[krow + 32][kcol * 8] = kreg[1];
    *(bf16x8*)&Ks[krow][64 + kcol * 8] = kreg[2];
    *(bf16x8*)&Ks[krow + 32][64 + kcol * 8] = kreg[3];
    #pragma unroll
    for (int i = 0; i < 4; ++i) *(bf16x8*)&Vs[krow + i * 32][kcol * 8] = vreg[i];
    if (tid < 64) gls[tid] = greg;
    __syncthreads();
    if (st < tqB) preload(st + 1);

    int s0 = st * 64;
    bool actA = (st <= tqA);
    #pragma unroll
    for (int ns = 0; ns < 4; ++ns) {
      bf16x8 bk0 = *(const bf16x8*)&Ks[ns * 16 + li][lg * 8];
      bf16x8 bk1 = *(const bf16x8*)&Ks[ns * 16 + li][32 + lg * 8];
      bf16x8 bk2 = *(const bf16x8*)&Ks[ns * 16 + li][64 + lg * 8];
      bf16x8 bk3 = *(const bf16x8*)&Ks[ns * 16 + li][96 + lg * 8];
      int s = s0 + ns * 16 + li;
      float gv = gls[ns * 16 + li];
      if (actA) {
        floatx4 pa = (floatx4)(0.f);
        pa = __builtin_amdgcn_mfma_f32_16x16x32_bf16(aqA[0], bk0, pa, 0, 0, 0);
        pa = __builtin_amdgcn_mfma_f32_16x16x32_bf16(aqA[1], bk1, pa, 0, 0, 0);
        pa = __builtin_amdgcn_mfma_f32_16x16x32_bf16(aqA[2], bk2, pa, 0, 0, 0);
        pa = __builtin_amdgcn_mfma_f32_16x16x32_bf16(aqA[3], bk3, pa, 0, 0, 0);
        #pragma unroll
        for (int r = 0; r < 4; ++r) {
          int t = tbA + lg * 4 + r;
          float val = pa[r] * scale * __expf(gv - mlA[r]);
          float w = (s <= t) ? val : 0.f;
          rsA[r] += w;
          plds[wv][0][lg * 4 + r][ns * 16 + li] = (__bf16)w;
        }
      }
      {
        floatx4 pb = (floatx4)(0.f);
        pb = __builtin_amdgcn_mfma_f32_16x16x32_bf16(aqB[0], bk0, pb, 0, 0, 0);
        pb = __builtin_amdgcn_mfma_f32_16x16x32_bf16(aqB[1], bk1, pb, 0, 0, 0);
        pb = __builtin_amdgcn_mfma_f32_16x16x32_bf16(aqB[2], bk2, pb, 0, 0, 0);
        pb = __builtin_amdgcn_mfma_f32_16x16x32_bf16(aqB[3], bk3, pb, 0, 0, 0);
        #pragma unroll
        for (int r = 0; r < 4; ++r) {
          int t = tbB + lg * 4 + r;
          float val = pb[r] * scale * __expf(gv - mlB[r]);
          float w = (s <= t) ? val : 0.f;
          rsB[r] += w;
          plds[wv][1][lg * 4 + r][ns * 16 + li] = (__bf16)w;
        }
      }
    }
    bf16x8 apA0, apA1, apB0, apB1;
    if (actA) {
      apA0 = *(const bf16x8*)&plds[wv][0][li][lg * 8];
      apA1 = *(const bf16x8*)&plds[wv][0][li][32 + lg * 8];
    }
    apB0 = *(const bf16x8*)&plds[wv][1][li][lg * 8];
    apB1 = *(const bf16x8*)&plds[wv][1][li][32 + lg * 8];
    #pragma unroll
    for (int df = 0; df < 8; ++df) {
      bf16x8 bv0 = *(const bf16x8*)&Vs[df * 16 + li][lg * 8];
      bf16x8 bv1 = *(const bf16x8*)&Vs[df * 16 + li][32 + lg * 8];
      if (actA) {
        oA[df] = __builtin_amdgcn_mfma_f32_16x16x32_bf16(apA0, bv0, oA[df], 0, 0, 0);
        oA[df] = __builtin_amdgcn_mfma_f32_16x16x32_bf16(apA1, bv1, oA[df], 0, 0, 0);
      }
      oB[df] = __builtin_amdgcn_mfma_f32_16x16x32_bf16(apB0, bv0, oB[df], 0, 0, 0);
      oB[df] = __builtin_amdgcn_mfma_f32_16x16x32_bf16(apB1, bv1, oB[df], 0, 0, 0);
    }
  }
  #pragma unroll
  for (int r = 0; r < 4; ++r) {
    float a = rsA[r], b = rsB[r];
    a += __shfl_xor(a, 1, 64); a += __shfl_xor(a, 2, 64);
    a += __shfl_xor(a, 4, 64); a += __shfl_xor(a, 8, 64);
    b += __shfl_xor(b, 1, 64); b += __shfl_xor(b, 2, 64);
    b += __shfl_xor(b, 4, 64); b += __shfl_xor(b, 8, 64);
    rsA[r] = a; rsB[r] = b;
  }
  #pragma unroll
  for (int tile = 0; tile < 2; ++tile) {
    int tb = tile == 0 ? tbA : tbB;
    #pragma unroll
    for (int r = 0; r < 4; ++r) {
      float rs = tile == 0 ? rsA[r] : rsB[r];
      float nf = tile == 0 ? nfA[r] : nfB[r];
      float inv = 1.f / (fmaxf(fabsf(rs), nf) + 1e-6f);
      float v8[8], s1 = 0.f, s2 = 0.f;
      #pragma unroll
      for (int df = 0; df < 8; ++df) {
        float v = (tile == 0 ? oA[df][r] : oB[df][r]) * inv;
        v8[df] = v;
        s1 += v;
        s2 += v * v;
      }
      s1 += __shfl_xor(s1, 1, 64); s1 += __shfl_xor(s1, 2, 64);
      s1 += __shfl_xor(s1, 4, 64); s1 += __shfl_xor(s1, 8, 64);
      s2 += __shfl_xor(s2, 1, 64); s2 += __shfl_xor(s2, 2, 64);
      s2 += __shfl_xor(s2, 4, 64); s2 += __shfl_xor(s2, 8, 64);
      float mu = s1 * (1.f / 128.f);
      float var = s2 * (1.f / 128.f) - mu * mu;
      float rq = rsqrtf(var + 1e-5f);
      int t = tb + lg * 4 + r;
      const __bf16* xr = xc + ((size_t)(bb * S + t)) * 512 + hh * 128 + li;
      const __bf16* zr = up + ((size_t)(bb * S + t)) * 1024 + 512 + hh * 128 + li;
      __bf16* od = hd + ((size_t)(bb * S + t)) * 512 + hh * 128 + li;
      #pragma unroll
      for (int df = 0; df < 8; ++df) {
        int c = df * 16 + li;
        float ln = (v8[df] - mu) * rq * glds[c] + blds[c];
        float val = ln + slds[c] * (float)xr[df * 16];
        float z = (float)zr[df * 16];
        float sg = 1.f / (1.f + __expf(-z));
        od[df * 16] = (__bf16)(val * (z * sg));
      }
    }
  }
}

// ---------------- final LN + head ----------------
__global__ __launch_bounds__(256) void final_kernel(
    const float* __restrict__ h, const float* __restrict__ g,
    const float* __restrict__ b, const float* __restrict__ Wf,
    const float* __restrict__ bf, float* __restrict__ out) {
  int bb = blockIdx.x, tid = threadIdx.x;
  size_t row = (size_t)(bb * S + S - 1) * 256;
  __shared__ float red[4];
  float v = h[row + tid];
  float s = wave_sum(v);
  int wid = tid >> 6, lane = tid & 63;
  if (lane == 0) red[wid] = s;
  __syncthreads();
  float mu = (red[0] + red[1] + red[2] + red[3]) * (1.f / 256.f);
  __syncthreads();
  float d = v - mu;
  float s2 = wave_sum(d * d);
  if (lane == 0) red[wid] = s2;
  __syncthreads();
  float var = (red[0] + red[1] + red[2] + red[3]) * (1.f / 256.f);
  float rs = rsqrtf(var + 1e-5f);
  float ln = d * rs * g[tid] + b[tid];
  float p = ln * Wf[tid];
  float psum = wave_sum(p);
  __syncthreads();
  if (lane == 0) red[wid] = psum;
  __syncthreads();
  if (tid == 0) out[bb] = red[0] + red[1] + red[2] + red[3] + bf[0];
}

extern "C" void kernel_launch(void* const* d_in, const int* in_sizes, int n_in,
                              void* d_out, int out_size, void* d_ws, size_t ws_size,
                              hipStream_t stream) {
  const float* x      = (const float*)d_in[0];
  const float* tf     = (const float*)d_in[1];
  const float* Wp     = (const float*)d_in[2];
  const float* bp     = (const float*)d_in[3];
  const float* ln_g   = (const float*)d_in[4];
  const float* ln_b   = (const float*)d_in[5];
  const float* Wup    = (const float*)d_in[6];
  const float* bup    = (const float*)d_in[7];
  const float* conv_w = (const float*)d_in[8];
  const float* conv_b = (const float*)d_in[9];
  const float* Wq     = (const float*)d_in[10];
  const float* Wk     = (const float*)d_in[11];
  const float* Wv     = (const float*)d_in[12];
  const float* Wif    = (const float*)d_in[13];
  const float* bif    = (const float*)d_in[14];
  const float* gn_g   = (const float*)d_in[15];
  const float* gn_b   = (const float*)d_in[16];
  const float* skip   = (const float*)d_in[17];
  const float* Wdown  = (const float*)d_in[18];
  const float* bdown  = (const float*)d_in[19];
  const float* lnf_g  = (const float*)d_in[20];
  const float* lnf_b  = (const float*)d_in[21];
  const float* Wf     = (const float*)d_in[22];
  const float* bf     = (const float*)d_in[23];
  float* out = (float*)d_out;

  float* h     = (float*)d_ws;              // 2,097,152 f32
  float* gates = h + 2097152;               // 65,536 f32
  float* gbuf  = gates + 65536;             // 32,768
  float* Mbuf  = gbuf + 32768;              // 32,768
  float* NFbuf = Mbuf + 32768;              // 32,768
  float* wgbuf = NFbuf + 32768;             // 32,768
  __bf16* hn   = (__bf16*)(wgbuf + 32768);  // 2,097,152 bf16
  __bf16* up   = hn + 2097152;              // 8,388,608
  __bf16* xc   = up + 8388608;              // 4,194,304
  __bf16* qk   = xc + 4194304;              // 8,388,608
  __bf16* vT   = qk + 8388608;              // 4,194,304
  __bf16* hd   = vT + 4194304;              // 4,194,304
  __bf16* WupT   = hd + 4194304;            // 1,048,576
  __bf16* WqkT   = WupT + 1048576;          // 2,097,152
  __bf16* WvT    = WqkT + 2097152;          // 1,048,576
  __bf16* WdownT = WvT + 1048576;           // 524,288

  prep_kernel<<<13824, 256, 0, stream>>>(
      x, tf, Wp, bp, ln_g, ln_b, Wup, Wq, Wk, Wv, Wdown, Wif,
      WupT, WqkT, WvT, WdownT, wgbuf, h, hn);
  for (int l = 0; l < NLAYER; ++l) {
    if (l > 0)
      ln256_kernel<<<8192, 256, 0, stream>>>(h, ln_g + l * 256, ln_b + l * 256, hn);
    hgemm<128, 1, 0><<<dim3(64, 8), 256, 20480, stream>>>(
        hn, 256, WupT + (size_t)l * 262144, 256, bup + l * 1024, up, 1024);
    conv_silu_kernel<<<2048, 256, 0, stream>>>(up, conv_w + l * 2048, conv_b + l * 512,
                                               wgbuf + l * 8192, bif + l * 8, xc, gates);
    scan_kernel<<<32, 64, 0, stream>>>(gates, gbuf, Mbuf, NFbuf);
    qkv_kernel<<<dim3(64, 16), 256, 20480, stream>>>(
        xc, WqkT + (size_t)l * 524288, qk, up, WvT + (size_t)l * 262144, vT);
    attn_kernel<<<dim3(32, 8), 256, 0, stream>>>(
        qk, vT, gbuf, Mbuf, NFbuf, gn_g + l * 512, gn_b + l * 512, skip + l * 512,
        xc, up, hd);
    hgemm<64, 0, 1><<<dim3(128, 2), 256, 15360, stream>>>(
        hd, 512, WdownT + (size_t)l * 131072, 512, bdown + l * 256, h, 256);
  }
  final_kernel<<<8, 256, 0, stream>>>(h, lnf_g, lnf_b, Wf, bf, out);
}

// Round 13
// 641.873 us; speedup vs baseline: 1.2194x; 1.0502x over previous
//
#include <hip/hip_runtime.h>
#include <hip/hip_bf16.h>
#include <math.h>

#define S 1024
#define NLAYER 4

typedef __bf16 bf16x8 __attribute__((ext_vector_type(8)));
typedef float floatx4 __attribute__((ext_vector_type(4)));

__device__ __forceinline__ float wave_sum(float v) {
  #pragma unroll
  for (int off = 32; off > 0; off >>= 1) v += __shfl_xor(v, off, 64);
  return v;
}

// ---------------- combined prep: weight transpose + Wg precompute + embed/LN ----------------
__device__ __forceinline__ void wtrans_body(
    int bid, const float* Wup, const float* Wq, const float* Wk, const float* Wv,
    const float* Wdown, __bf16* WupT, __bf16* WqkT, __bf16* WvT, __bf16* WdownT) {
  __shared__ float T[32][33];
  int layer = bid / 1152, rr = bid % 1152;
  const float* src; __bf16* dst; int K, N, tile;
  if (rr < 256)       { src = Wup   + layer * 262144; dst = WupT  + layer * 262144;          K = 256; N = 1024; tile = rr; }
  else if (rr < 512)  { src = Wq    + layer * 262144; dst = WqkT  + layer * 524288;          K = 512; N = 512;  tile = rr - 256; }
  else if (rr < 768)  { src = Wk    + layer * 262144; dst = WqkT  + layer * 524288 + 262144; K = 512; N = 512;  tile = rr - 512; }
  else if (rr < 1024) { src = Wv    + layer * 262144; dst = WvT   + layer * 262144;          K = 512; N = 512;  tile = rr - 768; }
  else                { src = Wdown + layer * 131072; dst = WdownT + layer * 131072;         K = 512; N = 256;  tile = rr - 1024; }
  int ntn = N >> 5;
  int tk = tile / ntn, tn = tile % ntn;
  int tid = threadIdx.x;
  int r = tid >> 3, c4 = (tid & 7) * 4;
  float4 v = *(const float4*)(src + (size_t)(tk * 32 + r) * N + tn * 32 + c4);
  T[c4 + 0][r] = v.x; T[c4 + 1][r] = v.y; T[c4 + 2][r] = v.z; T[c4 + 3][r] = v.w;
  __syncthreads();
  __bf16 o[4];
  #pragma unroll
  for (int j = 0; j < 4; ++j) o[j] = (__bf16)T[r][c4 + j];
  *(uint2*)(dst + (size_t)(tn * 32 + r) * K + tk * 32 + c4) = *(uint2*)o;
}

__device__ __forceinline__ void wgprep_body(
    int bid, const float* Wq, const float* Wk, const float* Wv,
    const float* Wif, float* wg) {
  int l = bid >> 8;
  int rem = bid & 255;
  int sel = rem >> 7;
  int kg = rem & 127;
  int tid = threadIdx.x;
  int wv = tid >> 6, lane = tid & 63;
  int k = kg * 4 + wv;
  const float* wif = Wif + (size_t)l * 1536 * 8;
  float part[8] = {0, 0, 0, 0, 0, 0, 0, 0};
  if (sel == 0) {
    const float* qr = Wq + (size_t)l * 262144 + (size_t)k * 512;
    const float* kr = Wk + (size_t)l * 262144 + (size_t)k * 512;
    #pragma unroll
    for (int i = 0; i < 8; ++i) {
      int n = lane + i * 64;
      float qv = qr[n], kv = kr[n];
      const float* wq8 = wif + (size_t)n * 8;
      const float* wk8 = wif + (size_t)(512 + n) * 8;
      #pragma unroll
      for (int j = 0; j < 8; ++j) part[j] += qv * wq8[j] + kv * wk8[j];
    }
  } else {
    const float* vr = Wv + (size_t)l * 262144 + (size_t)k * 512;
    #pragma unroll
    for (int i = 0; i < 8; ++i) {
      int n = lane + i * 64;
      float vv = vr[n];
      const float* wv8 = wif + (size_t)(1024 + n) * 8;
      #pragma unroll
      for (int j = 0; j < 8; ++j) part[j] += vv * wv8[j];
    }
  }
  #pragma unroll
  for (int j = 0; j < 8; ++j) part[j] = wave_sum(part[j]);
  if (lane < 8) wg[(size_t)l * 8192 + sel * 4096 + (size_t)k * 8 + lane] = part[lane];
}

__device__ __forceinline__ void embed_body(
    int row, const float* x, const float* tf, const float* Wp, const float* bp,
    const float* g, const float* b, float* h, __bf16* hn) {
  int n = threadIdx.x;
  float xv = x[row];
  const float* t4 = tf + (size_t)row * 4;
  float acc = bp[n] + xv * Wp[n];
  acc += t4[0] * Wp[256 + n];
  acc += t4[1] * Wp[512 + n];
  acc += t4[2] * Wp[768 + n];
  acc += t4[3] * Wp[1024 + n];
  h[(size_t)row * 256 + n] = acc;
  __shared__ float red[4];
  int wid = n >> 6, lane = n & 63;
  float s = wave_sum(acc);
  if (lane == 0) red[wid] = s;
  __syncthreads();
  float mu = (red[0] + red[1] + red[2] + red[3]) * (1.f / 256.f);
  __syncthreads();
  float d = acc - mu;
  float s2 = wave_sum(d * d);
  if (lane == 0) red[wid] = s2;
  __syncthreads();
  float var = (red[0] + red[1] + red[2] + red[3]) * (1.f / 256.f);
  float rs = rsqrtf(var + 1e-5f);
  hn[(size_t)row * 256 + n] = (__bf16)(d * rs * g[n] + b[n]);
}

__global__ __launch_bounds__(256) void prep_kernel(
    const float* __restrict__ x, const float* __restrict__ tf,
    const float* __restrict__ Wp, const float* __restrict__ bp,
    const float* __restrict__ ln_g, const float* __restrict__ ln_b,
    const float* __restrict__ Wup, const float* __restrict__ Wq,
    const float* __restrict__ Wk, const float* __restrict__ Wv,
    const float* __restrict__ Wdown, const float* __restrict__ Wif,
    __bf16* __restrict__ WupT, __bf16* __restrict__ WqkT,
    __bf16* __restrict__ WvT, __bf16* __restrict__ WdownT,
    float* __restrict__ wg, float* __restrict__ h, __bf16* __restrict__ hn) {
  int bid = blockIdx.x;
  if (bid < 4608) {
    wtrans_body(bid, Wup, Wq, Wk, Wv, Wdown, WupT, WqkT, WvT, WdownT);
  } else if (bid < 4608 + 1024) {
    wgprep_body(bid - 4608, Wq, Wk, Wv, Wif, wg);
  } else {
    embed_body(bid - 5632, x, tf, Wp, bp, ln_g, ln_b, h, hn);
  }
}

// ---------------- bf16 MFMA GEMM body: TM x 128 tile, register prefetch ----------------
template <int TM, int MODE, int ACC>
__device__ __forceinline__ void hgemm_body(
    char* smem_raw,
    const __bf16* __restrict__ A, int lda,
    const __bf16* __restrict__ BT, int Kdim,
    const float* __restrict__ bias,
    void* __restrict__ Cout, int ldc, int bxi, int byi) {
  auto As = (__bf16(*)[40])smem_raw;
  auto Bs = (__bf16(*)[40])(smem_raw + (size_t)TM * 80);
  int tid = threadIdx.x;
  int bm = bxi * TM, bn = byi * 128;
  int wid = tid >> 6, lane = tid & 63;
  int wr = wid >> 1, wc = wid & 1;
  int lg = lane >> 4, li = lane & 15;
  constexpr int MI = TM / 32;
  constexpr int WROW = TM / 2;
  floatx4 acc[MI][4];
  #pragma unroll
  for (int i = 0; i < MI; ++i)
    #pragma unroll
    for (int j = 0; j < 4; ++j) acc[i][j] = (floatx4)(0.f);

  int arow = tid >> 2, aseg = tid & 3;
  bf16x8 pa0, pa1, pb0, pb1;
  auto pre = [&](int k0) {
    pa0 = *(const bf16x8*)(A + (size_t)(bm + arow) * lda + k0 + aseg * 8);
    if constexpr (TM == 128)
      pa1 = *(const bf16x8*)(A + (size_t)(bm + arow + 64) * lda + k0 + aseg * 8);
    pb0 = *(const bf16x8*)(BT + (size_t)(bn + arow) * Kdim + k0 + aseg * 8);
    pb1 = *(const bf16x8*)(BT + (size_t)(bn + arow + 64) * Kdim + k0 + aseg * 8);
  };
  pre(0);
  for (int k0 = 0; k0 < Kdim; k0 += 32) {
    __syncthreads();
    *(bf16x8*)&As[arow][aseg * 8] = pa0;
    if constexpr (TM == 128) *(bf16x8*)&As[arow + 64][aseg * 8] = pa1;
    *(bf16x8*)&Bs[arow][aseg * 8] = pb0;
    *(bf16x8*)&Bs[arow + 64][aseg * 8] = pb1;
    __syncthreads();
    if (k0 + 32 < Kdim) pre(k0 + 32);
    bf16x8 af[MI], bfr[4];
    #pragma unroll
    for (int mi = 0; mi < MI; ++mi)
      af[mi] = *(const bf16x8*)&As[wr * WROW + mi * 16 + li][lg * 8];
    #pragma unroll
    for (int ni = 0; ni < 4; ++ni)
      bfr[ni] = *(const bf16x8*)&Bs[wc * 64 + ni * 16 + li][lg * 8];
    #pragma unroll
    for (int mi = 0; mi < MI; ++mi)
      #pragma unroll
      for (int ni = 0; ni < 4; ++ni)
        acc[mi][ni] = __builtin_amdgcn_mfma_f32_16x16x32_bf16(af[mi], bfr[ni], acc[mi][ni], 0, 0, 0);
  }
  if constexpr (MODE == 1) {
    __bf16* eb = (__bf16*)smem_raw;
    const int PITCH = 136;
    __bf16* C = (__bf16*)Cout;
    #pragma unroll
    for (int mi = 0; mi < MI; ++mi) {
      __syncthreads();
      #pragma unroll
      for (int ni = 0; ni < 4; ++ni) {
        int col = wc * 64 + ni * 16 + li;
        float bz = bias ? bias[bn + col] : 0.f;
        #pragma unroll
        for (int r = 0; r < 4; ++r) {
          int lr = wr * 16 + lg * 4 + r;
          eb[lr * PITCH + col] = (__bf16)(acc[mi][ni][r] + bz);
        }
      }
      __syncthreads();
      #pragma unroll
      for (int i = 0; i < 2; ++i) {
        int lr = (tid >> 4) + i * 16;
        int c8 = (tid & 15) * 8;
        bf16x8 v = *(const bf16x8*)&eb[lr * PITCH + c8];
        int row_g = bm + (lr >> 4) * 64 + mi * 16 + (lr & 15);
        *(bf16x8*)(C + (size_t)row_g * ldc + bn + c8) = v;
      }
    }
  } else {
    #pragma unroll
    for (int mi = 0; mi < MI; ++mi) {
      int row = bm + wr * WROW + mi * 16 + lg * 4;
      #pragma unroll
      for (int ni = 0; ni < 4; ++ni) {
        int col = bn + wc * 64 + ni * 16 + li;
        if constexpr (MODE == 2) {
          __bf16 o4[4];
          #pragma unroll
          for (int r = 0; r < 4; ++r) o4[r] = (__bf16)acc[mi][ni][r];
          __bf16* vt = (__bf16*)Cout;
          size_t off = ((size_t)((row >> 10) * 4 + (col >> 7)) * 128 + (col & 127)) * 1024 + (row & 1023);
          *(uint2*)(vt + off) = *(uint2*)o4;
        } else {
          float bz = bias ? bias[col] : 0.f;
          float* C = (float*)Cout;
          #pragma unroll
          for (int r = 0; r < 4; ++r) {
            float v = acc[mi][ni][r] + bz;
            if (ACC) v += C[(size_t)(row + r) * ldc + col];
            C[(size_t)(row + r) * ldc + col] = v;
          }
        }
      }
    }
  }
}

template <int TM, int MODE, int ACC>
__global__ __launch_bounds__(256) void hgemm(
    const __bf16* __restrict__ A, int lda,
    const __bf16* __restrict__ BT, int Kdim,
    const float* __restrict__ bias,
    void* __restrict__ Cout, int ldc) {
  extern __shared__ char smem[];
  hgemm_body<TM, MODE, ACC>(smem, A, lda, BT, Kdim, bias, Cout, ldc,
                            blockIdx.x, blockIdx.y);
}

// Merged QK + V GEMM: grid (64, 16). by<8 -> qk (128-tile); by>=8 -> vT (64-tile).
__global__ __launch_bounds__(256) void qkv_kernel(
    const __bf16* __restrict__ xc, const __bf16* __restrict__ WqkT,
    __bf16* __restrict__ qk, const __bf16* __restrict__ up,
    const __bf16* __restrict__ WvT, __bf16* __restrict__ vT) {
  extern __shared__ char smem[];
  if (blockIdx.y < 8) {
    hgemm_body<128, 1, 0>(smem, xc, 512, WqkT, 512, nullptr, qk, 1024,
                          blockIdx.x, blockIdx.y);
  } else {
    int j = blockIdx.y - 8;
    hgemm_body<64, 2, 0>(smem, up, 1024, WvT, 512, nullptr, vT, 0,
                         blockIdx.x * 2 + (j & 1), j >> 1);
  }
}

// ---------------- down-proj GEMM (32x256 tile) + residual + fused next-layer LN ----------------
// C = hd[32rows x 512] @ WdownT^T + bdown + h_old -> h (f32); then LN over the full
// 256-col rows in-block -> hn (bf16). Grid: 256 blocks (8192/32 rows).
__global__ __launch_bounds__(256) void dgemm_ln_kernel(
    const __bf16* __restrict__ A, const __bf16* __restrict__ BT,
    const float* __restrict__ bias, float* __restrict__ h,
    const float* __restrict__ lng, const float* __restrict__ lnb,
    __bf16* __restrict__ hn) {
  __shared__ __bf16 As[32][40];
  __shared__ __bf16 Bs[256][40];
  __shared__ float redS[2][32], redQ[2][32];
  int tid = threadIdx.x;
  int bm = blockIdx.x * 32;
  int wid = tid >> 6, lane = tid & 63;
  int wr = wid >> 1, wc = wid & 1;
  int lg = lane >> 4, li = lane & 15;
  floatx4 acc[8];
  #pragma unroll
  for (int j = 0; j < 8; ++j) acc[j] = (floatx4)(0.f);

  int arow = tid >> 2, aseg = tid & 3;  // arow 0..63 (A uses <32), brow base
  bf16x8 pa, pb[4];
  auto pre = [&](int k0) {
    if (tid < 128)
      pa = *(const bf16x8*)(A + (size_t)(bm + arow) * 512 + k0 + aseg * 8);
    #pragma unroll
    for (int i = 0; i < 4; ++i)
      pb[i] = *(const bf16x8*)(BT + (size_t)(arow + i * 64) * 512 + k0 + aseg * 8);
  };
  pre(0);
  for (int k0 = 0; k0 < 512; k0 += 32) {
    __syncthreads();
    if (tid < 128) *(bf16x8*)&As[arow][aseg * 8] = pa;
    #pragma unroll
    for (int i = 0; i < 4; ++i) *(bf16x8*)&Bs[arow + i * 64][aseg * 8] = pb[i];
    __syncthreads();
    if (k0 + 32 < 512) pre(k0 + 32);
    bf16x8 af = *(const bf16x8*)&As[wr * 16 + li][lg * 8];
    #pragma unroll
    for (int ni = 0; ni < 8; ++ni) {
      bf16x8 bfr = *(const bf16x8*)&Bs[wc * 128 + ni * 16 + li][lg * 8];
      acc[ni] = __builtin_amdgcn_mfma_f32_16x16x32_bf16(af, bfr, acc[ni], 0, 0, 0);
    }
  }
  // epilogue: v = acc + bias + h_old; write h; row LN stats
  #pragma unroll
  for (int r = 0; r < 4; ++r) {
    int lr = wr * 16 + lg * 4 + r;
    int row = bm + lr;
    float s1 = 0.f, s2 = 0.f;
    #pragma unroll
    for (int ni = 0; ni < 8; ++ni) {
      int col = wc * 128 + ni * 16 + li;
      float v = acc[ni][r] + bias[col] + h[(size_t)row * 256 + col];
      acc[ni][r] = v;
      h[(size_t)row * 256 + col] = v;
      s1 += v;
      s2 += v * v;
    }
    s1 += __shfl_xor(s1, 1, 64); s1 += __shfl_xor(s1, 2, 64);
    s1 += __shfl_xor(s1, 4, 64); s1 += __shfl_xor(s1, 8, 64);
    s2 += __shfl_xor(s2, 1, 64); s2 += __shfl_xor(s2, 2, 64);
    s2 += __shfl_xor(s2, 4, 64); s2 += __shfl_xor(s2, 8, 64);
    if (li == 0) { redS[wc][lr] = s1; redQ[wc][lr] = s2; }
  }
  if (!lng) return;
  __syncthreads();
  #pragma unroll
  for (int r = 0; r < 4; ++r) {
    int lr = wr * 16 + lg * 4 + r;
    int row = bm + lr;
    float s1 = redS[0][lr] + redS[1][lr];
    float s2 = redQ[0][lr] + redQ[1][lr];
    float mu = s1 * (1.f / 256.f);
    float var = s2 * (1.f / 256.f) - mu * mu;
    float rs = rsqrtf(var + 1e-5f);
    #pragma unroll
    for (int ni = 0; ni < 8; ++ni) {
      int col = wc * 128 + ni * 16 + li;
      hn[(size_t)row * 256 + col] = (__bf16)((acc[ni][r] - mu) * rs * lng[col] + lnb[col]);
    }
  }
}

// ---------------- causal conv (K=4) + SiLU + fused gate projection ----------------
__global__ __launch_bounds__(256) void conv_silu_kernel(
    const __bf16* __restrict__ up, const float* __restrict__ cw,
    const float* __restrict__ cb, const float* __restrict__ wg,
    const float* __restrict__ bif, __bf16* __restrict__ xc,
    float* __restrict__ gates) {
  int tid = threadIdx.x;
  int wv = tid >> 6, lane = tid & 63;
  int row = blockIdx.x * 4 + wv;
  int c8 = lane * 8;
  int t = row & (S - 1);
  float acc[8];
  *(float4*)&acc[0] = *(const float4*)(cb + c8);
  *(float4*)&acc[4] = *(const float4*)(cb + c8 + 4);
  float xm[8];
  #pragma unroll
  for (int j = 0; j < 4; ++j) {
    int tt = t - 3 + j;
    if (tt >= 0) {
      bf16x8 xv = *(const bf16x8*)(up + (size_t)(row - 3 + j) * 1024 + c8);
      float4 w0 = *(const float4*)(cw + j * 512 + c8);
      float4 w1 = *(const float4*)(cw + j * 512 + c8 + 4);
      acc[0] += w0.x * (float)xv[0]; acc[1] += w0.y * (float)xv[1];
      acc[2] += w0.z * (float)xv[2]; acc[3] += w0.w * (float)xv[3];
      acc[4] += w1.x * (float)xv[4]; acc[5] += w1.y * (float)xv[5];
      acc[6] += w1.z * (float)xv[6]; acc[7] += w1.w * (float)xv[7];
      if (j == 3) {
        #pragma unroll
        for (int m = 0; m < 8; ++m) xm[m] = (float)xv[m];
      }
    }
  }
  bf16x8 o;
  float xcs[8];
  #pragma unroll
  for (int m = 0; m < 8; ++m) {
    float sg = 1.f / (1.f + __expf(-acc[m]));
    xcs[m] = acc[m] * sg;
    o[m] = (__bf16)xcs[m];
  }
  *(bf16x8*)(xc + (size_t)row * 512 + c8) = o;
  const float* w1 = wg + (size_t)c8 * 8;
  const float* w2 = wg + 4096 + (size_t)c8 * 8;
  float part[8] = {0, 0, 0, 0, 0, 0, 0, 0};
  #pragma unroll
  for (int m = 0; m < 8; ++m) {
    const float* a = w1 + m * 8;
    const float* b = w2 + m * 8;
    #pragma unroll
    for (int j = 0; j < 8; ++j) part[j] += xcs[m] * a[j] + xm[m] * b[j];
  }
  #pragma unroll
  for (int j = 0; j < 8; ++j) part[j] = wave_sum(part[j]);
  if (lane < 8) gates[(size_t)row * 8 + lane] = part[lane] + bif[lane];
}

// ---------------- per-(b,h) gate scan: one wave ----------------
__global__ __launch_bounds__(64) void scan_kernel(
    const float* __restrict__ gates, float* __restrict__ gout,
    float* __restrict__ Mout, float* __restrict__ NFout) {
  int bh = blockIdx.x;
  int bb = bh >> 2, hh = bh & 3;
  int lane = threadIdx.x;
  float ip[16], pf[16];
  #pragma unroll
  for (int i = 0; i < 16; ++i) {
    int t = lane * 16 + i;
    const float* grow = gates + ((size_t)(bb * S + t)) * 8;
    ip[i] = grow[hh];
    float fp = grow[4 + hh];
    float lf = fminf(fp, 0.f) - log1pf(__expf(-fabsf(fp)));
    pf[i] = (i == 0) ? lf : pf[i - 1] + lf;
  }
  float T = pf[15];
  float inc = T;
  #pragma unroll
  for (int off = 1; off < 64; off <<= 1) {
    float v = __shfl_up(inc, off, 64);
    if (lane >= off) inc += v;
  }
  float excl = inc - T;
  float F[16], g[16], pm[16];
  #pragma unroll
  for (int i = 0; i < 16; ++i) {
    F[i] = excl + pf[i];
    g[i] = ip[i] - F[i];
    pm[i] = (i == 0) ? g[0] : fmaxf(pm[i - 1], g[i]);
  }
  float Mx = pm[15];
  float incm = Mx;
  #pragma unroll
  for (int off = 1; off < 64; off <<= 1) {
    float v = __shfl_up(incm, off, 64);
    if (lane >= off) incm = fmaxf(incm, v);
  }
  float em = __shfl_up(incm, 1, 64);
  if (lane == 0) em = -3.4e38f;
  #pragma unroll
  for (int i = 0; i < 16; ++i) {
    int t = lane * 16 + i;
    size_t o = (size_t)bh * S + t;
    float M = fmaxf(em, pm[i]);
    gout[o] = g[i];
    Mout[o] = M;
    NFout[o] = __expf(-F[i] - M);
  }
}

// ---------------- MFMA mLSTM attention + fused GroupNorm/skip/silu-gate ----------------
__global__ __launch_bounds__(256, 1) void attn_kernel(
    const __bf16* __restrict__ qk, const __bf16* __restrict__ vT,
    const float* __restrict__ gbuf, const float* __restrict__ Mbuf,
    const float* __restrict__ NFbuf,
    const float* __restrict__ gn_g, const float* __restrict__ gn_b,
    const float* __restrict__ skip,
    const __bf16* __restrict__ xc, const __bf16* __restrict__ up,
    __bf16* __restrict__ hd) {
  __shared__ __bf16 Ks[64][136];
  __shared__ __bf16 Vs[128][72];
  __shared__ __bf16 plds[4][2][16][72];
  __shared__ float gls[64];
  __shared__ float glds[128], blds[128], slds[128];
  int px = blockIdx.y, bh = blockIdx.x;
  int tqA = px, tqB = 15 - px;
  int bb = bh >> 2, hh = bh & 3;
  int tid = threadIdx.x;
  int wv = tid >> 6, lane = tid & 63;
  int lg = lane >> 4, li = lane & 15;
  int tbA = tqA * 64 + wv * 16;
  int tbB = tqB * 64 + wv * 16;
  const float scale = 0.08838834764831845f;

  if (tid < 128) {
    glds[tid] = gn_g[hh * 128 + tid];
    blds[tid] = gn_b[hh * 128 + tid];
    slds[tid] = skip[hh * 128 + tid];
  }

  bf16x8 aqA[4], aqB[4];
  {
    const __bf16* qpA = qk + ((size_t)(bb * S + tbA + li)) * 1024 + hh * 128 + lg * 8;
    const __bf16* qpB = qk + ((size_t)(bb * S + tbB + li)) * 1024 + hh * 128 + lg * 8;
    #pragma unroll
    for (int cd = 0; cd < 4; ++cd) {
      aqA[cd] = *(const bf16x8*)(qpA + cd * 32);
      aqB[cd] = *(const bf16x8*)(qpB + cd * 32);
    }
  }
  float mlA[4], nfA[4], mlB[4], nfB[4];
  #pragma unroll
  for (int r = 0; r < 4; ++r) {
    mlA[r] = Mbuf[(size_t)bh * S + tbA + lg * 4 + r];
    nfA[r] = NFbuf[(size_t)bh * S + tbA + lg * 4 + r];
    mlB[r] = Mbuf[(size_t)bh * S + tbB + lg * 4 + r];
    nfB[r] = NFbuf[(size_t)bh * S + tbB + lg * 4 + r];
  }

  floatx4 oA[8], oB[8];
  #pragma unroll
  for (int df = 0; df < 8; ++df) { oA[df] = (floatx4)(0.f); oB[df] = (floatx4)(0.f); }
  float rsA[4] = {0, 0, 0, 0}, rsB[4] = {0, 0, 0, 0};

  int krow = tid >> 3, kcol = tid & 7;
  bf16x8 kreg[4], vreg[4];
  float greg = 0.f;
  auto preload = [&](int st) {
    int s0 = st * 64;
    const __bf16* kp = qk + ((size_t)(bb * S + s0 + krow)) * 1024 + 512 + hh * 128;
    kreg[0] = *(const bf16x8*)(kp + kcol * 8);
    kreg[1] = *(const bf16x8*)(kp + (size_t)32 * 1024 + kcol * 8);
    kreg[2] = *(const bf16x8*)(kp + 64 + kcol * 8);
    kreg[3] = *(const bf16x8*)(kp + (size_t)32 * 1024 + 64 + kcol * 8);
    #pragma unroll
    for (int i = 0; i < 4; ++i)
      vreg[i] = *(const bf16x8*)(vT + ((size_t)(bh * 128 + krow + i * 32)) * 1024 + s0 + kcol * 8);
    if (tid < 64) greg = gbuf[(size_t)bh * S + s0 + tid];
  };
  preload(0);

  for (int st = 0; st <= tqB; ++st) {
    __syncthreads();
    *(bf16x8*)&Ks[krow][kcol * 8] = kreg[0];
    *(bf16x8*)&Ks[krow + 32][kcol * 8] = kreg[1];
    *(bf16x8*)&Ks[krow][64 + kcol * 8] = kreg[2];
    *(bf16x8*)&Ks[krow + 32][64 + kcol * 8] = kreg[3];
    #pragma unroll
    for (int i = 0; i < 4; ++i) *(bf16x8*)&Vs[krow + i * 32][kcol * 8] = vreg[i];
    if (tid < 64) gls[tid] = greg;
    __syncthreads();
    if (st < tqB) preload(st + 1);

    int s0 = st * 64;
    bool actA = (st <= tqA);
    #pragma unroll
    for (int ns = 0; ns < 4; ++ns) {
      bf16x8 bk0 = *(const bf16x8*)&Ks[ns * 16 + li][lg * 8];
      bf16x8 bk1 = *(const bf16x8*)&Ks[ns * 16 + li][32 + lg * 8];
      bf16x8 bk2 = *(const bf16x8*)&Ks[ns * 16 + li][64 + lg * 8];
      bf16x8 bk3 = *(const bf16x8*)&Ks[ns * 16 + li][96 + lg * 8];
      int s = s0 + ns * 16 + li;
      float gv = gls[ns * 16 + li];
      if (actA) {
        floatx4 pa = (floatx4)(0.f);
        pa = __builtin_amdgcn_mfma_f32_16x16x32_bf16(aqA[0], bk0, pa, 0, 0, 0);
        pa = __builtin_amdgcn_mfma_f32_16x16x32_bf16(aqA[1], bk1, pa, 0, 0, 0);
        pa = __builtin_amdgcn_mfma_f32_16x16x32_bf16(aqA[2], bk2, pa, 0, 0, 0);
        pa = __builtin_amdgcn_mfma_f32_16x16x32_bf16(aqA[3], bk3, pa, 0, 0, 0);
        #pragma unroll
        for (int r = 0; r < 4; ++r) {
          int t = tbA + lg * 4 + r;
          float val = pa[r] * scale * __expf(gv - mlA[r]);
          float w = (s <= t) ? val : 0.f;
          rsA[r] += w;
          plds[wv][0][lg * 4 + r][ns * 16 + li] = (__bf16)w;
        }
      }
      {
        floatx4 pb = (floatx4)(0.f);
        pb = __builtin_amdgcn_mfma_f32_16x16x32_bf16(aqB[0], bk0, pb, 0, 0, 0);
        pb = __builtin_amdgcn_mfma_f32_16x16x32_bf16(aqB[1], bk1, pb, 0, 0, 0);
        pb = __builtin_amdgcn_mfma_f32_16x16x32_bf16(aqB[2], bk2, pb, 0, 0, 0);
        pb = __builtin_amdgcn_mfma_f32_16x16x32_bf16(aqB[3], bk3, pb, 0, 0, 0);
        #pragma unroll
        for (int r = 0; r < 4; ++r) {
          int t = tbB + lg * 4 + r;
          float val = pb[r] * scale * __expf(gv - mlB[r]);
          float w = (s <= t) ? val : 0.f;
          rsB[r] += w;
          plds[wv][1][lg * 4 + r][ns * 16 + li] = (__bf16)w;
        }
      }
    }
    bf16x8 apA0, apA1, apB0, apB1;
    if (actA) {
      apA0 = *(const bf16x8*)&plds[wv][0][li][lg * 8];
      apA1 = *(const bf16x8*)&plds[wv][0][li][32 + lg * 8];
    }
    apB0 = *(const bf16x8*)&plds[wv][1][li][lg * 8];
    apB1 = *(const bf16x8*)&plds[wv][1][li][32 + lg * 8];
    #pragma unroll
    for (int df = 0; df < 8; ++df) {
      bf16x8 bv0 = *(const bf16x8*)&Vs[df * 16 + li][lg * 8];
      bf16x8 bv1 = *(const bf16x8*)&Vs[df * 16 + li][32 + lg * 8];
      if (actA) {
        oA[df] = __builtin_amdgcn_mfma_f32_16x16x32_bf16(apA0, bv0, oA[df], 0, 0, 0);
        oA[df] = __builtin_amdgcn_mfma_f32_16x16x32_bf16(apA1, bv1, oA[df], 0, 0, 0);
      }
      oB[df] = __builtin_amdgcn_mfma_f32_16x16x32_bf16(apB0, bv0, oB[df], 0, 0, 0);
      oB[df] = __builtin_amdgcn_mfma_f32_16x16x32_bf16(apB1, bv1, oB[df], 0, 0, 0);
    }
  }
  #pragma unroll
  for (int r = 0; r < 4; ++r) {
    float a = rsA[r], b = rsB[r];
    a += __shfl_xor(a, 1, 64); a += __shfl_xor(a, 2, 64);
    a += __shfl_xor(a, 4, 64); a += __shfl_xor(a, 8, 64);
    b += __shfl_xor(b, 1, 64); b += __shfl_xor(b, 2, 64);
    b += __shfl_xor(b, 4, 64); b += __shfl_xor(b, 8, 64);
    rsA[r] = a; rsB[r] = b;
  }
  #pragma unroll
  for (int tile = 0; tile < 2; ++tile) {
    int tb = tile == 0 ? tbA : tbB;
    #pragma unroll
    for (int r = 0; r < 4; ++r) {
      float rs = tile == 0 ? rsA[r] : rsB[r];
      float nf = tile == 0 ? nfA[r] : nfB[r];
      float inv = 1.f / (fmaxf(fabsf(rs), nf) + 1e-6f);
      float v8[8], s1 = 0.f, s2 = 0.f;
      #pragma unroll
      for (int df = 0; df < 8; ++df) {
        float v = (tile == 0 ? oA[df][r] : oB[df][r]) * inv;
        v8[df] = v;
        s1 += v;
        s2 += v * v;
      }
      s1 += __shfl_xor(s1, 1, 64); s1 += __shfl_xor(s1, 2, 64);
      s1 += __shfl_xor(s1, 4, 64); s1 += __shfl_xor(s1, 8, 64);
      s2 += __shfl_xor(s2, 1, 64); s2 += __shfl_xor(s2, 2, 64);
      s2 += __shfl_xor(s2, 4, 64); s2 += __shfl_xor(s2, 8, 64);
      float mu = s1 * (1.f / 128.f);
      float var = s2 * (1.f / 128.f) - mu * mu;
      float rq = rsqrtf(var + 1e-5f);
      int t = tb + lg * 4 + r;
      const __bf16* xr = xc + ((size_t)(bb * S + t)) * 512 + hh * 128 + li;
      const __bf16* zr = up + ((size_t)(bb * S + t)) * 1024 + 512 + hh * 128 + li;
      __bf16* od = hd + ((size_t)(bb * S + t)) * 512 + hh * 128 + li;
      #pragma unroll
      for (int df = 0; df < 8; ++df) {
        int c = df * 16 + li;
        float ln = (v8[df] - mu) * rq * glds[c] + blds[c];
        float val = ln + slds[c] * (float)xr[df * 16];
        float z = (float)zr[df * 16];
        float sg = 1.f / (1.f + __expf(-z));
        od[df * 16] = (__bf16)(val * (z * sg));
      }
    }
  }
}

// ---------------- final LN + head ----------------
__global__ __launch_bounds__(256) void final_kernel(
    const float* __restrict__ h, const float* __restrict__ g,
    const float* __restrict__ b, const float* __restrict__ Wf,
    const float* __restrict__ bf, float* __restrict__ out) {
  int bb = blockIdx.x, tid = threadIdx.x;
  size_t row = (size_t)(bb * S + S - 1) * 256;
  __shared__ float red[4];
  float v = h[row + tid];
  float s = wave_sum(v);
  int wid = tid >> 6, lane = tid & 63;
  if (lane == 0) red[wid] = s;
  __syncthreads();
  float mu = (red[0] + red[1] + red[2] + red[3]) * (1.f / 256.f);
  __syncthreads();
  float d = v - mu;
  float s2 = wave_sum(d * d);
  if (lane == 0) red[wid] = s2;
  __syncthreads();
  float var = (red[0] + red[1] + red[2] + red[3]) * (1.f / 256.f);
  float rs = rsqrtf(var + 1e-5f);
  float ln = d * rs * g[tid] + b[tid];
  float p = ln * Wf[tid];
  float psum = wave_sum(p);
  __syncthreads();
  if (lane == 0) red[wid] = psum;
  __syncthreads();
  if (tid == 0) out[bb] = red[0] + red[1] + red[2] + red[3] + bf[0];
}

extern "C" void kernel_launch(void* const* d_in, const int* in_sizes, int n_in,
                              void* d_out, int out_size, void* d_ws, size_t ws_size,
                              hipStream_t stream) {
  const float* x      = (const float*)d_in[0];
  const float* tf     = (const float*)d_in[1];
  const float* Wp     = (const float*)d_in[2];
  const float* bp     = (const float*)d_in[3];
  const float* ln_g   = (const float*)d_in[4];
  const float* ln_b   = (const float*)d_in[5];
  const float* Wup    = (const float*)d_in[6];
  const float* bup    = (const float*)d_in[7];
  const float* conv_w = (const float*)d_in[8];
  const float* conv_b = (const float*)d_in[9];
  const float* Wq     = (const float*)d_in[10];
  const float* Wk     = (const float*)d_in[11];
  const float* Wv     = (const float*)d_in[12];
  const float* Wif    = (const float*)d_in[13];
  const float* bif    = (const float*)d_in[14];
  const float* gn_g   = (const float*)d_in[15];
  const float* gn_b   = (const float*)d_in[16];
  const float* skip   = (const float*)d_in[17];
  const float* Wdown  = (const float*)d_in[18];
  const float* bdown  = (const float*)d_in[19];
  const float* lnf_g  = (const float*)d_in[20];
  const float* lnf_b  = (const float*)d_in[21];
  const float* Wf     = (const float*)d_in[22];
  const float* bf     = (const float*)d_in[23];
  float* out = (float*)d_out;

  float* h     = (float*)d_ws;              // 2,097,152 f32
  float* gates = h + 2097152;               // 65,536 f32
  float* gbuf  = gates + 65536;             // 32,768
  float* Mbuf  = gbuf + 32768;              // 32,768
  float* NFbuf = Mbuf + 32768;              // 32,768
  float* wgbuf = NFbuf + 32768;             // 32,768
  __bf16* hn   = (__bf16*)(wgbuf + 32768);  // 2,097,152 bf16
  __bf16* up   = hn + 2097152;              // 8,388,608
  __bf16* xc   = up + 8388608;              // 4,194,304
  __bf16* qk   = xc + 4194304;              // 8,388,608
  __bf16* vT   = qk + 8388608;              // 4,194,304
  __bf16* hd   = vT + 4194304;              // 4,194,304
  __bf16* WupT   = hd + 4194304;            // 1,048,576
  __bf16* WqkT   = WupT + 1048576;          // 2,097,152
  __bf16* WvT    = WqkT + 2097152;          // 1,048,576
  __bf16* WdownT = WvT + 1048576;           // 524,288

  prep_kernel<<<13824, 256, 0, stream>>>(
      x, tf, Wp, bp, ln_g, ln_b, Wup, Wq, Wk, Wv, Wdown, Wif,
      WupT, WqkT, WvT, WdownT, wgbuf, h, hn);
  for (int l = 0; l < NLAYER; ++l) {
    hgemm<128, 1, 0><<<dim3(64, 8), 256, 20480, stream>>>(
        hn, 256, WupT + (size_t)l * 262144, 256, bup + l * 1024, up, 1024);
    conv_silu_kernel<<<2048, 256, 0, stream>>>(up, conv_w + l * 2048, conv_b + l * 512,
                                               wgbuf + l * 8192, bif + l * 8, xc, gates);
    scan_kernel<<<32, 64, 0, stream>>>(gates, gbuf, Mbuf, NFbuf);
    qkv_kernel<<<dim3(64, 16), 256, 20480, stream>>>(
        xc, WqkT + (size_t)l * 524288, qk, up, WvT + (size_t)l * 262144, vT);
    attn_kernel<<<dim3(32, 8), 256, 0, stream>>>(
        qk, vT, gbuf, Mbuf, NFbuf, gn_g + l * 512, gn_b + l * 512, skip + l * 512,
        xc, up, hd);
    const float* lng = (l + 1 < NLAYER) ? (ln_g + (l + 1) * 256) : nullptr;
    const float* lnb = (l + 1 < NLAYER) ? (ln_b + (l + 1) * 256) : nullptr;
    dgemm_ln_kernel<<<256, 256, 0, stream>>>(
        hd, WdownT + (size_t)l * 131072, bdown + l * 256, h, lng, lnb, hn);
  }
  final_kernel<<<8, 256, 0, stream>>>(h, lnf_g, lnf_b, Wf, bf, out);
}

// Round 14
// 619.372 us; speedup vs baseline: 1.2637x; 1.0363x over previous
//
#include <hip/hip_runtime.h>
#include <hip/hip_bf16.h>
#include <math.h>

#define S 1024
#define NLAYER 4

typedef __bf16 bf16x8 __attribute__((ext_vector_type(8)));
typedef float floatx4 __attribute__((ext_vector_type(4)));

__device__ __forceinline__ float wave_sum(float v) {
  #pragma unroll
  for (int off = 32; off > 0; off >>= 1) v += __shfl_xor(v, off, 64);
  return v;
}

// ---------------- combined prep: weight transpose + Wg precompute + embed/LN ----------------
__device__ __forceinline__ void wtrans_body(
    int bid, const float* Wup, const float* Wq, const float* Wk, const float* Wv,
    const float* Wdown, __bf16* WupT, __bf16* WqkT, __bf16* WvT, __bf16* WdownT) {
  __shared__ float T[32][33];
  int layer = bid / 1152, rr = bid % 1152;
  const float* src; __bf16* dst; int K, N, tile;
  if (rr < 256)       { src = Wup   + layer * 262144; dst = WupT  + layer * 262144;          K = 256; N = 1024; tile = rr; }
  else if (rr < 512)  { src = Wq    + layer * 262144; dst = WqkT  + layer * 524288;          K = 512; N = 512;  tile = rr - 256; }
  else if (rr < 768)  { src = Wk    + layer * 262144; dst = WqkT  + layer * 524288 + 262144; K = 512; N = 512;  tile = rr - 512; }
  else if (rr < 1024) { src = Wv    + layer * 262144; dst = WvT   + layer * 262144;          K = 512; N = 512;  tile = rr - 768; }
  else                { src = Wdown + layer * 131072; dst = WdownT + layer * 131072;         K = 512; N = 256;  tile = rr - 1024; }
  int ntn = N >> 5;
  int tk = tile / ntn, tn = tile % ntn;
  int tid = threadIdx.x;
  int r = tid >> 3, c4 = (tid & 7) * 4;
  float4 v = *(const float4*)(src + (size_t)(tk * 32 + r) * N + tn * 32 + c4);
  T[c4 + 0][r] = v.x; T[c4 + 1][r] = v.y; T[c4 + 2][r] = v.z; T[c4 + 3][r] = v.w;
  __syncthreads();
  __bf16 o[4];
  #pragma unroll
  for (int j = 0; j < 4; ++j) o[j] = (__bf16)T[r][c4 + j];
  *(uint2*)(dst + (size_t)(tn * 32 + r) * K + tk * 32 + c4) = *(uint2*)o;
}

__device__ __forceinline__ void wgprep_body(
    int bid, const float* Wq, const float* Wk, const float* Wv,
    const float* Wif, float* wg) {
  int l = bid >> 8;
  int rem = bid & 255;
  int sel = rem >> 7;
  int kg = rem & 127;
  int tid = threadIdx.x;
  int wv = tid >> 6, lane = tid & 63;
  int k = kg * 4 + wv;
  const float* wif = Wif + (size_t)l * 1536 * 8;
  float part[8] = {0, 0, 0, 0, 0, 0, 0, 0};
  if (sel == 0) {
    const float* qr = Wq + (size_t)l * 262144 + (size_t)k * 512;
    const float* kr = Wk + (size_t)l * 262144 + (size_t)k * 512;
    #pragma unroll
    for (int i = 0; i < 8; ++i) {
      int n = lane + i * 64;
      float qv = qr[n], kv = kr[n];
      const float* wq8 = wif + (size_t)n * 8;
      const float* wk8 = wif + (size_t)(512 + n) * 8;
      #pragma unroll
      for (int j = 0; j < 8; ++j) part[j] += qv * wq8[j] + kv * wk8[j];
    }
  } else {
    const float* vr = Wv + (size_t)l * 262144 + (size_t)k * 512;
    #pragma unroll
    for (int i = 0; i < 8; ++i) {
      int n = lane + i * 64;
      float vv = vr[n];
      const float* wv8 = wif + (size_t)(1024 + n) * 8;
      #pragma unroll
      for (int j = 0; j < 8; ++j) part[j] += vv * wv8[j];
    }
  }
  #pragma unroll
  for (int j = 0; j < 8; ++j) part[j] = wave_sum(part[j]);
  if (lane < 8) wg[(size_t)l * 8192 + sel * 4096 + (size_t)k * 8 + lane] = part[lane];
}

__device__ __forceinline__ void embed_body(
    int row, const float* x, const float* tf, const float* Wp, const float* bp,
    const float* g, const float* b, float* h, __bf16* hn) {
  int n = threadIdx.x;
  float xv = x[row];
  const float* t4 = tf + (size_t)row * 4;
  float acc = bp[n] + xv * Wp[n];
  acc += t4[0] * Wp[256 + n];
  acc += t4[1] * Wp[512 + n];
  acc += t4[2] * Wp[768 + n];
  acc += t4[3] * Wp[1024 + n];
  h[(size_t)row * 256 + n] = acc;
  __shared__ float red[4];
  int wid = n >> 6, lane = n & 63;
  float s = wave_sum(acc);
  if (lane == 0) red[wid] = s;
  __syncthreads();
  float mu = (red[0] + red[1] + red[2] + red[3]) * (1.f / 256.f);
  __syncthreads();
  float d = acc - mu;
  float s2 = wave_sum(d * d);
  if (lane == 0) red[wid] = s2;
  __syncthreads();
  float var = (red[0] + red[1] + red[2] + red[3]) * (1.f / 256.f);
  float rs = rsqrtf(var + 1e-5f);
  hn[(size_t)row * 256 + n] = (__bf16)(d * rs * g[n] + b[n]);
}

__global__ __launch_bounds__(256) void prep_kernel(
    const float* __restrict__ x, const float* __restrict__ tf,
    const float* __restrict__ Wp, const float* __restrict__ bp,
    const float* __restrict__ ln_g, const float* __restrict__ ln_b,
    const float* __restrict__ Wup, const float* __restrict__ Wq,
    const float* __restrict__ Wk, const float* __restrict__ Wv,
    const float* __restrict__ Wdown, const float* __restrict__ Wif,
    __bf16* __restrict__ WupT, __bf16* __restrict__ WqkT,
    __bf16* __restrict__ WvT, __bf16* __restrict__ WdownT,
    float* __restrict__ wg, float* __restrict__ h, __bf16* __restrict__ hn) {
  int bid = blockIdx.x;
  if (bid < 4608) {
    wtrans_body(bid, Wup, Wq, Wk, Wv, Wdown, WupT, WqkT, WvT, WdownT);
  } else if (bid < 4608 + 1024) {
    wgprep_body(bid - 4608, Wq, Wk, Wv, Wif, wg);
  } else {
    embed_body(bid - 5632, x, tf, Wp, bp, ln_g, ln_b, h, hn);
  }
}

// ---------------- bf16 MFMA GEMM body: TM x 128 tile, register prefetch ----------------
template <int TM, int MODE, int ACC>
__device__ __forceinline__ void hgemm_body(
    char* smem_raw,
    const __bf16* __restrict__ A, int lda,
    const __bf16* __restrict__ BT, int Kdim,
    const float* __restrict__ bias,
    void* __restrict__ Cout, int ldc, int bxi, int byi) {
  auto As = (__bf16(*)[40])smem_raw;
  auto Bs = (__bf16(*)[40])(smem_raw + (size_t)TM * 80);
  int tid = threadIdx.x;
  int bm = bxi * TM, bn = byi * 128;
  int wid = tid >> 6, lane = tid & 63;
  int wr = wid >> 1, wc = wid & 1;
  int lg = lane >> 4, li = lane & 15;
  constexpr int MI = TM / 32;
  constexpr int WROW = TM / 2;
  floatx4 acc[MI][4];
  #pragma unroll
  for (int i = 0; i < MI; ++i)
    #pragma unroll
    for (int j = 0; j < 4; ++j) acc[i][j] = (floatx4)(0.f);

  int arow = tid >> 2, aseg = tid & 3;
  bf16x8 pa0, pa1, pb0, pb1;
  auto pre = [&](int k0) {
    pa0 = *(const bf16x8*)(A + (size_t)(bm + arow) * lda + k0 + aseg * 8);
    if constexpr (TM == 128)
      pa1 = *(const bf16x8*)(A + (size_t)(bm + arow + 64) * lda + k0 + aseg * 8);
    pb0 = *(const bf16x8*)(BT + (size_t)(bn + arow) * Kdim + k0 + aseg * 8);
    pb1 = *(const bf16x8*)(BT + (size_t)(bn + arow + 64) * Kdim + k0 + aseg * 8);
  };
  pre(0);
  for (int k0 = 0; k0 < Kdim; k0 += 32) {
    __syncthreads();
    *(bf16x8*)&As[arow][aseg * 8] = pa0;
    if constexpr (TM == 128) *(bf16x8*)&As[arow + 64][aseg * 8] = pa1;
    *(bf16x8*)&Bs[arow][aseg * 8] = pb0;
    *(bf16x8*)&Bs[arow + 64][aseg * 8] = pb1;
    __syncthreads();
    if (k0 + 32 < Kdim) pre(k0 + 32);
    bf16x8 af[MI], bfr[4];
    #pragma unroll
    for (int mi = 0; mi < MI; ++mi)
      af[mi] = *(const bf16x8*)&As[wr * WROW + mi * 16 + li][lg * 8];
    #pragma unroll
    for (int ni = 0; ni < 4; ++ni)
      bfr[ni] = *(const bf16x8*)&Bs[wc * 64 + ni * 16 + li][lg * 8];
    #pragma unroll
    for (int mi = 0; mi < MI; ++mi)
      #pragma unroll
      for (int ni = 0; ni < 4; ++ni)
        acc[mi][ni] = __builtin_amdgcn_mfma_f32_16x16x32_bf16(af[mi], bfr[ni], acc[mi][ni], 0, 0, 0);
  }
  if constexpr (MODE == 1) {
    __bf16* eb = (__bf16*)smem_raw;
    const int PITCH = 136;
    __bf16* C = (__bf16*)Cout;
    #pragma unroll
    for (int mi = 0; mi < MI; ++mi) {
      __syncthreads();
      #pragma unroll
      for (int ni = 0; ni < 4; ++ni) {
        int col = wc * 64 + ni * 16 + li;
        float bz = bias ? bias[bn + col] : 0.f;
        #pragma unroll
        for (int r = 0; r < 4; ++r) {
          int lr = wr * 16 + lg * 4 + r;
          eb[lr * PITCH + col] = (__bf16)(acc[mi][ni][r] + bz);
        }
      }
      __syncthreads();
      #pragma unroll
      for (int i = 0; i < 2; ++i) {
        int lr = (tid >> 4) + i * 16;
        int c8 = (tid & 15) * 8;
        bf16x8 v = *(const bf16x8*)&eb[lr * PITCH + c8];
        int row_g = bm + (lr >> 4) * 64 + mi * 16 + (lr & 15);
        *(bf16x8*)(C + (size_t)row_g * ldc + bn + c8) = v;
      }
    }
  } else {
    #pragma unroll
    for (int mi = 0; mi < MI; ++mi) {
      int row = bm + wr * WROW + mi * 16 + lg * 4;
      #pragma unroll
      for (int ni = 0; ni < 4; ++ni) {
        int col = bn + wc * 64 + ni * 16 + li;
        if constexpr (MODE == 2) {
          __bf16 o4[4];
          #pragma unroll
          for (int r = 0; r < 4; ++r) o4[r] = (__bf16)acc[mi][ni][r];
          __bf16* vt = (__bf16*)Cout;
          size_t off = ((size_t)((row >> 10) * 4 + (col >> 7)) * 128 + (col & 127)) * 1024 + (row & 1023);
          *(uint2*)(vt + off) = *(uint2*)o4;
        } else {
          float bz = bias ? bias[col] : 0.f;
          float* C = (float*)Cout;
          #pragma unroll
          for (int r = 0; r < 4; ++r) {
            float v = acc[mi][ni][r] + bz;
            if (ACC) v += C[(size_t)(row + r) * ldc + col];
            C[(size_t)(row + r) * ldc + col] = v;
          }
        }
      }
    }
  }
}

template <int TM, int MODE, int ACC>
__global__ __launch_bounds__(256) void hgemm(
    const __bf16* __restrict__ A, int lda,
    const __bf16* __restrict__ BT, int Kdim,
    const float* __restrict__ bias,
    void* __restrict__ Cout, int ldc) {
  extern __shared__ char smem[];
  hgemm_body<TM, MODE, ACC>(smem, A, lda, BT, Kdim, bias, Cout, ldc,
                            blockIdx.x, blockIdx.y);
}

// ---------------- per-(b,h) gate scan body: one wave ----------------
__device__ __forceinline__ void scan_body(
    int bh, int lane, const float* __restrict__ gates, float* __restrict__ gout,
    float* __restrict__ Mout, float* __restrict__ NFout) {
  int bb = bh >> 2, hh = bh & 3;
  float ip[16], pf[16];
  #pragma unroll
  for (int i = 0; i < 16; ++i) {
    int t = lane * 16 + i;
    const float* grow = gates + ((size_t)(bb * S + t)) * 8;
    ip[i] = grow[hh];
    float fp = grow[4 + hh];
    float lf = fminf(fp, 0.f) - log1pf(__expf(-fabsf(fp)));
    pf[i] = (i == 0) ? lf : pf[i - 1] + lf;
  }
  float T = pf[15];
  float inc = T;
  #pragma unroll
  for (int off = 1; off < 64; off <<= 1) {
    float v = __shfl_up(inc, off, 64);
    if (lane >= off) inc += v;
  }
  float excl = inc - T;
  float F[16], g[16], pm[16];
  #pragma unroll
  for (int i = 0; i < 16; ++i) {
    F[i] = excl + pf[i];
    g[i] = ip[i] - F[i];
    pm[i] = (i == 0) ? g[0] : fmaxf(pm[i - 1], g[i]);
  }
  float Mx = pm[15];
  float incm = Mx;
  #pragma unroll
  for (int off = 1; off < 64; off <<= 1) {
    float v = __shfl_up(incm, off, 64);
    if (lane >= off) incm = fmaxf(incm, v);
  }
  float em = __shfl_up(incm, 1, 64);
  if (lane == 0) em = -3.4e38f;
  #pragma unroll
  for (int i = 0; i < 16; ++i) {
    int t = lane * 16 + i;
    size_t o = (size_t)bh * S + t;
    float M = fmaxf(em, pm[i]);
    gout[o] = g[i];
    Mout[o] = M;
    NFout[o] = __expf(-F[i] - M);
  }
}

// Merged QK + V GEMM + gate scan: grid (64, 17).
// by<8 -> qk (128-tile); 8<=by<16 -> vT (64-tile); by==16, bx<32 -> scan.
__global__ __launch_bounds__(256) void qkv_kernel(
    const __bf16* __restrict__ xc, const __bf16* __restrict__ WqkT,
    __bf16* __restrict__ qk, const __bf16* __restrict__ up,
    const __bf16* __restrict__ WvT, __bf16* __restrict__ vT,
    const float* __restrict__ gates, float* __restrict__ gbuf,
    float* __restrict__ Mbuf, float* __restrict__ NFbuf) {
  extern __shared__ char smem[];
  if (blockIdx.y < 8) {
    hgemm_body<128, 1, 0>(smem, xc, 512, WqkT, 512, nullptr, qk, 1024,
                          blockIdx.x, blockIdx.y);
  } else if (blockIdx.y < 16) {
    int j = blockIdx.y - 8;
    hgemm_body<64, 2, 0>(smem, up, 1024, WvT, 512, nullptr, vT, 0,
                         blockIdx.x * 2 + (j & 1), j >> 1);
  } else {
    if (blockIdx.x < 32 && threadIdx.x < 64)
      scan_body(blockIdx.x, threadIdx.x, gates, gbuf, Mbuf, NFbuf);
  }
}

// ---------------- down-proj GEMM (32x256 tile) + residual + fused next-layer LN ----------------
__global__ __launch_bounds__(256) void dgemm_ln_kernel(
    const __bf16* __restrict__ A, const __bf16* __restrict__ BT,
    const float* __restrict__ bias, float* __restrict__ h,
    const float* __restrict__ lng, const float* __restrict__ lnb,
    __bf16* __restrict__ hn) {
  __shared__ __bf16 As[32][40];
  __shared__ __bf16 Bs[256][40];
  __shared__ float redS[2][32], redQ[2][32];
  int tid = threadIdx.x;
  int bm = blockIdx.x * 32;
  int wid = tid >> 6, lane = tid & 63;
  int wr = wid >> 1, wc = wid & 1;
  int lg = lane >> 4, li = lane & 15;
  floatx4 acc[8];
  #pragma unroll
  for (int j = 0; j < 8; ++j) acc[j] = (floatx4)(0.f);

  int arow = tid >> 2, aseg = tid & 3;
  bf16x8 pa, pb[4];
  auto pre = [&](int k0) {
    if (tid < 128)
      pa = *(const bf16x8*)(A + (size_t)(bm + arow) * 512 + k0 + aseg * 8);
    #pragma unroll
    for (int i = 0; i < 4; ++i)
      pb[i] = *(const bf16x8*)(BT + (size_t)(arow + i * 64) * 512 + k0 + aseg * 8);
  };
  pre(0);
  for (int k0 = 0; k0 < 512; k0 += 32) {
    __syncthreads();
    if (tid < 128) *(bf16x8*)&As[arow][aseg * 8] = pa;
    #pragma unroll
    for (int i = 0; i < 4; ++i) *(bf16x8*)&Bs[arow + i * 64][aseg * 8] = pb[i];
    __syncthreads();
    if (k0 + 32 < 512) pre(k0 + 32);
    bf16x8 af = *(const bf16x8*)&As[wr * 16 + li][lg * 8];
    #pragma unroll
    for (int ni = 0; ni < 8; ++ni) {
      bf16x8 bfr = *(const bf16x8*)&Bs[wc * 128 + ni * 16 + li][lg * 8];
      acc[ni] = __builtin_amdgcn_mfma_f32_16x16x32_bf16(af, bfr, acc[ni], 0, 0, 0);
    }
  }
  #pragma unroll
  for (int r = 0; r < 4; ++r) {
    int lr = wr * 16 + lg * 4 + r;
    int row = bm + lr;
    float s1 = 0.f, s2 = 0.f;
    #pragma unroll
    for (int ni = 0; ni < 8; ++ni) {
      int col = wc * 128 + ni * 16 + li;
      float v = acc[ni][r] + bias[col] + h[(size_t)row * 256 + col];
      acc[ni][r] = v;
      h[(size_t)row * 256 + col] = v;
      s1 += v;
      s2 += v * v;
    }
    s1 += __shfl_xor(s1, 1, 64); s1 += __shfl_xor(s1, 2, 64);
    s1 += __shfl_xor(s1, 4, 64); s1 += __shfl_xor(s1, 8, 64);
    s2 += __shfl_xor(s2, 1, 64); s2 += __shfl_xor(s2, 2, 64);
    s2 += __shfl_xor(s2, 4, 64); s2 += __shfl_xor(s2, 8, 64);
    if (li == 0) { redS[wc][lr] = s1; redQ[wc][lr] = s2; }
  }
  if (!lng) return;
  __syncthreads();
  #pragma unroll
  for (int r = 0; r < 4; ++r) {
    int lr = wr * 16 + lg * 4 + r;
    int row = bm + lr;
    float s1 = redS[0][lr] + redS[1][lr];
    float s2 = redQ[0][lr] + redQ[1][lr];
    float mu = s1 * (1.f / 256.f);
    float var = s2 * (1.f / 256.f) - mu * mu;
    float rs = rsqrtf(var + 1e-5f);
    #pragma unroll
    for (int ni = 0; ni < 8; ++ni) {
      int col = wc * 128 + ni * 16 + li;
      hn[(size_t)row * 256 + col] = (__bf16)((acc[ni][r] - mu) * rs * lng[col] + lnb[col]);
    }
  }
}

// ---------------- causal conv (K=4) + SiLU + fused gate projection ----------------
__global__ __launch_bounds__(256) void conv_silu_kernel(
    const __bf16* __restrict__ up, const float* __restrict__ cw,
    const float* __restrict__ cb, const float* __restrict__ wg,
    const float* __restrict__ bif, __bf16* __restrict__ xc,
    float* __restrict__ gates) {
  int tid = threadIdx.x;
  int wv = tid >> 6, lane = tid & 63;
  int row = blockIdx.x * 4 + wv;
  int c8 = lane * 8;
  int t = row & (S - 1);
  float acc[8];
  *(float4*)&acc[0] = *(const float4*)(cb + c8);
  *(float4*)&acc[4] = *(const float4*)(cb + c8 + 4);
  float xm[8];
  #pragma unroll
  for (int j = 0; j < 4; ++j) {
    int tt = t - 3 + j;
    if (tt >= 0) {
      bf16x8 xv = *(const bf16x8*)(up + (size_t)(row - 3 + j) * 1024 + c8);
      float4 w0 = *(const float4*)(cw + j * 512 + c8);
      float4 w1 = *(const float4*)(cw + j * 512 + c8 + 4);
      acc[0] += w0.x * (float)xv[0]; acc[1] += w0.y * (float)xv[1];
      acc[2] += w0.z * (float)xv[2]; acc[3] += w0.w * (float)xv[3];
      acc[4] += w1.x * (float)xv[4]; acc[5] += w1.y * (float)xv[5];
      acc[6] += w1.z * (float)xv[6]; acc[7] += w1.w * (float)xv[7];
      if (j == 3) {
        #pragma unroll
        for (int m = 0; m < 8; ++m) xm[m] = (float)xv[m];
      }
    }
  }
  bf16x8 o;
  float xcs[8];
  #pragma unroll
  for (int m = 0; m < 8; ++m) {
    float sg = 1.f / (1.f + __expf(-acc[m]));
    xcs[m] = acc[m] * sg;
    o[m] = (__bf16)xcs[m];
  }
  *(bf16x8*)(xc + (size_t)row * 512 + c8) = o;
  const float* w1 = wg + (size_t)c8 * 8;
  const float* w2 = wg + 4096 + (size_t)c8 * 8;
  float part[8] = {0, 0, 0, 0, 0, 0, 0, 0};
  #pragma unroll
  for (int m = 0; m < 8; ++m) {
    const float* a = w1 + m * 8;
    const float* b = w2 + m * 8;
    #pragma unroll
    for (int j = 0; j < 8; ++j) part[j] += xcs[m] * a[j] + xm[m] * b[j];
  }
  #pragma unroll
  for (int j = 0; j < 8; ++j) part[j] = wave_sum(part[j]);
  if (lane < 8) gates[(size_t)row * 8 + lane] = part[lane] + bif[lane];
}

// ---------------- MFMA mLSTM attention (512 threads, 8 waves: 4 per q-tile) ----------------
// grid (bh=32, px=8): XCD-local K/V. Waves 0-3 own tile A rows, waves 4-7 tile B rows.
__global__ __launch_bounds__(512, 1) void attn_kernel(
    const __bf16* __restrict__ qk, const __bf16* __restrict__ vT,
    const float* __restrict__ gbuf, const float* __restrict__ Mbuf,
    const float* __restrict__ NFbuf,
    const float* __restrict__ gn_g, const float* __restrict__ gn_b,
    const float* __restrict__ skip,
    const __bf16* __restrict__ xc, const __bf16* __restrict__ up,
    __bf16* __restrict__ hd) {
  __shared__ __bf16 Ks[64][136];
  __shared__ __bf16 Vs[128][72];
  __shared__ __bf16 plds[8][16][72];
  __shared__ float gls[64];
  __shared__ float glds[128], blds[128], slds[128];
  int px = blockIdx.y, bh = blockIdx.x;
  int tqA = px, tqB = 15 - px;
  int bb = bh >> 2, hh = bh & 3;
  int tid = threadIdx.x;
  int wv = tid >> 6, lane = tid & 63;
  int sel = wv >> 2, wl = wv & 3;
  int lg = lane >> 4, li = lane & 15;
  int tq = (sel == 0) ? tqA : tqB;
  int tb = tq * 64 + wl * 16;
  const float scale = 0.08838834764831845f;

  if (tid < 128) {
    glds[tid] = gn_g[hh * 128 + tid];
    blds[tid] = gn_b[hh * 128 + tid];
    slds[tid] = skip[hh * 128 + tid];
  }

  // Q fragments for this wave's 16 rows
  bf16x8 aq[4];
  {
    const __bf16* qp = qk + ((size_t)(bb * S + tb + li)) * 1024 + hh * 128 + lg * 8;
    #pragma unroll
    for (int cd = 0; cd < 4; ++cd) aq[cd] = *(const bf16x8*)(qp + cd * 32);
  }
  float ml[4], nf[4];
  #pragma unroll
  for (int r = 0; r < 4; ++r) {
    ml[r] = Mbuf[(size_t)bh * S + tb + lg * 4 + r];
    nf[r] = NFbuf[(size_t)bh * S + tb + lg * 4 + r];
  }

  floatx4 oacc[8];
  #pragma unroll
  for (int df = 0; df < 8; ++df) oacc[df] = (floatx4)(0.f);
  float rs[4] = {0, 0, 0, 0};

  // staging: 512 threads; krow = tid>>3 in 0..63, kcol = tid&7
  int krow = tid >> 3, kcol = tid & 7;
  bf16x8 kreg0, kreg1, vreg0, vreg1;
  float greg = 0.f;
  auto preload = [&](int st) {
    int s0 = st * 64;
    const __bf16* kp = qk + ((size_t)(bb * S + s0 + krow)) * 1024 + 512 + hh * 128;
    kreg0 = *(const bf16x8*)(kp + kcol * 8);
    kreg1 = *(const bf16x8*)(kp + 64 + kcol * 8);
    vreg0 = *(const bf16x8*)(vT + ((size_t)(bh * 128 + krow)) * 1024 + s0 + kcol * 8);
    vreg1 = *(const bf16x8*)(vT + ((size_t)(bh * 128 + 64 + krow)) * 1024 + s0 + kcol * 8);
    if (tid < 64) greg = gbuf[(size_t)bh * S + s0 + tid];
  };
  preload(0);

  for (int st = 0; st <= tqB; ++st) {
    __syncthreads();
    *(bf16x8*)&Ks[krow][kcol * 8] = kreg0;
    *(bf16x8*)&Ks[krow][64 + kcol * 8] = kreg1;
    *(bf16x8*)&Vs[krow][kcol * 8] = vreg0;
    *(bf16x8*)&Vs[64 + krow][kcol * 8] = vreg1;
    if (tid < 64) gls[tid] = greg;
    __syncthreads();
    if (st < tqB) preload(st + 1);

    if (st <= tq) {
      int s0 = st * 64;
      #pragma unroll
      for (int ns = 0; ns < 4; ++ns) {
        bf16x8 bk0 = *(const bf16x8*)&Ks[ns * 16 + li][lg * 8];
        bf16x8 bk1 = *(const bf16x8*)&Ks[ns * 16 + li][32 + lg * 8];
        bf16x8 bk2 = *(const bf16x8*)&Ks[ns * 16 + li][64 + lg * 8];
        bf16x8 bk3 = *(const bf16x8*)&Ks[ns * 16 + li][96 + lg * 8];
        int s = s0 + ns * 16 + li;
        float gv = gls[ns * 16 + li];
        floatx4 pa = (floatx4)(0.f);
        pa = __builtin_amdgcn_mfma_f32_16x16x32_bf16(aq[0], bk0, pa, 0, 0, 0);
        pa = __builtin_amdgcn_mfma_f32_16x16x32_bf16(aq[1], bk1, pa, 0, 0, 0);
        pa = __builtin_amdgcn_mfma_f32_16x16x32_bf16(aq[2], bk2, pa, 0, 0, 0);
        pa = __builtin_amdgcn_mfma_f32_16x16x32_bf16(aq[3], bk3, pa, 0, 0, 0);
        #pragma unroll
        for (int r = 0; r < 4; ++r) {
          int t = tb + lg * 4 + r;
          float val = pa[r] * scale * __expf(gv - ml[r]);
          float w = (s <= t) ? val : 0.f;
          rs[r] += w;
          plds[wv][lg * 4 + r][ns * 16 + li] = (__bf16)w;
        }
      }
      bf16x8 ap0 = *(const bf16x8*)&plds[wv][li][lg * 8];
      bf16x8 ap1 = *(const bf16x8*)&plds[wv][li][32 + lg * 8];
      #pragma unroll
      for (int df = 0; df < 8; ++df) {
        bf16x8 bv0 = *(const bf16x8*)&Vs[df * 16 + li][lg * 8];
        bf16x8 bv1 = *(const bf16x8*)&Vs[df * 16 + li][32 + lg * 8];
        oacc[df] = __builtin_amdgcn_mfma_f32_16x16x32_bf16(ap0, bv0, oacc[df], 0, 0, 0);
        oacc[df] = __builtin_amdgcn_mfma_f32_16x16x32_bf16(ap1, bv1, oacc[df], 0, 0, 0);
      }
    }
  }
  // row-sum reduce across the 16 col-lanes
  #pragma unroll
  for (int r = 0; r < 4; ++r) {
    float a = rs[r];
    a += __shfl_xor(a, 1, 64); a += __shfl_xor(a, 2, 64);
    a += __shfl_xor(a, 4, 64); a += __shfl_xor(a, 8, 64);
    rs[r] = a;
  }
  // fused epilogue: normalize + GroupNorm(128) + skip*xc + *silu(z)
  #pragma unroll
  for (int r = 0; r < 4; ++r) {
    float inv = 1.f / (fmaxf(fabsf(rs[r]), nf[r]) + 1e-6f);
    float v8[8], s1 = 0.f, s2 = 0.f;
    #pragma unroll
    for (int df = 0; df < 8; ++df) {
      float v = oacc[df][r] * inv;
      v8[df] = v;
      s1 += v;
      s2 += v * v;
    }
    s1 += __shfl_xor(s1, 1, 64); s1 += __shfl_xor(s1, 2, 64);
    s1 += __shfl_xor(s1, 4, 64); s1 += __shfl_xor(s1, 8, 64);
    s2 += __shfl_xor(s2, 1, 64); s2 += __shfl_xor(s2, 2, 64);
    s2 += __shfl_xor(s2, 4, 64); s2 += __shfl_xor(s2, 8, 64);
    float mu = s1 * (1.f / 128.f);
    float var = s2 * (1.f / 128.f) - mu * mu;
    float rq = rsqrtf(var + 1e-5f);
    int t = tb + lg * 4 + r;
    const __bf16* xr = xc + ((size_t)(bb * S + t)) * 512 + hh * 128 + li;
    const __bf16* zr = up + ((size_t)(bb * S + t)) * 1024 + 512 + hh * 128 + li;
    __bf16* od = hd + ((size_t)(bb * S + t)) * 512 + hh * 128 + li;
    #pragma unroll
    for (int df = 0; df < 8; ++df) {
      int c = df * 16 + li;
      float ln = (v8[df] - mu) * rq * glds[c] + blds[c];
      float val = ln + slds[c] * (float)xr[df * 16];
      float z = (float)zr[df * 16];
      float sg = 1.f / (1.f + __expf(-z));
      od[df * 16] = (__bf16)(val * (z * sg));
    }
  }
}

// ---------------- final LN + head ----------------
__global__ __launch_bounds__(256) void final_kernel(
    const float* __restrict__ h, const float* __restrict__ g,
    const float* __restrict__ b, const float* __restrict__ Wf,
    const float* __restrict__ bf, float* __restrict__ out) {
  int bb = blockIdx.x, tid = threadIdx.x;
  size_t row = (size_t)(bb * S + S - 1) * 256;
  __shared__ float red[4];
  float v = h[row + tid];
  float s = wave_sum(v);
  int wid = tid >> 6, lane = tid & 63;
  if (lane == 0) red[wid] = s;
  __syncthreads();
  float mu = (red[0] + red[1] + red[2] + red[3]) * (1.f / 256.f);
  __syncthreads();
  float d = v - mu;
  float s2 = wave_sum(d * d);
  if (lane == 0) red[wid] = s2;
  __syncthreads();
  float var = (red[0] + red[1] + red[2] + red[3]) * (1.f / 256.f);
  float rs = rsqrtf(var + 1e-5f);
  float ln = d * rs * g[tid] + b[tid];
  float p = ln * Wf[tid];
  float psum = wave_sum(p);
  __syncthreads();
  if (lane == 0) red[wid] = psum;
  __syncthreads();
  if (tid == 0) out[bb] = red[0] + red[1] + red[2] + red[3] + bf[0];
}

extern "C" void kernel_launch(void* const* d_in, const int* in_sizes, int n_in,
                              void* d_out, int out_size, void* d_ws, size_t ws_size,
                              hipStream_t stream) {
  const float* x      = (const float*)d_in[0];
  const float* tf     = (const float*)d_in[1];
  const float* Wp     = (const float*)d_in[2];
  const float* bp     = (const float*)d_in[3];
  const float* ln_g   = (const float*)d_in[4];
  const float* ln_b   = (const float*)d_in[5];
  const float* Wup    = (const float*)d_in[6];
  const float* bup    = (const float*)d_in[7];
  const float* conv_w = (const float*)d_in[8];
  const float* conv_b = (const float*)d_in[9];
  const float* Wq     = (const float*)d_in[10];
  const float* Wk     = (const float*)d_in[11];
  const float* Wv     = (const float*)d_in[12];
  const float* Wif    = (const float*)d_in[13];
  const float* bif    = (const float*)d_in[14];
  const float* gn_g   = (const float*)d_in[15];
  const float* gn_b   = (const float*)d_in[16];
  const float* skip   = (const float*)d_in[17];
  const float* Wdown  = (const float*)d_in[18];
  const float* bdown  = (const float*)d_in[19];
  const float* lnf_g  = (const float*)d_in[20];
  const float* lnf_b  = (const float*)d_in[21];
  const float* Wf     = (const float*)d_in[22];
  const float* bf     = (const float*)d_in[23];
  float* out = (float*)d_out;

  float* h     = (float*)d_ws;              // 2,097,152 f32
  float* gates = h + 2097152;               // 65,536 f32
  float* gbuf  = gates + 65536;             // 32,768
  float* Mbuf  = gbuf + 32768;              // 32,768
  float* NFbuf = Mbuf + 32768;              // 32,768
  float* wgbuf = NFbuf + 32768;             // 32,768
  __bf16* hn   = (__bf16*)(wgbuf + 32768);  // 2,097,152 bf16
  __bf16* up   = hn + 2097152;              // 8,388,608
  __bf16* xc   = up + 8388608;              // 4,194,304
  __bf16* qk   = xc + 4194304;              // 8,388,608
  __bf16* vT   = qk + 8388608;              // 4,194,304
  __bf16* hd   = vT + 4194304;              // 4,194,304
  __bf16* WupT   = hd + 4194304;            // 1,048,576
  __bf16* WqkT   = WupT + 1048576;          // 2,097,152
  __bf16* WvT    = WqkT + 2097152;          // 1,048,576
  __bf16* WdownT = WvT + 1048576;           // 524,288

  prep_kernel<<<13824, 256, 0, stream>>>(
      x, tf, Wp, bp, ln_g, ln_b, Wup, Wq, Wk, Wv, Wdown, Wif,
      WupT, WqkT, WvT, WdownT, wgbuf, h, hn);
  for (int l = 0; l < NLAYER; ++l) {
    hgemm<128, 1, 0><<<dim3(64, 8), 256, 20480, stream>>>(
        hn, 256, WupT + (size_t)l * 262144, 256, bup + l * 1024, up, 1024);
    conv_silu_kernel<<<2048, 256, 0, stream>>>(up, conv_w + l * 2048, conv_b + l * 512,
                                               wgbuf + l * 8192, bif + l * 8, xc, gates);
    qkv_kernel<<<dim3(64, 17), 256, 20480, stream>>>(
        xc, WqkT + (size_t)l * 524288, qk, up, WvT + (size_t)l * 262144, vT,
        gates, gbuf, Mbuf, NFbuf);
    attn_kernel<<<dim3(32, 8), 512, 0, stream>>>(
        qk, vT, gbuf, Mbuf, NFbuf, gn_g + l * 512, gn_b + l * 512, skip + l * 512,
        xc, up, hd);
    const float* lng = (l + 1 < NLAYER) ? (ln_g + (l + 1) * 256) : nullptr;
    const float* lnb = (l + 1 < NLAYER) ? (ln_b + (l + 1) * 256) : nullptr;
    dgemm_ln_kernel<<<256, 256, 0, stream>>>(
        hd, WdownT + (size_t)l * 131072, bdown + l * 256, h, lng, lnb, hn);
  }
  final_kernel<<<8, 256, 0, stream>>>(h, lnf_g, lnf_b, Wf, bf, out);
}

// Round 15
// 593.904 us; speedup vs baseline: 1.3179x; 1.0429x over previous
//
#include <hip/hip_runtime.h>
#include <hip/hip_bf16.h>
#include <math.h>

#define S 1024
#define NLAYER 4

typedef __bf16 bf16x8 __attribute__((ext_vector_type(8)));
typedef float floatx4 __attribute__((ext_vector_type(4)));

__device__ __forceinline__ float wave_sum(float v) {
  #pragma unroll
  for (int off = 32; off > 0; off >>= 1) v += __shfl_xor(v, off, 64);
  return v;
}

// ---------------- combined prep: weight transpose + Wg precompute + embed/LN ----------------
__device__ __forceinline__ void wtrans_body(
    int bid, const float* Wup, const float* Wq, const float* Wk, const float* Wv,
    const float* Wdown, __bf16* WupT, __bf16* WqkT, __bf16* WvT, __bf16* WdownT) {
  __shared__ float T[32][33];
  int layer = bid / 1152, rr = bid % 1152;
  const float* src; __bf16* dst; int K, N, tile;
  if (rr < 256)       { src = Wup   + layer * 262144; dst = WupT  + layer * 262144;          K = 256; N = 1024; tile = rr; }
  else if (rr < 512)  { src = Wq    + layer * 262144; dst = WqkT  + layer * 524288;          K = 512; N = 512;  tile = rr - 256; }
  else if (rr < 768)  { src = Wk    + layer * 262144; dst = WqkT  + layer * 524288 + 262144; K = 512; N = 512;  tile = rr - 512; }
  else if (rr < 1024) { src = Wv    + layer * 262144; dst = WvT   + layer * 262144;          K = 512; N = 512;  tile = rr - 768; }
  else                { src = Wdown + layer * 131072; dst = WdownT + layer * 131072;         K = 512; N = 256;  tile = rr - 1024; }
  int ntn = N >> 5;
  int tk = tile / ntn, tn = tile % ntn;
  int tid = threadIdx.x;
  int r = tid >> 3, c4 = (tid & 7) * 4;
  float4 v = *(const float4*)(src + (size_t)(tk * 32 + r) * N + tn * 32 + c4);
  T[c4 + 0][r] = v.x; T[c4 + 1][r] = v.y; T[c4 + 2][r] = v.z; T[c4 + 3][r] = v.w;
  __syncthreads();
  __bf16 o[4];
  #pragma unroll
  for (int j = 0; j < 4; ++j) o[j] = (__bf16)T[r][c4 + j];
  *(uint2*)(dst + (size_t)(tn * 32 + r) * K + tk * 32 + c4) = *(uint2*)o;
}

__device__ __forceinline__ void wgprep_body(
    int bid, const float* Wq, const float* Wk, const float* Wv,
    const float* Wif, float* wg) {
  int l = bid >> 8;
  int rem = bid & 255;
  int sel = rem >> 7;
  int kg = rem & 127;
  int tid = threadIdx.x;
  int wv = tid >> 6, lane = tid & 63;
  int k = kg * 4 + wv;
  const float* wif = Wif + (size_t)l * 1536 * 8;
  float part[8] = {0, 0, 0, 0, 0, 0, 0, 0};
  if (sel == 0) {
    const float* qr = Wq + (size_t)l * 262144 + (size_t)k * 512;
    const float* kr = Wk + (size_t)l * 262144 + (size_t)k * 512;
    #pragma unroll
    for (int i = 0; i < 8; ++i) {
      int n = lane + i * 64;
      float qv = qr[n], kv = kr[n];
      const float* wq8 = wif + (size_t)n * 8;
      const float* wk8 = wif + (size_t)(512 + n) * 8;
      #pragma unroll
      for (int j = 0; j < 8; ++j) part[j] += qv * wq8[j] + kv * wk8[j];
    }
  } else {
    const float* vr = Wv + (size_t)l * 262144 + (size_t)k * 512;
    #pragma unroll
    for (int i = 0; i < 8; ++i) {
      int n = lane + i * 64;
      float vv = vr[n];
      const float* wv8 = wif + (size_t)(1024 + n) * 8;
      #pragma unroll
      for (int j = 0; j < 8; ++j) part[j] += vv * wv8[j];
    }
  }
  #pragma unroll
  for (int j = 0; j < 8; ++j) part[j] = wave_sum(part[j]);
  if (lane < 8) wg[(size_t)l * 8192 + sel * 4096 + (size_t)k * 8 + lane] = part[lane];
}

__device__ __forceinline__ void embed_body(
    int row, const float* x, const float* tf, const float* Wp, const float* bp,
    const float* g, const float* b, float* h, __bf16* hn) {
  int n = threadIdx.x;
  float xv = x[row];
  const float* t4 = tf + (size_t)row * 4;
  float acc = bp[n] + xv * Wp[n];
  acc += t4[0] * Wp[256 + n];
  acc += t4[1] * Wp[512 + n];
  acc += t4[2] * Wp[768 + n];
  acc += t4[3] * Wp[1024 + n];
  h[(size_t)row * 256 + n] = acc;
  __shared__ float red[4];
  int wid = n >> 6, lane = n & 63;
  float s = wave_sum(acc);
  if (lane == 0) red[wid] = s;
  __syncthreads();
  float mu = (red[0] + red[1] + red[2] + red[3]) * (1.f / 256.f);
  __syncthreads();
  float d = acc - mu;
  float s2 = wave_sum(d * d);
  if (lane == 0) red[wid] = s2;
  __syncthreads();
  float var = (red[0] + red[1] + red[2] + red[3]) * (1.f / 256.f);
  float rs = rsqrtf(var + 1e-5f);
  hn[(size_t)row * 256 + n] = (__bf16)(d * rs * g[n] + b[n]);
}

__global__ __launch_bounds__(256) void prep_kernel(
    const float* __restrict__ x, const float* __restrict__ tf,
    const float* __restrict__ Wp, const float* __restrict__ bp,
    const float* __restrict__ ln_g, const float* __restrict__ ln_b,
    const float* __restrict__ Wup, const float* __restrict__ Wq,
    const float* __restrict__ Wk, const float* __restrict__ Wv,
    const float* __restrict__ Wdown, const float* __restrict__ Wif,
    __bf16* __restrict__ WupT, __bf16* __restrict__ WqkT,
    __bf16* __restrict__ WvT, __bf16* __restrict__ WdownT,
    float* __restrict__ wg, float* __restrict__ h, __bf16* __restrict__ hn) {
  int bid = blockIdx.x;
  if (bid < 4608) {
    wtrans_body(bid, Wup, Wq, Wk, Wv, Wdown, WupT, WqkT, WvT, WdownT);
  } else if (bid < 4608 + 1024) {
    wgprep_body(bid - 4608, Wq, Wk, Wv, Wif, wg);
  } else {
    embed_body(bid - 5632, x, tf, Wp, bp, ln_g, ln_b, h, hn);
  }
}

// ---------------- bf16 MFMA GEMM body: TM x 128 tile, dbuf LDS + reg prefetch ----------------
// One __syncthreads per K-step: compute from buf `cur` while storing prefetched regs
// into buf `cur^1`. LDS layout: As[2*TM][40] then Bs[2*128][40].
template <int TM, int MODE, int ACC>
__device__ __forceinline__ void hgemm_body(
    char* smem_raw,
    const __bf16* __restrict__ A, int lda,
    const __bf16* __restrict__ BT, int Kdim,
    const float* __restrict__ bias,
    void* __restrict__ Cout, int ldc, int bxi, int byi) {
  auto As = (__bf16(*)[40])smem_raw;
  auto Bs = (__bf16(*)[40])(smem_raw + (size_t)TM * 160);
  int tid = threadIdx.x;
  int bm = bxi * TM, bn = byi * 128;
  int wid = tid >> 6, lane = tid & 63;
  int wr = wid >> 1, wc = wid & 1;
  int lg = lane >> 4, li = lane & 15;
  constexpr int MI = TM / 32;
  constexpr int WROW = TM / 2;
  floatx4 acc[MI][4];
  #pragma unroll
  for (int i = 0; i < MI; ++i)
    #pragma unroll
    for (int j = 0; j < 4; ++j) acc[i][j] = (floatx4)(0.f);

  int arow = tid >> 2, aseg = tid & 3;
  bf16x8 pa0, pa1, pb0, pb1;
  auto pre = [&](int k0) {
    pa0 = *(const bf16x8*)(A + (size_t)(bm + arow) * lda + k0 + aseg * 8);
    if constexpr (TM == 128)
      pa1 = *(const bf16x8*)(A + (size_t)(bm + arow + 64) * lda + k0 + aseg * 8);
    pb0 = *(const bf16x8*)(BT + (size_t)(bn + arow) * Kdim + k0 + aseg * 8);
    pb1 = *(const bf16x8*)(BT + (size_t)(bn + arow + 64) * Kdim + k0 + aseg * 8);
  };
  auto stor = [&](int buf) {
    *(bf16x8*)&As[buf * TM + arow][aseg * 8] = pa0;
    if constexpr (TM == 128) *(bf16x8*)&As[buf * TM + arow + 64][aseg * 8] = pa1;
    *(bf16x8*)&Bs[buf * 128 + arow][aseg * 8] = pb0;
    *(bf16x8*)&Bs[buf * 128 + arow + 64][aseg * 8] = pb1;
  };
  pre(0);
  stor(0);
  if (32 < Kdim) pre(32);
  int cur = 0;
  for (int k0 = 0; k0 < Kdim; k0 += 32) {
    __syncthreads();
    bf16x8 af[MI], bfr[4];
    #pragma unroll
    for (int mi = 0; mi < MI; ++mi)
      af[mi] = *(const bf16x8*)&As[cur * TM + wr * WROW + mi * 16 + li][lg * 8];
    #pragma unroll
    for (int ni = 0; ni < 4; ++ni)
      bfr[ni] = *(const bf16x8*)&Bs[cur * 128 + wc * 64 + ni * 16 + li][lg * 8];
    #pragma unroll
    for (int mi = 0; mi < MI; ++mi)
      #pragma unroll
      for (int ni = 0; ni < 4; ++ni)
        acc[mi][ni] = __builtin_amdgcn_mfma_f32_16x16x32_bf16(af[mi], bfr[ni], acc[mi][ni], 0, 0, 0);
    if (k0 + 32 < Kdim) {
      stor(cur ^ 1);
      if (k0 + 64 < Kdim) pre(k0 + 64);
    }
    cur ^= 1;
  }
  if constexpr (MODE == 1) {
    __bf16* eb = (__bf16*)smem_raw;
    const int PITCH = 136;
    __bf16* C = (__bf16*)Cout;
    #pragma unroll
    for (int mi = 0; mi < MI; ++mi) {
      __syncthreads();
      #pragma unroll
      for (int ni = 0; ni < 4; ++ni) {
        int col = wc * 64 + ni * 16 + li;
        float bz = bias ? bias[bn + col] : 0.f;
        #pragma unroll
        for (int r = 0; r < 4; ++r) {
          int lr = wr * 16 + lg * 4 + r;
          eb[lr * PITCH + col] = (__bf16)(acc[mi][ni][r] + bz);
        }
      }
      __syncthreads();
      #pragma unroll
      for (int i = 0; i < 2; ++i) {
        int lr = (tid >> 4) + i * 16;
        int c8 = (tid & 15) * 8;
        bf16x8 v = *(const bf16x8*)&eb[lr * PITCH + c8];
        int row_g = bm + (lr >> 4) * 64 + mi * 16 + (lr & 15);
        *(bf16x8*)(C + (size_t)row_g * ldc + bn + c8) = v;
      }
    }
  } else {
    #pragma unroll
    for (int mi = 0; mi < MI; ++mi) {
      int row = bm + wr * WROW + mi * 16 + lg * 4;
      #pragma unroll
      for (int ni = 0; ni < 4; ++ni) {
        int col = bn + wc * 64 + ni * 16 + li;
        if constexpr (MODE == 2) {
          __bf16 o4[4];
          #pragma unroll
          for (int r = 0; r < 4; ++r) o4[r] = (__bf16)acc[mi][ni][r];
          __bf16* vt = (__bf16*)Cout;
          size_t off = ((size_t)((row >> 10) * 4 + (col >> 7)) * 128 + (col & 127)) * 1024 + (row & 1023);
          *(uint2*)(vt + off) = *(uint2*)o4;
        } else {
          float bz = bias ? bias[col] : 0.f;
          float* C = (float*)Cout;
          #pragma unroll
          for (int r = 0; r < 4; ++r) {
            float v = acc[mi][ni][r] + bz;
            if (ACC) v += C[(size_t)(row + r) * ldc + col];
            C[(size_t)(row + r) * ldc + col] = v;
          }
        }
      }
    }
  }
}

template <int TM, int MODE, int ACC>
__global__ __launch_bounds__(256) void hgemm(
    const __bf16* __restrict__ A, int lda,
    const __bf16* __restrict__ BT, int Kdim,
    const float* __restrict__ bias,
    void* __restrict__ Cout, int ldc) {
  extern __shared__ char smem[];
  hgemm_body<TM, MODE, ACC>(smem, A, lda, BT, Kdim, bias, Cout, ldc,
                            blockIdx.x, blockIdx.y);
}

// ---------------- per-(b,h) gate scan body: one wave ----------------
__device__ __forceinline__ void scan_body(
    int bh, int lane, const float* __restrict__ gates, float* __restrict__ gout,
    float* __restrict__ Mout, float* __restrict__ NFout) {
  int bb = bh >> 2, hh = bh & 3;
  float ip[16], pf[16];
  #pragma unroll
  for (int i = 0; i < 16; ++i) {
    int t = lane * 16 + i;
    const float* grow = gates + ((size_t)(bb * S + t)) * 8;
    ip[i] = grow[hh];
    float fp = grow[4 + hh];
    float lf = fminf(fp, 0.f) - log1pf(__expf(-fabsf(fp)));
    pf[i] = (i == 0) ? lf : pf[i - 1] + lf;
  }
  float T = pf[15];
  float inc = T;
  #pragma unroll
  for (int off = 1; off < 64; off <<= 1) {
    float v = __shfl_up(inc, off, 64);
    if (lane >= off) inc += v;
  }
  float excl = inc - T;
  float F[16], g[16], pm[16];
  #pragma unroll
  for (int i = 0; i < 16; ++i) {
    F[i] = excl + pf[i];
    g[i] = ip[i] - F[i];
    pm[i] = (i == 0) ? g[0] : fmaxf(pm[i - 1], g[i]);
  }
  float Mx = pm[15];
  float incm = Mx;
  #pragma unroll
  for (int off = 1; off < 64; off <<= 1) {
    float v = __shfl_up(incm, off, 64);
    if (lane >= off) incm = fmaxf(incm, v);
  }
  float em = __shfl_up(incm, 1, 64);
  if (lane == 0) em = -3.4e38f;
  #pragma unroll
  for (int i = 0; i < 16; ++i) {
    int t = lane * 16 + i;
    size_t o = (size_t)bh * S + t;
    float M = fmaxf(em, pm[i]);
    gout[o] = g[i];
    Mout[o] = M;
    NFout[o] = __expf(-F[i] - M);
  }
}

// Merged QK + V GEMM + gate scan: grid (64, 17).
__global__ __launch_bounds__(256) void qkv_kernel(
    const __bf16* __restrict__ xc, const __bf16* __restrict__ WqkT,
    __bf16* __restrict__ qk, const __bf16* __restrict__ up,
    const __bf16* __restrict__ WvT, __bf16* __restrict__ vT,
    const float* __restrict__ gates, float* __restrict__ gbuf,
    float* __restrict__ Mbuf, float* __restrict__ NFbuf) {
  extern __shared__ char smem[];
  if (blockIdx.y < 8) {
    hgemm_body<128, 1, 0>(smem, xc, 512, WqkT, 512, nullptr, qk, 1024,
                          blockIdx.x, blockIdx.y);
  } else if (blockIdx.y < 16) {
    int j = blockIdx.y - 8;
    hgemm_body<64, 2, 0>(smem, up, 1024, WvT, 512, nullptr, vT, 0,
                         blockIdx.x * 2 + (j & 1), j >> 1);
  } else {
    if (blockIdx.x < 32 && threadIdx.x < 64)
      scan_body(blockIdx.x, threadIdx.x, gates, gbuf, Mbuf, NFbuf);
  }
}

// ---------------- down-proj GEMM (32x256, dbuf) + residual + LN / final head ----------------
__global__ __launch_bounds__(256) void dgemm_ln_kernel(
    const __bf16* __restrict__ A, const __bf16* __restrict__ BT,
    const float* __restrict__ bias, float* __restrict__ h,
    const float* __restrict__ lng, const float* __restrict__ lnb,
    __bf16* __restrict__ hn,
    const float* __restrict__ lnfg, const float* __restrict__ lnfb,
    const float* __restrict__ Wf, const float* __restrict__ bf,
    float* __restrict__ out) {
  __shared__ __bf16 As[2 * 32][40];
  __shared__ __bf16 Bs[2 * 256][40];
  __shared__ float redS[2][32], redQ[2][32];
  int tid = threadIdx.x;
  int bm = blockIdx.x * 32;
  int wid = tid >> 6, lane = tid & 63;
  int wr = wid >> 1, wc = wid & 1;
  int lg = lane >> 4, li = lane & 15;
  floatx4 acc[8];
  #pragma unroll
  for (int j = 0; j < 8; ++j) acc[j] = (floatx4)(0.f);

  int arow = tid >> 2, aseg = tid & 3;
  bf16x8 pa, pb[4];
  auto pre = [&](int k0) {
    if (tid < 128)
      pa = *(const bf16x8*)(A + (size_t)(bm + arow) * 512 + k0 + aseg * 8);
    #pragma unroll
    for (int i = 0; i < 4; ++i)
      pb[i] = *(const bf16x8*)(BT + (size_t)(arow + i * 64) * 512 + k0 + aseg * 8);
  };
  auto stor = [&](int buf) {
    if (tid < 128) *(bf16x8*)&As[buf * 32 + arow][aseg * 8] = pa;
    #pragma unroll
    for (int i = 0; i < 4; ++i)
      *(bf16x8*)&Bs[buf * 256 + arow + i * 64][aseg * 8] = pb[i];
  };
  pre(0);
  stor(0);
  pre(32);
  int cur = 0;
  for (int k0 = 0; k0 < 512; k0 += 32) {
    __syncthreads();
    bf16x8 af = *(const bf16x8*)&As[cur * 32 + wr * 16 + li][lg * 8];
    #pragma unroll
    for (int ni = 0; ni < 8; ++ni) {
      bf16x8 bfr = *(const bf16x8*)&Bs[cur * 256 + wc * 128 + ni * 16 + li][lg * 8];
      acc[ni] = __builtin_amdgcn_mfma_f32_16x16x32_bf16(af, bfr, acc[ni], 0, 0, 0);
    }
    if (k0 + 32 < 512) {
      stor(cur ^ 1);
      if (k0 + 64 < 512) pre(k0 + 64);
    }
    cur ^= 1;
  }
  #pragma unroll
  for (int r = 0; r < 4; ++r) {
    int lr = wr * 16 + lg * 4 + r;
    int row = bm + lr;
    float s1 = 0.f, s2 = 0.f;
    #pragma unroll
    for (int ni = 0; ni < 8; ++ni) {
      int col = wc * 128 + ni * 16 + li;
      float v = acc[ni][r] + bias[col] + h[(size_t)row * 256 + col];
      acc[ni][r] = v;
      h[(size_t)row * 256 + col] = v;
      s1 += v;
      s2 += v * v;
    }
    s1 += __shfl_xor(s1, 1, 64); s1 += __shfl_xor(s1, 2, 64);
    s1 += __shfl_xor(s1, 4, 64); s1 += __shfl_xor(s1, 8, 64);
    s2 += __shfl_xor(s2, 1, 64); s2 += __shfl_xor(s2, 2, 64);
    s2 += __shfl_xor(s2, 4, 64); s2 += __shfl_xor(s2, 8, 64);
    if (li == 0) { redS[wc][lr] = s1; redQ[wc][lr] = s2; }
  }
  __syncthreads();
  if (lng) {
    #pragma unroll
    for (int r = 0; r < 4; ++r) {
      int lr = wr * 16 + lg * 4 + r;
      int row = bm + lr;
      float s1 = redS[0][lr] + redS[1][lr];
      float s2 = redQ[0][lr] + redQ[1][lr];
      float mu = s1 * (1.f / 256.f);
      float var = s2 * (1.f / 256.f) - mu * mu;
      float rs = rsqrtf(var + 1e-5f);
      #pragma unroll
      for (int ni = 0; ni < 8; ++ni) {
        int col = wc * 128 + ni * 16 + li;
        hn[(size_t)row * 256 + col] = (__bf16)((acc[ni][r] - mu) * rs * lng[col] + lnb[col]);
      }
    }
  } else if ((bm & 1023) == 992) {
    // final LN + head for row b*1024+1023 (local lr=31: wr==1, lg==3, r==3)
    if (wr == 1 && lg == 3) {
      float s1 = redS[0][31] + redS[1][31];
      float s2 = redQ[0][31] + redQ[1][31];
      float mu = s1 * (1.f / 256.f);
      float var = s2 * (1.f / 256.f) - mu * mu;
      float rs = rsqrtf(var + 1e-5f);
      float p = 0.f;
      #pragma unroll
      for (int ni = 0; ni < 8; ++ni) {
        int col = wc * 128 + ni * 16 + li;
        float ln = (acc[ni][3] - mu) * rs * lnfg[col] + lnfb[col];
        p += ln * Wf[col];
      }
      p += __shfl_xor(p, 1, 64); p += __shfl_xor(p, 2, 64);
      p += __shfl_xor(p, 4, 64); p += __shfl_xor(p, 8, 64);
      if (li == 0) redS[wc][0] = p;
    }
    __syncthreads();
    if (tid == 0) out[bm >> 10] = redS[0][0] + redS[1][0] + bf[0];
  }
}

// ---------------- causal conv (K=4) + SiLU + fused gate projection ----------------
__global__ __launch_bounds__(256) void conv_silu_kernel(
    const __bf16* __restrict__ up, const float* __restrict__ cw,
    const float* __restrict__ cb, const float* __restrict__ wg,
    const float* __restrict__ bif, __bf16* __restrict__ xc,
    float* __restrict__ gates) {
  int tid = threadIdx.x;
  int wv = tid >> 6, lane = tid & 63;
  int row = blockIdx.x * 4 + wv;
  int c8 = lane * 8;
  int t = row & (S - 1);
  float acc[8];
  *(float4*)&acc[0] = *(const float4*)(cb + c8);
  *(float4*)&acc[4] = *(const float4*)(cb + c8 + 4);
  float xm[8];
  #pragma unroll
  for (int j = 0; j < 4; ++j) {
    int tt = t - 3 + j;
    if (tt >= 0) {
      bf16x8 xv = *(const bf16x8*)(up + (size_t)(row - 3 + j) * 1024 + c8);
      float4 w0 = *(const float4*)(cw + j * 512 + c8);
      float4 w1 = *(const float4*)(cw + j * 512 + c8 + 4);
      acc[0] += w0.x * (float)xv[0]; acc[1] += w0.y * (float)xv[1];
      acc[2] += w0.z * (float)xv[2]; acc[3] += w0.w * (float)xv[3];
      acc[4] += w1.x * (float)xv[4]; acc[5] += w1.y * (float)xv[5];
      acc[6] += w1.z * (float)xv[6]; acc[7] += w1.w * (float)xv[7];
      if (j == 3) {
        #pragma unroll
        for (int m = 0; m < 8; ++m) xm[m] = (float)xv[m];
      }
    }
  }
  bf16x8 o;
  float xcs[8];
  #pragma unroll
  for (int m = 0; m < 8; ++m) {
    float sg = 1.f / (1.f + __expf(-acc[m]));
    xcs[m] = acc[m] * sg;
    o[m] = (__bf16)xcs[m];
  }
  *(bf16x8*)(xc + (size_t)row * 512 + c8) = o;
  const float* w1 = wg + (size_t)c8 * 8;
  const float* w2 = wg + 4096 + (size_t)c8 * 8;
  float part[8] = {0, 0, 0, 0, 0, 0, 0, 0};
  #pragma unroll
  for (int m = 0; m < 8; ++m) {
    const float* a = w1 + m * 8;
    const float* b = w2 + m * 8;
    #pragma unroll
    for (int j = 0; j < 8; ++j) part[j] += xcs[m] * a[j] + xm[m] * b[j];
  }
  #pragma unroll
  for (int j = 0; j < 8; ++j) part[j] = wave_sum(part[j]);
  if (lane < 8) gates[(size_t)row * 8 + lane] = part[lane] + bif[lane];
}

// ---------------- MFMA mLSTM attention (512 threads, 8 waves: 4 per q-tile) ----------------
__global__ __launch_bounds__(512, 1) void attn_kernel(
    const __bf16* __restrict__ qk, const __bf16* __restrict__ vT,
    const float* __restrict__ gbuf, const float* __restrict__ Mbuf,
    const float* __restrict__ NFbuf,
    const float* __restrict__ gn_g, const float* __restrict__ gn_b,
    const float* __restrict__ skip,
    const __bf16* __restrict__ xc, const __bf16* __restrict__ up,
    __bf16* __restrict__ hd) {
  __shared__ __bf16 Ks[64][136];
  __shared__ __bf16 Vs[128][72];
  __shared__ __bf16 plds[8][16][72];
  __shared__ float gls[64];
  __shared__ float glds[128], blds[128], slds[128];
  int px = blockIdx.y, bh = blockIdx.x;
  int tqA = px, tqB = 15 - px;
  int bb = bh >> 2, hh = bh & 3;
  int tid = threadIdx.x;
  int wv = tid >> 6, lane = tid & 63;
  int sel = wv >> 2, wl = wv & 3;
  int lg = lane >> 4, li = lane & 15;
  int tq = (sel == 0) ? tqA : tqB;
  int tb = tq * 64 + wl * 16;
  const float scale = 0.08838834764831845f;

  if (tid < 128) {
    glds[tid] = gn_g[hh * 128 + tid];
    blds[tid] = gn_b[hh * 128 + tid];
    slds[tid] = skip[hh * 128 + tid];
  }

  bf16x8 aq[4];
  {
    const __bf16* qp = qk + ((size_t)(bb * S + tb + li)) * 1024 + hh * 128 + lg * 8;
    #pragma unroll
    for (int cd = 0; cd < 4; ++cd) aq[cd] = *(const bf16x8*)(qp + cd * 32);
  }
  float ml[4], nf[4];
  #pragma unroll
  for (int r = 0; r < 4; ++r) {
    ml[r] = Mbuf[(size_t)bh * S + tb + lg * 4 + r];
    nf[r] = NFbuf[(size_t)bh * S + tb + lg * 4 + r];
  }

  floatx4 oacc[8];
  #pragma unroll
  for (int df = 0; df < 8; ++df) oacc[df] = (floatx4)(0.f);
  float rs[4] = {0, 0, 0, 0};

  int krow = tid >> 3, kcol = tid & 7;
  bf16x8 kreg0, kreg1, vreg0, vreg1;
  float greg = 0.f;
  auto preload = [&](int st) {
    int s0 = st * 64;
    const __bf16* kp = qk + ((size_t)(bb * S + s0 + krow)) * 1024 + 512 + hh * 128;
    kreg0 = *(const bf16x8*)(kp + kcol * 8);
    kreg1 = *(const bf16x8*)(kp + 64 + kcol * 8);
    vreg0 = *(const bf16x8*)(vT + ((size_t)(bh * 128 + krow)) * 1024 + s0 + kcol * 8);
    vreg1 = *(const bf16x8*)(vT + ((size_t)(bh * 128 + 64 + krow)) * 1024 + s0 + kcol * 8);
    if (tid < 64) greg = gbuf[(size_t)bh * S + s0 + tid];
  };
  preload(0);

  for (int st = 0; st <= tqB; ++st) {
    __syncthreads();
    *(bf16x8*)&Ks[krow][kcol * 8] = kreg0;
    *(bf16x8*)&Ks[krow][64 + kcol * 8] = kreg1;
    *(bf16x8*)&Vs[krow][kcol * 8] = vreg0;
    *(bf16x8*)&Vs[64 + krow][kcol * 8] = vreg1;
    if (tid < 64) gls[tid] = greg;
    __syncthreads();
    if (st < tqB) preload(st + 1);

    if (st <= tq) {
      int s0 = st * 64;
      #pragma unroll
      for (int ns = 0; ns < 4; ++ns) {
        bf16x8 bk0 = *(const bf16x8*)&Ks[ns * 16 + li][lg * 8];
        bf16x8 bk1 = *(const bf16x8*)&Ks[ns * 16 + li][32 + lg * 8];
        bf16x8 bk2 = *(const bf16x8*)&Ks[ns * 16 + li][64 + lg * 8];
        bf16x8 bk3 = *(const bf16x8*)&Ks[ns * 16 + li][96 + lg * 8];
        int s = s0 + ns * 16 + li;
        float gv = gls[ns * 16 + li];
        floatx4 pa = (floatx4)(0.f);
        pa = __builtin_amdgcn_mfma_f32_16x16x32_bf16(aq[0], bk0, pa, 0, 0, 0);
        pa = __builtin_amdgcn_mfma_f32_16x16x32_bf16(aq[1], bk1, pa, 0, 0, 0);
        pa = __builtin_amdgcn_mfma_f32_16x16x32_bf16(aq[2], bk2, pa, 0, 0, 0);
        pa = __builtin_amdgcn_mfma_f32_16x16x32_bf16(aq[3], bk3, pa, 0, 0, 0);
        #pragma unroll
        for (int r = 0; r < 4; ++r) {
          int t = tb + lg * 4 + r;
          float val = pa[r] * scale * __expf(gv - ml[r]);
          float w = (s <= t) ? val : 0.f;
          rs[r] += w;
          plds[wv][lg * 4 + r][ns * 16 + li] = (__bf16)w;
        }
      }
      bf16x8 ap0 = *(const bf16x8*)&plds[wv][li][lg * 8];
      bf16x8 ap1 = *(const bf16x8*)&plds[wv][li][32 + lg * 8];
      #pragma unroll
      for (int df = 0; df < 8; ++df) {
        bf16x8 bv0 = *(const bf16x8*)&Vs[df * 16 + li][lg * 8];
        bf16x8 bv1 = *(const bf16x8*)&Vs[df * 16 + li][32 + lg * 8];
        oacc[df] = __builtin_amdgcn_mfma_f32_16x16x32_bf16(ap0, bv0, oacc[df], 0, 0, 0);
        oacc[df] = __builtin_amdgcn_mfma_f32_16x16x32_bf16(ap1, bv1, oacc[df], 0, 0, 0);
      }
    }
  }
  #pragma unroll
  for (int r = 0; r < 4; ++r) {
    float a = rs[r];
    a += __shfl_xor(a, 1, 64); a += __shfl_xor(a, 2, 64);
    a += __shfl_xor(a, 4, 64); a += __shfl_xor(a, 8, 64);
    rs[r] = a;
  }
  #pragma unroll
  for (int r = 0; r < 4; ++r) {
    float inv = 1.f / (fmaxf(fabsf(rs[r]), nf[r]) + 1e-6f);
    float v8[8], s1 = 0.f, s2 = 0.f;
    #pragma unroll
    for (int df = 0; df < 8; ++df) {
      float v = oacc[df][r] * inv;
      v8[df] = v;
      s1 += v;
      s2 += v * v;
    }
    s1 += __shfl_xor(s1, 1, 64); s1 += __shfl_xor(s1, 2, 64);
    s1 += __shfl_xor(s1, 4, 64); s1 += __shfl_xor(s1, 8, 64);
    s2 += __shfl_xor(s2, 1, 64); s2 += __shfl_xor(s2, 2, 64);
    s2 += __shfl_xor(s2, 4, 64); s2 += __shfl_xor(s2, 8, 64);
    float mu = s1 * (1.f / 128.f);
    float var = s2 * (1.f / 128.f) - mu * mu;
    float rq = rsqrtf(var + 1e-5f);
    int t = tb + lg * 4 + r;
    const __bf16* xr = xc + ((size_t)(bb * S + t)) * 512 + hh * 128 + li;
    const __bf16* zr = up + ((size_t)(bb * S + t)) * 1024 + 512 + hh * 128 + li;
    __bf16* od = hd + ((size_t)(bb * S + t)) * 512 + hh * 128 + li;
    #pragma unroll
    for (int df = 0; df < 8; ++df) {
      int c = df * 16 + li;
      float ln = (v8[df] - mu) * rq * glds[c] + blds[c];
      float val = ln + slds[c] * (float)xr[df * 16];
      float z = (float)zr[df * 16];
      float sg = 1.f / (1.f + __expf(-z));
      od[df * 16] = (__bf16)(val * (z * sg));
    }
  }
}

extern "C" void kernel_launch(void* const* d_in, const int* in_sizes, int n_in,
                              void* d_out, int out_size, void* d_ws, size_t ws_size,
                              hipStream_t stream) {
  const float* x      = (const float*)d_in[0];
  const float* tf     = (const float*)d_in[1];
  const float* Wp     = (const float*)d_in[2];
  const float* bp     = (const float*)d_in[3];
  const float* ln_g   = (const float*)d_in[4];
  const float* ln_b   = (const float*)d_in[5];
  const float* Wup    = (const float*)d_in[6];
  const float* bup    = (const float*)d_in[7];
  const float* conv_w = (const float*)d_in[8];
  const float* conv_b = (const float*)d_in[9];
  const float* Wq     = (const float*)d_in[10];
  const float* Wk     = (const float*)d_in[11];
  const float* Wv     = (const float*)d_in[12];
  const float* Wif    = (const float*)d_in[13];
  const float* bif    = (const float*)d_in[14];
  const float* gn_g   = (const float*)d_in[15];
  const float* gn_b   = (const float*)d_in[16];
  const float* skip   = (const float*)d_in[17];
  const float* Wdown  = (const float*)d_in[18];
  const float* bdown  = (const float*)d_in[19];
  const float* lnf_g  = (const float*)d_in[20];
  const float* lnf_b  = (const float*)d_in[21];
  const float* Wf     = (const float*)d_in[22];
  const float* bf     = (const float*)d_in[23];
  float* out = (float*)d_out;

  float* h     = (float*)d_ws;              // 2,097,152 f32
  float* gates = h + 2097152;               // 65,536 f32
  float* gbuf  = gates + 65536;             // 32,768
  float* Mbuf  = gbuf + 32768;              // 32,768
  float* NFbuf = Mbuf + 32768;              // 32,768
  float* wgbuf = NFbuf + 32768;             // 32,768
  __bf16* hn   = (__bf16*)(wgbuf + 32768);  // 2,097,152 bf16
  __bf16* up   = hn + 2097152;              // 8,388,608
  __bf16* xc   = up + 8388608;              // 4,194,304
  __bf16* qk   = xc + 4194304;              // 8,388,608
  __bf16* vT   = qk + 8388608;              // 4,194,304
  __bf16* hd   = vT + 4194304;              // 4,194,304
  __bf16* WupT   = hd + 4194304;            // 1,048,576
  __bf16* WqkT   = WupT + 1048576;          // 2,097,152
  __bf16* WvT    = WqkT + 2097152;          // 1,048,576
  __bf16* WdownT = WvT + 1048576;           // 524,288

  prep_kernel<<<13824, 256, 0, stream>>>(
      x, tf, Wp, bp, ln_g, ln_b, Wup, Wq, Wk, Wv, Wdown, Wif,
      WupT, WqkT, WvT, WdownT, wgbuf, h, hn);
  for (int l = 0; l < NLAYER; ++l) {
    hgemm<128, 1, 0><<<dim3(64, 8), 256, 40960, stream>>>(
        hn, 256, WupT + (size_t)l * 262144, 256, bup + l * 1024, up, 1024);
    conv_silu_kernel<<<2048, 256, 0, stream>>>(up, conv_w + l * 2048, conv_b + l * 512,
                                               wgbuf + l * 8192, bif + l * 8, xc, gates);
    qkv_kernel<<<dim3(64, 17), 256, 40960, stream>>>(
        xc, WqkT + (size_t)l * 524288, qk, up, WvT + (size_t)l * 262144, vT,
        gates, gbuf, Mbuf, NFbuf);
    attn_kernel<<<dim3(32, 8), 512, 0, stream>>>(
        qk, vT, gbuf, Mbuf, NFbuf, gn_g + l * 512, gn_b + l * 512, skip + l * 512,
        xc, up, hd);
    const float* lng = (l + 1 < NLAYER) ? (ln_g + (l + 1) * 256) : nullptr;
    const float* lnb = (l + 1 < NLAYER) ? (ln_b + (l + 1) * 256) : nullptr;
    dgemm_ln_kernel<<<256, 256, 0, stream>>>(
        hd, WdownT + (size_t)l * 131072, bdown + l * 256, h, lng, lnb, hn,
        lnf_g, lnf_b, Wf, bf, out);
  }
}

// Round 16
// 588.778 us; speedup vs baseline: 1.3293x; 1.0087x over previous
//
#include <hip/hip_runtime.h>
#include <hip/hip_bf16.h>
#include <math.h>

#define S 1024
#define NLAYER 4

typedef __bf16 bf16x8 __attribute__((ext_vector_type(8)));
typedef float floatx4 __attribute__((ext_vector_type(4)));

__device__ __forceinline__ float wave_sum(float v) {
  #pragma unroll
  for (int off = 32; off > 0; off >>= 1) v += __shfl_xor(v, off, 64);
  return v;
}

// ---------------- combined prep: weight transpose + Wg precompute + embed/LN ----------------
__device__ __forceinline__ void wtrans_body(
    int bid, const float* Wup, const float* Wq, const float* Wk, const float* Wv,
    const float* Wdown, __bf16* WupT, __bf16* WqkT, __bf16* WvT, __bf16* WdownT) {
  __shared__ float T[32][33];
  int layer = bid / 1152, rr = bid % 1152;
  const float* src; __bf16* dst; int K, N, tile;
  if (rr < 256)       { src = Wup   + layer * 262144; dst = WupT  + layer * 262144;          K = 256; N = 1024; tile = rr; }
  else if (rr < 512)  { src = Wq    + layer * 262144; dst = WqkT  + layer * 524288;          K = 512; N = 512;  tile = rr - 256; }
  else if (rr < 768)  { src = Wk    + layer * 262144; dst = WqkT  + layer * 524288 + 262144; K = 512; N = 512;  tile = rr - 512; }
  else if (rr < 1024) { src = Wv    + layer * 262144; dst = WvT   + layer * 262144;          K = 512; N = 512;  tile = rr - 768; }
  else                { src = Wdown + layer * 131072; dst = WdownT + layer * 131072;         K = 512; N = 256;  tile = rr - 1024; }
  int ntn = N >> 5;
  int tk = tile / ntn, tn = tile % ntn;
  int tid = threadIdx.x;
  int r = tid >> 3, c4 = (tid & 7) * 4;
  float4 v = *(const float4*)(src + (size_t)(tk * 32 + r) * N + tn * 32 + c4);
  T[c4 + 0][r] = v.x; T[c4 + 1][r] = v.y; T[c4 + 2][r] = v.z; T[c4 + 3][r] = v.w;
  __syncthreads();
  __bf16 o[4];
  #pragma unroll
  for (int j = 0; j < 4; ++j) o[j] = (__bf16)T[r][c4 + j];
  *(uint2*)(dst + (size_t)(tn * 32 + r) * K + tk * 32 + c4) = *(uint2*)o;
}

__device__ __forceinline__ void wgprep_body(
    int bid, const float* Wq, const float* Wk, const float* Wv,
    const float* Wif, float* wg) {
  int l = bid >> 8;
  int rem = bid & 255;
  int sel = rem >> 7;
  int kg = rem & 127;
  int tid = threadIdx.x;
  int wv = tid >> 6, lane = tid & 63;
  int k = kg * 4 + wv;
  const float* wif = Wif + (size_t)l * 1536 * 8;
  float part[8] = {0, 0, 0, 0, 0, 0, 0, 0};
  if (sel == 0) {
    const float* qr = Wq + (size_t)l * 262144 + (size_t)k * 512;
    const float* kr = Wk + (size_t)l * 262144 + (size_t)k * 512;
    #pragma unroll
    for (int i = 0; i < 8; ++i) {
      int n = lane + i * 64;
      float qv = qr[n], kv = kr[n];
      const float* wq8 = wif + (size_t)n * 8;
      const float* wk8 = wif + (size_t)(512 + n) * 8;
      #pragma unroll
      for (int j = 0; j < 8; ++j) part[j] += qv * wq8[j] + kv * wk8[j];
    }
  } else {
    const float* vr = Wv + (size_t)l * 262144 + (size_t)k * 512;
    #pragma unroll
    for (int i = 0; i < 8; ++i) {
      int n = lane + i * 64;
      float vv = vr[n];
      const float* wv8 = wif + (size_t)(1024 + n) * 8;
      #pragma unroll
      for (int j = 0; j < 8; ++j) part[j] += vv * wv8[j];
    }
  }
  #pragma unroll
  for (int j = 0; j < 8; ++j) part[j] = wave_sum(part[j]);
  if (lane < 8) wg[(size_t)l * 8192 + sel * 4096 + (size_t)k * 8 + lane] = part[lane];
}

__device__ __forceinline__ void embed_body(
    int row, const float* x, const float* tf, const float* Wp, const float* bp,
    const float* g, const float* b, float* h, __bf16* hn) {
  int n = threadIdx.x;
  float xv = x[row];
  const float* t4 = tf + (size_t)row * 4;
  float acc = bp[n] + xv * Wp[n];
  acc += t4[0] * Wp[256 + n];
  acc += t4[1] * Wp[512 + n];
  acc += t4[2] * Wp[768 + n];
  acc += t4[3] * Wp[1024 + n];
  h[(size_t)row * 256 + n] = acc;
  __shared__ float red[4];
  int wid = n >> 6, lane = n & 63;
  float s = wave_sum(acc);
  if (lane == 0) red[wid] = s;
  __syncthreads();
  float mu = (red[0] + red[1] + red[2] + red[3]) * (1.f / 256.f);
  __syncthreads();
  float d = acc - mu;
  float s2 = wave_sum(d * d);
  if (lane == 0) red[wid] = s2;
  __syncthreads();
  float var = (red[0] + red[1] + red[2] + red[3]) * (1.f / 256.f);
  float rs = rsqrtf(var + 1e-5f);
  hn[(size_t)row * 256 + n] = (__bf16)(d * rs * g[n] + b[n]);
}

__global__ __launch_bounds__(256) void prep_kernel(
    const float* __restrict__ x, const float* __restrict__ tf,
    const float* __restrict__ Wp, const float* __restrict__ bp,
    const float* __restrict__ ln_g, const float* __restrict__ ln_b,
    const float* __restrict__ Wup, const float* __restrict__ Wq,
    const float* __restrict__ Wk, const float* __restrict__ Wv,
    const float* __restrict__ Wdown, const float* __restrict__ Wif,
    __bf16* __restrict__ WupT, __bf16* __restrict__ WqkT,
    __bf16* __restrict__ WvT, __bf16* __restrict__ WdownT,
    float* __restrict__ wg, float* __restrict__ h, __bf16* __restrict__ hn) {
  int bid = blockIdx.x;
  if (bid < 4608) {
    wtrans_body(bid, Wup, Wq, Wk, Wv, Wdown, WupT, WqkT, WvT, WdownT);
  } else if (bid < 4608 + 1024) {
    wgprep_body(bid - 4608, Wq, Wk, Wv, Wif, wg);
  } else {
    embed_body(bid - 5632, x, tf, Wp, bp, ln_g, ln_b, h, hn);
  }
}

// ---------------- bf16 MFMA GEMM body: TM x 128 tile, dbuf LDS + reg prefetch ----------------
template <int TM, int MODE, int ACC>
__device__ __forceinline__ void hgemm_body(
    char* smem_raw,
    const __bf16* __restrict__ A, int lda,
    const __bf16* __restrict__ BT, int Kdim,
    const float* __restrict__ bias,
    void* __restrict__ Cout, int ldc, int bxi, int byi) {
  auto As = (__bf16(*)[40])smem_raw;
  auto Bs = (__bf16(*)[40])(smem_raw + (size_t)TM * 160);
  int tid = threadIdx.x;
  int bm = bxi * TM, bn = byi * 128;
  int wid = tid >> 6, lane = tid & 63;
  int wr = wid >> 1, wc = wid & 1;
  int lg = lane >> 4, li = lane & 15;
  constexpr int MI = TM / 32;
  constexpr int WROW = TM / 2;
  floatx4 acc[MI][4];
  #pragma unroll
  for (int i = 0; i < MI; ++i)
    #pragma unroll
    for (int j = 0; j < 4; ++j) acc[i][j] = (floatx4)(0.f);

  int arow = tid >> 2, aseg = tid & 3;
  bf16x8 pa0, pa1, pb0, pb1;
  auto pre = [&](int k0) {
    pa0 = *(const bf16x8*)(A + (size_t)(bm + arow) * lda + k0 + aseg * 8);
    if constexpr (TM == 128)
      pa1 = *(const bf16x8*)(A + (size_t)(bm + arow + 64) * lda + k0 + aseg * 8);
    pb0 = *(const bf16x8*)(BT + (size_t)(bn + arow) * Kdim + k0 + aseg * 8);
    pb1 = *(const bf16x8*)(BT + (size_t)(bn + arow + 64) * Kdim + k0 + aseg * 8);
  };
  auto stor = [&](int buf) {
    *(bf16x8*)&As[buf * TM + arow][aseg * 8] = pa0;
    if constexpr (TM == 128) *(bf16x8*)&As[buf * TM + arow + 64][aseg * 8] = pa1;
    *(bf16x8*)&Bs[buf * 128 + arow][aseg * 8] = pb0;
    *(bf16x8*)&Bs[buf * 128 + arow + 64][aseg * 8] = pb1;
  };
  pre(0);
  stor(0);
  if (32 < Kdim) pre(32);
  int cur = 0;
  for (int k0 = 0; k0 < Kdim; k0 += 32) {
    __syncthreads();
    bf16x8 af[MI], bfr[4];
    #pragma unroll
    for (int mi = 0; mi < MI; ++mi)
      af[mi] = *(const bf16x8*)&As[cur * TM + wr * WROW + mi * 16 + li][lg * 8];
    #pragma unroll
    for (int ni = 0; ni < 4; ++ni)
      bfr[ni] = *(const bf16x8*)&Bs[cur * 128 + wc * 64 + ni * 16 + li][lg * 8];
    #pragma unroll
    for (int mi = 0; mi < MI; ++mi)
      #pragma unroll
      for (int ni = 0; ni < 4; ++ni)
        acc[mi][ni] = __builtin_amdgcn_mfma_f32_16x16x32_bf16(af[mi], bfr[ni], acc[mi][ni], 0, 0, 0);
    if (k0 + 32 < Kdim) {
      stor(cur ^ 1);
      if (k0 + 64 < Kdim) pre(k0 + 64);
    }
    cur ^= 1;
  }
  if constexpr (MODE == 1) {
    __bf16* eb = (__bf16*)smem_raw;
    const int PITCH = 136;
    __bf16* C = (__bf16*)Cout;
    #pragma unroll
    for (int mi = 0; mi < MI; ++mi) {
      __syncthreads();
      #pragma unroll
      for (int ni = 0; ni < 4; ++ni) {
        int col = wc * 64 + ni * 16 + li;
        float bz = bias ? bias[bn + col] : 0.f;
        #pragma unroll
        for (int r = 0; r < 4; ++r) {
          int lr = wr * 16 + lg * 4 + r;
          eb[lr * PITCH + col] = (__bf16)(acc[mi][ni][r] + bz);
        }
      }
      __syncthreads();
      #pragma unroll
      for (int i = 0; i < 2; ++i) {
        int lr = (tid >> 4) + i * 16;
        int c8 = (tid & 15) * 8;
        bf16x8 v = *(const bf16x8*)&eb[lr * PITCH + c8];
        int row_g = bm + (lr >> 4) * 64 + mi * 16 + (lr & 15);
        *(bf16x8*)(C + (size_t)row_g * ldc + bn + c8) = v;
      }
    }
  } else {
    #pragma unroll
    for (int mi = 0; mi < MI; ++mi) {
      int row = bm + wr * WROW + mi * 16 + lg * 4;
      #pragma unroll
      for (int ni = 0; ni < 4; ++ni) {
        int col = bn + wc * 64 + ni * 16 + li;
        if constexpr (MODE == 2) {
          __bf16 o4[4];
          #pragma unroll
          for (int r = 0; r < 4; ++r) o4[r] = (__bf16)acc[mi][ni][r];
          __bf16* vt = (__bf16*)Cout;
          size_t off = ((size_t)((row >> 10) * 4 + (col >> 7)) * 128 + (col & 127)) * 1024 + (row & 1023);
          *(uint2*)(vt + off) = *(uint2*)o4;
        } else {
          float bz = bias ? bias[col] : 0.f;
          float* C = (float*)Cout;
          #pragma unroll
          for (int r = 0; r < 4; ++r) {
            float v = acc[mi][ni][r] + bz;
            if (ACC) v += C[(size_t)(row + r) * ldc + col];
            C[(size_t)(row + r) * ldc + col] = v;
          }
        }
      }
    }
  }
}

template <int TM, int MODE, int ACC>
__global__ __launch_bounds__(256) void hgemm(
    const __bf16* __restrict__ A, int lda,
    const __bf16* __restrict__ BT, int Kdim,
    const float* __restrict__ bias,
    void* __restrict__ Cout, int ldc) {
  extern __shared__ char smem[];
  hgemm_body<TM, MODE, ACC>(smem, A, lda, BT, Kdim, bias, Cout, ldc,
                            blockIdx.x, blockIdx.y);
}

// ---------------- per-(b,h) gate scan body: one wave ----------------
__device__ __forceinline__ void scan_body(
    int bh, int lane, const float* __restrict__ gates, float* __restrict__ gout,
    float* __restrict__ Mout, float* __restrict__ NFout) {
  int bb = bh >> 2, hh = bh & 3;
  float ip[16], pf[16];
  #pragma unroll
  for (int i = 0; i < 16; ++i) {
    int t = lane * 16 + i;
    const float* grow = gates + ((size_t)(bb * S + t)) * 8;
    ip[i] = grow[hh];
    float fp = grow[4 + hh];
    float lf = fminf(fp, 0.f) - log1pf(__expf(-fabsf(fp)));
    pf[i] = (i == 0) ? lf : pf[i - 1] + lf;
  }
  float T = pf[15];
  float inc = T;
  #pragma unroll
  for (int off = 1; off < 64; off <<= 1) {
    float v = __shfl_up(inc, off, 64);
    if (lane >= off) inc += v;
  }
  float excl = inc - T;
  float F[16], g[16], pm[16];
  #pragma unroll
  for (int i = 0; i < 16; ++i) {
    F[i] = excl + pf[i];
    g[i] = ip[i] - F[i];
    pm[i] = (i == 0) ? g[0] : fmaxf(pm[i - 1], g[i]);
  }
  float Mx = pm[15];
  float incm = Mx;
  #pragma unroll
  for (int off = 1; off < 64; off <<= 1) {
    float v = __shfl_up(incm, off, 64);
    if (lane >= off) incm = fmaxf(incm, v);
  }
  float em = __shfl_up(incm, 1, 64);
  if (lane == 0) em = -3.4e38f;
  #pragma unroll
  for (int i = 0; i < 16; ++i) {
    int t = lane * 16 + i;
    size_t o = (size_t)bh * S + t;
    float M = fmaxf(em, pm[i]);
    gout[o] = g[i];
    Mout[o] = M;
    NFout[o] = __expf(-F[i] - M);
  }
}

// Merged QK + V GEMM + gate scan: grid (64, 17).
__global__ __launch_bounds__(256) void qkv_kernel(
    const __bf16* __restrict__ xc, const __bf16* __restrict__ WqkT,
    __bf16* __restrict__ qk, const __bf16* __restrict__ up,
    const __bf16* __restrict__ WvT, __bf16* __restrict__ vT,
    const float* __restrict__ gates, float* __restrict__ gbuf,
    float* __restrict__ Mbuf, float* __restrict__ NFbuf) {
  extern __shared__ char smem[];
  if (blockIdx.y < 8) {
    hgemm_body<128, 1, 0>(smem, xc, 512, WqkT, 512, nullptr, qk, 1024,
                          blockIdx.x, blockIdx.y);
  } else if (blockIdx.y < 16) {
    int j = blockIdx.y - 8;
    hgemm_body<64, 2, 0>(smem, up, 1024, WvT, 512, nullptr, vT, 0,
                         blockIdx.x * 2 + (j & 1), j >> 1);
  } else {
    if (blockIdx.x < 32 && threadIdx.x < 64)
      scan_body(blockIdx.x, threadIdx.x, gates, gbuf, Mbuf, NFbuf);
  }
}

// ---------------- down-proj GEMM (32x256, dbuf) + residual + LN / final head ----------------
__global__ __launch_bounds__(256) void dgemm_ln_kernel(
    const __bf16* __restrict__ A, const __bf16* __restrict__ BT,
    const float* __restrict__ bias, float* __restrict__ h,
    const float* __restrict__ lng, const float* __restrict__ lnb,
    __bf16* __restrict__ hn,
    const float* __restrict__ lnfg, const float* __restrict__ lnfb,
    const float* __restrict__ Wf, const float* __restrict__ bf,
    float* __restrict__ out) {
  __shared__ __bf16 As[2 * 32][40];
  __shared__ __bf16 Bs[2 * 256][40];
  __shared__ float redS[2][32], redQ[2][32];
  int tid = threadIdx.x;
  int bm = blockIdx.x * 32;
  int wid = tid >> 6, lane = tid & 63;
  int wr = wid >> 1, wc = wid & 1;
  int lg = lane >> 4, li = lane & 15;
  floatx4 acc[8];
  #pragma unroll
  for (int j = 0; j < 8; ++j) acc[j] = (floatx4)(0.f);

  int arow = tid >> 2, aseg = tid & 3;
  bf16x8 pa, pb[4];
  auto pre = [&](int k0) {
    if (tid < 128)
      pa = *(const bf16x8*)(A + (size_t)(bm + arow) * 512 + k0 + aseg * 8);
    #pragma unroll
    for (int i = 0; i < 4; ++i)
      pb[i] = *(const bf16x8*)(BT + (size_t)(arow + i * 64) * 512 + k0 + aseg * 8);
  };
  auto stor = [&](int buf) {
    if (tid < 128) *(bf16x8*)&As[buf * 32 + arow][aseg * 8] = pa;
    #pragma unroll
    for (int i = 0; i < 4; ++i)
      *(bf16x8*)&Bs[buf * 256 + arow + i * 64][aseg * 8] = pb[i];
  };
  pre(0);
  stor(0);
  pre(32);
  int cur = 0;
  for (int k0 = 0; k0 < 512; k0 += 32) {
    __syncthreads();
    bf16x8 af = *(const bf16x8*)&As[cur * 32 + wr * 16 + li][lg * 8];
    #pragma unroll
    for (int ni = 0; ni < 8; ++ni) {
      bf16x8 bfr = *(const bf16x8*)&Bs[cur * 256 + wc * 128 + ni * 16 + li][lg * 8];
      acc[ni] = __builtin_amdgcn_mfma_f32_16x16x32_bf16(af, bfr, acc[ni], 0, 0, 0);
    }
    if (k0 + 32 < 512) {
      stor(cur ^ 1);
      if (k0 + 64 < 512) pre(k0 + 64);
    }
    cur ^= 1;
  }
  #pragma unroll
  for (int r = 0; r < 4; ++r) {
    int lr = wr * 16 + lg * 4 + r;
    int row = bm + lr;
    float s1 = 0.f, s2 = 0.f;
    #pragma unroll
    for (int ni = 0; ni < 8; ++ni) {
      int col = wc * 128 + ni * 16 + li;
      float v = acc[ni][r] + bias[col] + h[(size_t)row * 256 + col];
      acc[ni][r] = v;
      h[(size_t)row * 256 + col] = v;
      s1 += v;
      s2 += v * v;
    }
    s1 += __shfl_xor(s1, 1, 64); s1 += __shfl_xor(s1, 2, 64);
    s1 += __shfl_xor(s1, 4, 64); s1 += __shfl_xor(s1, 8, 64);
    s2 += __shfl_xor(s2, 1, 64); s2 += __shfl_xor(s2, 2, 64);
    s2 += __shfl_xor(s2, 4, 64); s2 += __shfl_xor(s2, 8, 64);
    if (li == 0) { redS[wc][lr] = s1; redQ[wc][lr] = s2; }
  }
  __syncthreads();
  if (lng) {
    #pragma unroll
    for (int r = 0; r < 4; ++r) {
      int lr = wr * 16 + lg * 4 + r;
      int row = bm + lr;
      float s1 = redS[0][lr] + redS[1][lr];
      float s2 = redQ[0][lr] + redQ[1][lr];
      float mu = s1 * (1.f / 256.f);
      float var = s2 * (1.f / 256.f) - mu * mu;
      float rs = rsqrtf(var + 1e-5f);
      #pragma unroll
      for (int ni = 0; ni < 8; ++ni) {
        int col = wc * 128 + ni * 16 + li;
        hn[(size_t)row * 256 + col] = (__bf16)((acc[ni][r] - mu) * rs * lng[col] + lnb[col]);
      }
    }
  } else if ((bm & 1023) == 992) {
    if (wr == 1 && lg == 3) {
      float s1 = redS[0][31] + redS[1][31];
      float s2 = redQ[0][31] + redQ[1][31];
      float mu = s1 * (1.f / 256.f);
      float var = s2 * (1.f / 256.f) - mu * mu;
      float rs = rsqrtf(var + 1e-5f);
      float p = 0.f;
      #pragma unroll
      for (int ni = 0; ni < 8; ++ni) {
        int col = wc * 128 + ni * 16 + li;
        float ln = (acc[ni][3] - mu) * rs * lnfg[col] + lnfb[col];
        p += ln * Wf[col];
      }
      p += __shfl_xor(p, 1, 64); p += __shfl_xor(p, 2, 64);
      p += __shfl_xor(p, 4, 64); p += __shfl_xor(p, 8, 64);
      if (li == 0) redS[wc][0] = p;
    }
    __syncthreads();
    if (tid == 0) out[bm >> 10] = redS[0][0] + redS[1][0] + bf[0];
  }
}

// ---------------- causal conv (K=4) + SiLU + fused gate projection ----------------
__global__ __launch_bounds__(256) void conv_silu_kernel(
    const __bf16* __restrict__ up, const float* __restrict__ cw,
    const float* __restrict__ cb, const float* __restrict__ wg,
    const float* __restrict__ bif, __bf16* __restrict__ xc,
    float* __restrict__ gates) {
  int tid = threadIdx.x;
  int wv = tid >> 6, lane = tid & 63;
  int row = blockIdx.x * 4 + wv;
  int c8 = lane * 8;
  int t = row & (S - 1);
  float acc[8];
  *(float4*)&acc[0] = *(const float4*)(cb + c8);
  *(float4*)&acc[4] = *(const float4*)(cb + c8 + 4);
  float xm[8];
  #pragma unroll
  for (int j = 0; j < 4; ++j) {
    int tt = t - 3 + j;
    if (tt >= 0) {
      bf16x8 xv = *(const bf16x8*)(up + (size_t)(row - 3 + j) * 1024 + c8);
      float4 w0 = *(const float4*)(cw + j * 512 + c8);
      float4 w1 = *(const float4*)(cw + j * 512 + c8 + 4);
      acc[0] += w0.x * (float)xv[0]; acc[1] += w0.y * (float)xv[1];
      acc[2] += w0.z * (float)xv[2]; acc[3] += w0.w * (float)xv[3];
      acc[4] += w1.x * (float)xv[4]; acc[5] += w1.y * (float)xv[5];
      acc[6] += w1.z * (float)xv[6]; acc[7] += w1.w * (float)xv[7];
      if (j == 3) {
        #pragma unroll
        for (int m = 0; m < 8; ++m) xm[m] = (float)xv[m];
      }
    }
  }
  bf16x8 o;
  float xcs[8];
  #pragma unroll
  for (int m = 0; m < 8; ++m) {
    float sg = 1.f / (1.f + __expf(-acc[m]));
    xcs[m] = acc[m] * sg;
    o[m] = (__bf16)xcs[m];
  }
  *(bf16x8*)(xc + (size_t)row * 512 + c8) = o;
  const float* w1 = wg + (size_t)c8 * 8;
  const float* w2 = wg + 4096 + (size_t)c8 * 8;
  float part[8] = {0, 0, 0, 0, 0, 0, 0, 0};
  #pragma unroll
  for (int m = 0; m < 8; ++m) {
    const float* a = w1 + m * 8;
    const float* b = w2 + m * 8;
    #pragma unroll
    for (int j = 0; j < 8; ++j) part[j] += xcs[m] * a[j] + xm[m] * b[j];
  }
  #pragma unroll
  for (int j = 0; j < 8; ++j) part[j] = wave_sum(part[j]);
  if (lane < 8) gates[(size_t)row * 8 + lane] = part[lane] + bif[lane];
}

// ---------------- MFMA mLSTM attention: 256-thr block, ONE q-tile, heavy-first grid ------
// grid (bh=32, 16): px = 15 - blockIdx.y (heavy tiles dispatched first), XCD-local (bh fast).
// ~47 KB LDS -> 2-3 blocks/CU co-resident: independent staging pipelines hide latency.
__global__ __launch_bounds__(256, 1) void attn_kernel(
    const __bf16* __restrict__ qk, const __bf16* __restrict__ vT,
    const float* __restrict__ gbuf, const float* __restrict__ Mbuf,
    const float* __restrict__ NFbuf,
    const float* __restrict__ gn_g, const float* __restrict__ gn_b,
    const float* __restrict__ skip,
    const __bf16* __restrict__ xc, const __bf16* __restrict__ up,
    __bf16* __restrict__ hd) {
  __shared__ __bf16 Ks[64][136];
  __shared__ __bf16 Vs[128][72];
  __shared__ __bf16 plds[4][16][72];
  __shared__ float gls[64];
  __shared__ float glds[128], blds[128], slds[128];
  int bh = blockIdx.x;
  int tq = 15 - blockIdx.y;   // heavy-first
  int bb = bh >> 2, hh = bh & 3;
  int tid = threadIdx.x;
  int wv = tid >> 6, lane = tid & 63;
  int lg = lane >> 4, li = lane & 15;
  int tb = tq * 64 + wv * 16;
  const float scale = 0.08838834764831845f;

  if (tid < 128) {
    glds[tid] = gn_g[hh * 128 + tid];
    blds[tid] = gn_b[hh * 128 + tid];
    slds[tid] = skip[hh * 128 + tid];
  }

  bf16x8 aq[4];
  {
    const __bf16* qp = qk + ((size_t)(bb * S + tb + li)) * 1024 + hh * 128 + lg * 8;
    #pragma unroll
    for (int cd = 0; cd < 4; ++cd) aq[cd] = *(const bf16x8*)(qp + cd * 32);
  }
  float ml[4], nf[4];
  #pragma unroll
  for (int r = 0; r < 4; ++r) {
    ml[r] = Mbuf[(size_t)bh * S + tb + lg * 4 + r];
    nf[r] = NFbuf[(size_t)bh * S + tb + lg * 4 + r];
  }

  floatx4 oacc[8];
  #pragma unroll
  for (int df = 0; df < 8; ++df) oacc[df] = (floatx4)(0.f);
  float rs[4] = {0, 0, 0, 0};

  int krow = tid >> 3, kcol = tid & 7;
  bf16x8 kreg[4], vreg[4];
  float greg = 0.f;
  auto preload = [&](int st) {
    int s0 = st * 64;
    const __bf16* kp = qk + ((size_t)(bb * S + s0 + krow)) * 1024 + 512 + hh * 128;
    kreg[0] = *(const bf16x8*)(kp + kcol * 8);
    kreg[1] = *(const bf16x8*)(kp + (size_t)32 * 1024 + kcol * 8);
    kreg[2] = *(const bf16x8*)(kp + 64 + kcol * 8);
    kreg[3] = *(const bf16x8*)(kp + (size_t)32 * 1024 + 64 + kcol * 8);
    #pragma unroll
    for (int i = 0; i < 4; ++i)
      vreg[i] = *(const bf16x8*)(vT + ((size_t)(bh * 128 + krow + i * 32)) * 1024 + s0 + kcol * 8);
    if (tid < 64) greg = gbuf[(size_t)bh * S + s0 + tid];
  };
  preload(0);

  for (int st = 0; st <= tq; ++st) {
    __syncthreads();
    *(bf16x8*)&Ks[krow][kcol * 8] = kreg[0];
    *(bf16x8*)&Ks[krow + 32][kcol * 8] = kreg[1];
    *(bf16x8*)&Ks[krow][64 + kcol * 8] = kreg[2];
    *(bf16x8*)&Ks[krow + 32][64 + kcol * 8] = kreg[3];
    #pragma unroll
    for (int i = 0; i < 4; ++i) *(bf16x8*)&Vs[krow + i * 32][kcol * 8] = vreg[i];
    if (tid < 64) gls[tid] = greg;
    __syncthreads();
    if (st < tq) preload(st + 1);

    int s0 = st * 64;
    #pragma unroll
    for (int ns = 0; ns < 4; ++ns) {
      bf16x8 bk0 = *(const bf16x8*)&Ks[ns * 16 + li][lg * 8];
      bf16x8 bk1 = *(const bf16x8*)&Ks[ns * 16 + li][32 + lg * 8];
      bf16x8 bk2 = *(const bf16x8*)&Ks[ns * 16 + li][64 + lg * 8];
      bf16x8 bk3 = *(const bf16x8*)&Ks[ns * 16 + li][96 + lg * 8];
      int s = s0 + ns * 16 + li;
      float gv = gls[ns * 16 + li];
      floatx4 pa = (floatx4)(0.f);
      pa = __builtin_amdgcn_mfma_f32_16x16x32_bf16(aq[0], bk0, pa, 0, 0, 0);
      pa = __builtin_amdgcn_mfma_f32_16x16x32_bf16(aq[1], bk1, pa, 0, 0, 0);
      pa = __builtin_amdgcn_mfma_f32_16x16x32_bf16(aq[2], bk2, pa, 0, 0, 0);
      pa = __builtin_amdgcn_mfma_f32_16x16x32_bf16(aq[3], bk3, pa, 0, 0, 0);
      #pragma unroll
      for (int r = 0; r < 4; ++r) {
        int t = tb + lg * 4 + r;
        float val = pa[r] * scale * __expf(gv - ml[r]);
        float w = (s <= t) ? val : 0.f;
        rs[r] += w;
        plds[wv][lg * 4 + r][ns * 16 + li] = (__bf16)w;
      }
    }
    bf16x8 ap0 = *(const bf16x8*)&plds[wv][li][lg * 8];
    bf16x8 ap1 = *(const bf16x8*)&plds[wv][li][32 + lg * 8];
    #pragma unroll
    for (int df = 0; df < 8; ++df) {
      bf16x8 bv0 = *(const bf16x8*)&Vs[df * 16 + li][lg * 8];
      bf16x8 bv1 = *(const bf16x8*)&Vs[df * 16 + li][32 + lg * 8];
      oacc[df] = __builtin_amdgcn_mfma_f32_16x16x32_bf16(ap0, bv0, oacc[df], 0, 0, 0);
      oacc[df] = __builtin_amdgcn_mfma_f32_16x16x32_bf16(ap1, bv1, oacc[df], 0, 0, 0);
    }
  }
  #pragma unroll
  for (int r = 0; r < 4; ++r) {
    float a = rs[r];
    a += __shfl_xor(a, 1, 64); a += __shfl_xor(a, 2, 64);
    a += __shfl_xor(a, 4, 64); a += __shfl_xor(a, 8, 64);
    rs[r] = a;
  }
  #pragma unroll
  for (int r = 0; r < 4; ++r) {
    float inv = 1.f / (fmaxf(fabsf(rs[r]), nf[r]) + 1e-6f);
    float v8[8], s1 = 0.f, s2 = 0.f;
    #pragma unroll
    for (int df = 0; df < 8; ++df) {
      float v = oacc[df][r] * inv;
      v8[df] = v;
      s1 += v;
      s2 += v * v;
    }
    s1 += __shfl_xor(s1, 1, 64); s1 += __shfl_xor(s1, 2, 64);
    s1 += __shfl_xor(s1, 4, 64); s1 += __shfl_xor(s1, 8, 64);
    s2 += __shfl_xor(s2, 1, 64); s2 += __shfl_xor(s2, 2, 64);
    s2 += __shfl_xor(s2, 4, 64); s2 += __shfl_xor(s2, 8, 64);
    float mu = s1 * (1.f / 128.f);
    float var = s2 * (1.f / 128.f) - mu * mu;
    float rq = rsqrtf(var + 1e-5f);
    int t = tb + lg * 4 + r;
    const __bf16* xr = xc + ((size_t)(bb * S + t)) * 512 + hh * 128 + li;
    const __bf16* zr = up + ((size_t)(bb * S + t)) * 1024 + 512 + hh * 128 + li;
    __bf16* od = hd + ((size_t)(bb * S + t)) * 512 + hh * 128 + li;
    #pragma unroll
    for (int df = 0; df < 8; ++df) {
      int c = df * 16 + li;
      float ln = (v8[df] - mu) * rq * glds[c] + blds[c];
      float val = ln + slds[c] * (float)xr[df * 16];
      float z = (float)zr[df * 16];
      float sg = 1.f / (1.f + __expf(-z));
      od[df * 16] = (__bf16)(val * (z * sg));
    }
  }
}

extern "C" void kernel_launch(void* const* d_in, const int* in_sizes, int n_in,
                              void* d_out, int out_size, void* d_ws, size_t ws_size,
                              hipStream_t stream) {
  const float* x      = (const float*)d_in[0];
  const float* tf     = (const float*)d_in[1];
  const float* Wp     = (const float*)d_in[2];
  const float* bp     = (const float*)d_in[3];
  const float* ln_g   = (const float*)d_in[4];
  const float* ln_b   = (const float*)d_in[5];
  const float* Wup    = (const float*)d_in[6];
  const float* bup    = (const float*)d_in[7];
  const float* conv_w = (const float*)d_in[8];
  const float* conv_b = (const float*)d_in[9];
  const float* Wq     = (const float*)d_in[10];
  const float* Wk     = (const float*)d_in[11];
  const float* Wv     = (const float*)d_in[12];
  const float* Wif    = (const float*)d_in[13];
  const float* bif    = (const float*)d_in[14];
  const float* gn_g   = (const float*)d_in[15];
  const float* gn_b   = (const float*)d_in[16];
  const float* skip   = (const float*)d_in[17];
  const float* Wdown  = (const float*)d_in[18];
  const float* bdown  = (const float*)d_in[19];
  const float* lnf_g  = (const float*)d_in[20];
  const float* lnf_b  = (const float*)d_in[21];
  const float* Wf     = (const float*)d_in[22];
  const float* bf     = (const float*)d_in[23];
  float* out = (float*)d_out;

  float* h     = (float*)d_ws;              // 2,097,152 f32
  float* gates = h + 2097152;               // 65,536 f32
  float* gbuf  = gates + 65536;             // 32,768
  float* Mbuf  = gbuf + 32768;              // 32,768
  float* NFbuf = Mbuf + 32768;              // 32,768
  float* wgbuf = NFbuf + 32768;             // 32,768
  __bf16* hn   = (__bf16*)(wgbuf + 32768);  // 2,097,152 bf16
  __bf16* up   = hn + 2097152;              // 8,388,608
  __bf16* xc   = up + 8388608;              // 4,194,304
  __bf16* qk   = xc + 4194304;              // 8,388,608
  __bf16* vT   = qk + 8388608;              // 4,194,304
  __bf16* hd   = vT + 4194304;              // 4,194,304
  __bf16* WupT   = hd + 4194304;            // 1,048,576
  __bf16* WqkT   = WupT + 1048576;          // 2,097,152
  __bf16* WvT    = WqkT + 2097152;          // 1,048,576
  __bf16* WdownT = WvT + 1048576;           // 524,288

  prep_kernel<<<13824, 256, 0, stream>>>(
      x, tf, Wp, bp, ln_g, ln_b, Wup, Wq, Wk, Wv, Wdown, Wif,
      WupT, WqkT, WvT, WdownT, wgbuf, h, hn);
  for (int l = 0; l < NLAYER; ++l) {
    hgemm<128, 1, 0><<<dim3(64, 8), 256, 40960, stream>>>(
        hn, 256, WupT + (size_t)l * 262144, 256, bup + l * 1024, up, 1024);
    conv_silu_kernel<<<2048, 256, 0, stream>>>(up, conv_w + l * 2048, conv_b + l * 512,
                                               wgbuf + l * 8192, bif + l * 8, xc, gates);
    qkv_kernel<<<dim3(64, 17), 256, 40960, stream>>>(
        xc, WqkT + (size_t)l * 524288, qk, up, WvT + (size_t)l * 262144, vT,
        gates, gbuf, Mbuf, NFbuf);
    attn_kernel<<<dim3(32, 16), 256, 0, stream>>>(
        qk, vT, gbuf, Mbuf, NFbuf, gn_g + l * 512, gn_b + l * 512, skip + l * 512,
        xc, up, hd);
    const float* lng = (l + 1 < NLAYER) ? (ln_g + (l + 1) * 256) : nullptr;
    const float* lnb = (l + 1 < NLAYER) ? (ln_b + (l + 1) * 256) : nullptr;
    dgemm_ln_kernel<<<256, 256, 0, stream>>>(
        hd, WdownT + (size_t)l * 131072, bdown + l * 256, h, lng, lnb, hn,
        lnf_g, lnf_b, Wf, bf, out);
  }
}

// Round 17
// 583.958 us; speedup vs baseline: 1.3403x; 1.0083x over previous
//
#include <hip/hip_runtime.h>
#include <hip/hip_bf16.h>
#include <math.h>

#define S 1024
#define NLAYER 4
#define KQOFF 4194304  // offset of k-part inside qkh (elements)

typedef __bf16 bf16x8 __attribute__((ext_vector_type(8)));
typedef float floatx4 __attribute__((ext_vector_type(4)));

__device__ __forceinline__ float wave_sum(float v) {
  #pragma unroll
  for (int off = 32; off > 0; off >>= 1) v += __shfl_xor(v, off, 64);
  return v;
}

// ---------------- combined prep: weight transpose + Wg precompute + embed/LN ----------------
__device__ __forceinline__ void wtrans_body(
    int bid, const float* Wup, const float* Wq, const float* Wk, const float* Wv,
    const float* Wdown, __bf16* WupT, __bf16* WqkT, __bf16* WvT, __bf16* WdownT) {
  __shared__ float T[32][33];
  int layer = bid / 1152, rr = bid % 1152;
  const float* src; __bf16* dst; int K, N, tile;
  if (rr < 256)       { src = Wup   + layer * 262144; dst = WupT  + layer * 262144;          K = 256; N = 1024; tile = rr; }
  else if (rr < 512)  { src = Wq    + layer * 262144; dst = WqkT  + layer * 524288;          K = 512; N = 512;  tile = rr - 256; }
  else if (rr < 768)  { src = Wk    + layer * 262144; dst = WqkT  + layer * 524288 + 262144; K = 512; N = 512;  tile = rr - 512; }
  else if (rr < 1024) { src = Wv    + layer * 262144; dst = WvT   + layer * 262144;          K = 512; N = 512;  tile = rr - 768; }
  else                { src = Wdown + layer * 131072; dst = WdownT + layer * 131072;         K = 512; N = 256;  tile = rr - 1024; }
  int ntn = N >> 5;
  int tk = tile / ntn, tn = tile % ntn;
  int tid = threadIdx.x;
  int r = tid >> 3, c4 = (tid & 7) * 4;
  float4 v = *(const float4*)(src + (size_t)(tk * 32 + r) * N + tn * 32 + c4);
  T[c4 + 0][r] = v.x; T[c4 + 1][r] = v.y; T[c4 + 2][r] = v.z; T[c4 + 3][r] = v.w;
  __syncthreads();
  __bf16 o[4];
  #pragma unroll
  for (int j = 0; j < 4; ++j) o[j] = (__bf16)T[r][c4 + j];
  *(uint2*)(dst + (size_t)(tn * 32 + r) * K + tk * 32 + c4) = *(uint2*)o;
}

__device__ __forceinline__ void wgprep_body(
    int bid, const float* Wq, const float* Wk, const float* Wv,
    const float* Wif, float* wg) {
  int l = bid >> 8;
  int rem = bid & 255;
  int sel = rem >> 7;
  int kg = rem & 127;
  int tid = threadIdx.x;
  int wv = tid >> 6, lane = tid & 63;
  int k = kg * 4 + wv;
  const float* wif = Wif + (size_t)l * 1536 * 8;
  float part[8] = {0, 0, 0, 0, 0, 0, 0, 0};
  if (sel == 0) {
    const float* qr = Wq + (size_t)l * 262144 + (size_t)k * 512;
    const float* kr = Wk + (size_t)l * 262144 + (size_t)k * 512;
    #pragma unroll
    for (int i = 0; i < 8; ++i) {
      int n = lane + i * 64;
      float qv = qr[n], kv = kr[n];
      const float* wq8 = wif + (size_t)n * 8;
      const float* wk8 = wif + (size_t)(512 + n) * 8;
      #pragma unroll
      for (int j = 0; j < 8; ++j) part[j] += qv * wq8[j] + kv * wk8[j];
    }
  } else {
    const float* vr = Wv + (size_t)l * 262144 + (size_t)k * 512;
    #pragma unroll
    for (int i = 0; i < 8; ++i) {
      int n = lane + i * 64;
      float vv = vr[n];
      const float* wv8 = wif + (size_t)(1024 + n) * 8;
      #pragma unroll
      for (int j = 0; j < 8; ++j) part[j] += vv * wv8[j];
    }
  }
  #pragma unroll
  for (int j = 0; j < 8; ++j) part[j] = wave_sum(part[j]);
  if (lane < 8) wg[(size_t)l * 8192 + sel * 4096 + (size_t)k * 8 + lane] = part[lane];
}

__device__ __forceinline__ void embed_body(
    int row, const float* x, const float* tf, const float* Wp, const float* bp,
    const float* g, const float* b, float* h, __bf16* hn) {
  int n = threadIdx.x;
  float xv = x[row];
  const float* t4 = tf + (size_t)row * 4;
  float acc = bp[n] + xv * Wp[n];
  acc += t4[0] * Wp[256 + n];
  acc += t4[1] * Wp[512 + n];
  acc += t4[2] * Wp[768 + n];
  acc += t4[3] * Wp[1024 + n];
  h[(size_t)row * 256 + n] = acc;
  __shared__ float red[4];
  int wid = n >> 6, lane = n & 63;
  float s = wave_sum(acc);
  if (lane == 0) red[wid] = s;
  __syncthreads();
  float mu = (red[0] + red[1] + red[2] + red[3]) * (1.f / 256.f);
  __syncthreads();
  float d = acc - mu;
  float s2 = wave_sum(d * d);
  if (lane == 0) red[wid] = s2;
  __syncthreads();
  float var = (red[0] + red[1] + red[2] + red[3]) * (1.f / 256.f);
  float rs = rsqrtf(var + 1e-5f);
  hn[(size_t)row * 256 + n] = (__bf16)(d * rs * g[n] + b[n]);
}

__global__ __launch_bounds__(256) void prep_kernel(
    const float* __restrict__ x, const float* __restrict__ tf,
    const float* __restrict__ Wp, const float* __restrict__ bp,
    const float* __restrict__ ln_g, const float* __restrict__ ln_b,
    const float* __restrict__ Wup, const float* __restrict__ Wq,
    const float* __restrict__ Wk, const float* __restrict__ Wv,
    const float* __restrict__ Wdown, const float* __restrict__ Wif,
    __bf16* __restrict__ WupT, __bf16* __restrict__ WqkT,
    __bf16* __restrict__ WvT, __bf16* __restrict__ WdownT,
    float* __restrict__ wg, float* __restrict__ h, __bf16* __restrict__ hn) {
  int bid = blockIdx.x;
  if (bid < 4608) {
    wtrans_body(bid, Wup, Wq, Wk, Wv, Wdown, WupT, WqkT, WvT, WdownT);
  } else if (bid < 4608 + 1024) {
    wgprep_body(bid - 4608, Wq, Wk, Wv, Wif, wg);
  } else {
    embed_body(bid - 5632, x, tf, Wp, bp, ln_g, ln_b, h, hn);
  }
}

// ---------------- bf16 MFMA GEMM body: TM x 128 tile, dbuf LDS + reg prefetch ----------------
// MODE 0: f32 out (+ACC adds prev). MODE 1: bf16 row-major (LDS coalesced).
// MODE 2: bf16 -> vT[bh][128][1024] via transposed-LDS coalesced stores (TM=64).
// MODE 3: bf16 -> head-compact qkh (q at 0, k at KQOFF), layout [bh][1024][128].
template <int TM, int MODE, int ACC>
__device__ __forceinline__ void hgemm_body(
    char* smem_raw,
    const __bf16* __restrict__ A, int lda,
    const __bf16* __restrict__ BT, int Kdim,
    const float* __restrict__ bias,
    void* __restrict__ Cout, int ldc, int bxi, int byi) {
  auto As = (__bf16(*)[40])smem_raw;
  auto Bs = (__bf16(*)[40])(smem_raw + (size_t)TM * 160);
  int tid = threadIdx.x;
  int bm = bxi * TM, bn = byi * 128;
  int wid = tid >> 6, lane = tid & 63;
  int wr = wid >> 1, wc = wid & 1;
  int lg = lane >> 4, li = lane & 15;
  constexpr int MI = TM / 32;
  constexpr int WROW = TM / 2;
  floatx4 acc[MI][4];
  #pragma unroll
  for (int i = 0; i < MI; ++i)
    #pragma unroll
    for (int j = 0; j < 4; ++j) acc[i][j] = (floatx4)(0.f);

  int arow = tid >> 2, aseg = tid & 3;
  bf16x8 pa0, pa1, pb0, pb1;
  auto pre = [&](int k0) {
    pa0 = *(const bf16x8*)(A + (size_t)(bm + arow) * lda + k0 + aseg * 8);
    if constexpr (TM == 128)
      pa1 = *(const bf16x8*)(A + (size_t)(bm + arow + 64) * lda + k0 + aseg * 8);
    pb0 = *(const bf16x8*)(BT + (size_t)(bn + arow) * Kdim + k0 + aseg * 8);
    pb1 = *(const bf16x8*)(BT + (size_t)(bn + arow + 64) * Kdim + k0 + aseg * 8);
  };
  auto stor = [&](int buf) {
    *(bf16x8*)&As[buf * TM + arow][aseg * 8] = pa0;
    if constexpr (TM == 128) *(bf16x8*)&As[buf * TM + arow + 64][aseg * 8] = pa1;
    *(bf16x8*)&Bs[buf * 128 + arow][aseg * 8] = pb0;
    *(bf16x8*)&Bs[buf * 128 + arow + 64][aseg * 8] = pb1;
  };
  pre(0);
  stor(0);
  if (32 < Kdim) pre(32);
  int cur = 0;
  for (int k0 = 0; k0 < Kdim; k0 += 32) {
    __syncthreads();
    bf16x8 af[MI], bfr[4];
    #pragma unroll
    for (int mi = 0; mi < MI; ++mi)
      af[mi] = *(const bf16x8*)&As[cur * TM + wr * WROW + mi * 16 + li][lg * 8];
    #pragma unroll
    for (int ni = 0; ni < 4; ++ni)
      bfr[ni] = *(const bf16x8*)&Bs[cur * 128 + wc * 64 + ni * 16 + li][lg * 8];
    #pragma unroll
    for (int mi = 0; mi < MI; ++mi)
      #pragma unroll
      for (int ni = 0; ni < 4; ++ni)
        acc[mi][ni] = __builtin_amdgcn_mfma_f32_16x16x32_bf16(af[mi], bfr[ni], acc[mi][ni], 0, 0, 0);
    if (k0 + 32 < Kdim) {
      stor(cur ^ 1);
      if (k0 + 64 < Kdim) pre(k0 + 64);
    }
    cur ^= 1;
  }
  if constexpr (MODE == 1 || MODE == 3) {
    __bf16* eb = (__bf16*)smem_raw;
    const int PITCH = 136;
    #pragma unroll
    for (int mi = 0; mi < MI; ++mi) {
      __syncthreads();
      #pragma unroll
      for (int ni = 0; ni < 4; ++ni) {
        int col = wc * 64 + ni * 16 + li;
        float bz = (MODE == 1 && bias) ? bias[bn + col] : 0.f;
        #pragma unroll
        for (int r = 0; r < 4; ++r) {
          int lr = wr * 16 + lg * 4 + r;
          eb[lr * PITCH + col] = (__bf16)(acc[mi][ni][r] + bz);
        }
      }
      __syncthreads();
      #pragma unroll
      for (int i = 0; i < 2; ++i) {
        int lr = (tid >> 4) + i * 16;
        int c8 = (tid & 15) * 8;
        bf16x8 v = *(const bf16x8*)&eb[lr * PITCH + c8];
        int row_g = bm + (lr >> 4) * 64 + mi * 16 + (lr & 15);
        if constexpr (MODE == 1) {
          __bf16* C = (__bf16*)Cout;
          *(bf16x8*)(C + (size_t)row_g * ldc + bn + c8) = v;
        } else {
          // head-compact: head8 = bn>>7 (0-3 q, 4-7 k)
          int head8 = bn >> 7;
          __bf16* C = (__bf16*)Cout + (head8 >= 4 ? KQOFF : 0);
          int bhp = (row_g >> 10) * 4 + (head8 & 3);
          *(bf16x8*)(C + ((size_t)bhp * 1024 + (row_g & 1023)) * 128 + c8) = v;
        }
      }
    }
  } else if constexpr (MODE == 2) {
    // transposed-LDS epilogue: tile (64 t) x (128 d) -> vT[bh][d][t], coalesced along t
    __bf16* eb = (__bf16*)smem_raw;
    const int VP = 72;
    __syncthreads();
    #pragma unroll
    for (int mi = 0; mi < MI; ++mi)
      #pragma unroll
      for (int ni = 0; ni < 4; ++ni) {
        int c = wc * 64 + ni * 16 + li;
        #pragma unroll
        for (int r = 0; r < 4; ++r) {
          int rl = wr * WROW + mi * 16 + lg * 4 + r;
          eb[c * VP + rl] = (__bf16)acc[mi][ni][r];
        }
      }
    __syncthreads();
    __bf16* vt = (__bf16*)Cout;
    int bhv = (bm >> 10) * 4 + (bn >> 7);
    int t0 = bm & 1023;
    #pragma unroll
    for (int it = 0; it < 4; ++it) {
      int slot = it * 256 + tid;
      int d = slot >> 3;
      int s8 = (slot & 7) * 8;
      bf16x8 v = *(const bf16x8*)&eb[d * VP + s8];
      *(bf16x8*)(vt + ((size_t)(bhv * 128 + d)) * 1024 + t0 + s8) = v;
    }
  } else {
    #pragma unroll
    for (int mi = 0; mi < MI; ++mi) {
      int row = bm + wr * WROW + mi * 16 + lg * 4;
      #pragma unroll
      for (int ni = 0; ni < 4; ++ni) {
        int col = bn + wc * 64 + ni * 16 + li;
        float bz = bias ? bias[col] : 0.f;
        float* C = (float*)Cout;
        #pragma unroll
        for (int r = 0; r < 4; ++r) {
          float v = acc[mi][ni][r] + bz;
          if (ACC) v += C[(size_t)(row + r) * ldc + col];
          C[(size_t)(row + r) * ldc + col] = v;
        }
      }
    }
  }
}

template <int TM, int MODE, int ACC>
__global__ __launch_bounds__(256) void hgemm(
    const __bf16* __restrict__ A, int lda,
    const __bf16* __restrict__ BT, int Kdim,
    const float* __restrict__ bias,
    void* __restrict__ Cout, int ldc) {
  extern __shared__ char smem[];
  hgemm_body<TM, MODE, ACC>(smem, A, lda, BT, Kdim, bias, Cout, ldc,
                            blockIdx.x, blockIdx.y);
}

// ---------------- per-(b,h) gate scan body: one wave ----------------
__device__ __forceinline__ void scan_body(
    int bh, int lane, const float* __restrict__ gates, float* __restrict__ gout,
    float* __restrict__ Mout, float* __restrict__ NFout) {
  int bb = bh >> 2, hh = bh & 3;
  float ip[16], pf[16];
  #pragma unroll
  for (int i = 0; i < 16; ++i) {
    int t = lane * 16 + i;
    const float* grow = gates + ((size_t)(bb * S + t)) * 8;
    ip[i] = grow[hh];
    float fp = grow[4 + hh];
    float lf = fminf(fp, 0.f) - log1pf(__expf(-fabsf(fp)));
    pf[i] = (i == 0) ? lf : pf[i - 1] + lf;
  }
  float T = pf[15];
  float inc = T;
  #pragma unroll
  for (int off = 1; off < 64; off <<= 1) {
    float v = __shfl_up(inc, off, 64);
    if (lane >= off) inc += v;
  }
  float excl = inc - T;
  float F[16], g[16], pm[16];
  #pragma unroll
  for (int i = 0; i < 16; ++i) {
    F[i] = excl + pf[i];
    g[i] = ip[i] - F[i];
    pm[i] = (i == 0) ? g[0] : fmaxf(pm[i - 1], g[i]);
  }
  float Mx = pm[15];
  float incm = Mx;
  #pragma unroll
  for (int off = 1; off < 64; off <<= 1) {
    float v = __shfl_up(incm, off, 64);
    if (lane >= off) incm = fmaxf(incm, v);
  }
  float em = __shfl_up(incm, 1, 64);
  if (lane == 0) em = -3.4e38f;
  #pragma unroll
  for (int i = 0; i < 16; ++i) {
    int t = lane * 16 + i;
    size_t o = (size_t)bh * S + t;
    float M = fmaxf(em, pm[i]);
    gout[o] = g[i];
    Mout[o] = M;
    NFout[o] = __expf(-F[i] - M);
  }
}

// Merged QK + V GEMM + gate scan: grid (64, 17).
__global__ __launch_bounds__(256) void qkv_kernel(
    const __bf16* __restrict__ xc, const __bf16* __restrict__ WqkT,
    __bf16* __restrict__ qkh, const __bf16* __restrict__ up,
    const __bf16* __restrict__ WvT, __bf16* __restrict__ vT,
    const float* __restrict__ gates, float* __restrict__ gbuf,
    float* __restrict__ Mbuf, float* __restrict__ NFbuf) {
  extern __shared__ char smem[];
  if (blockIdx.y < 8) {
    hgemm_body<128, 3, 0>(smem, xc, 512, WqkT, 512, nullptr, qkh, 0,
                          blockIdx.x, blockIdx.y);
  } else if (blockIdx.y < 16) {
    int j = blockIdx.y - 8;
    hgemm_body<64, 2, 0>(smem, up, 1024, WvT, 512, nullptr, vT, 0,
                         blockIdx.x * 2 + (j & 1), j >> 1);
  } else {
    if (blockIdx.x < 32 && threadIdx.x < 64)
      scan_body(blockIdx.x, threadIdx.x, gates, gbuf, Mbuf, NFbuf);
  }
}

// ---------------- down-proj GEMM (32x256, dbuf) + residual + LN / final head ----------------
__global__ __launch_bounds__(256) void dgemm_ln_kernel(
    const __bf16* __restrict__ A, const __bf16* __restrict__ BT,
    const float* __restrict__ bias, float* __restrict__ h,
    const float* __restrict__ lng, const float* __restrict__ lnb,
    __bf16* __restrict__ hn,
    const float* __restrict__ lnfg, const float* __restrict__ lnfb,
    const float* __restrict__ Wf, const float* __restrict__ bf,
    float* __restrict__ out) {
  __shared__ __bf16 As[2 * 32][40];
  __shared__ __bf16 Bs[2 * 256][40];
  __shared__ float redS[2][32], redQ[2][32];
  int tid = threadIdx.x;
  int bm = blockIdx.x * 32;
  int wid = tid >> 6, lane = tid & 63;
  int wr = wid >> 1, wc = wid & 1;
  int lg = lane >> 4, li = lane & 15;
  floatx4 acc[8];
  #pragma unroll
  for (int j = 0; j < 8; ++j) acc[j] = (floatx4)(0.f);

  int arow = tid >> 2, aseg = tid & 3;
  bf16x8 pa, pb[4];
  auto pre = [&](int k0) {
    if (tid < 128)
      pa = *(const bf16x8*)(A + (size_t)(bm + arow) * 512 + k0 + aseg * 8);
    #pragma unroll
    for (int i = 0; i < 4; ++i)
      pb[i] = *(const bf16x8*)(BT + (size_t)(arow + i * 64) * 512 + k0 + aseg * 8);
  };
  auto stor = [&](int buf) {
    if (tid < 128) *(bf16x8*)&As[buf * 32 + arow][aseg * 8] = pa;
    #pragma unroll
    for (int i = 0; i < 4; ++i)
      *(bf16x8*)&Bs[buf * 256 + arow + i * 64][aseg * 8] = pb[i];
  };
  pre(0);
  stor(0);
  pre(32);
  int cur = 0;
  for (int k0 = 0; k0 < 512; k0 += 32) {
    __syncthreads();
    bf16x8 af = *(const bf16x8*)&As[cur * 32 + wr * 16 + li][lg * 8];
    #pragma unroll
    for (int ni = 0; ni < 8; ++ni) {
      bf16x8 bfr = *(const bf16x8*)&Bs[cur * 256 + wc * 128 + ni * 16 + li][lg * 8];
      acc[ni] = __builtin_amdgcn_mfma_f32_16x16x32_bf16(af, bfr, acc[ni], 0, 0, 0);
    }
    if (k0 + 32 < 512) {
      stor(cur ^ 1);
      if (k0 + 64 < 512) pre(k0 + 64);
    }
    cur ^= 1;
  }
  #pragma unroll
  for (int r = 0; r < 4; ++r) {
    int lr = wr * 16 + lg * 4 + r;
    int row = bm + lr;
    float s1 = 0.f, s2 = 0.f;
    #pragma unroll
    for (int ni = 0; ni < 8; ++ni) {
      int col = wc * 128 + ni * 16 + li;
      float v = acc[ni][r] + bias[col] + h[(size_t)row * 256 + col];
      acc[ni][r] = v;
      h[(size_t)row * 256 + col] = v;
      s1 += v;
      s2 += v * v;
    }
    s1 += __shfl_xor(s1, 1, 64); s1 += __shfl_xor(s1, 2, 64);
    s1 += __shfl_xor(s1, 4, 64); s1 += __shfl_xor(s1, 8, 64);
    s2 += __shfl_xor(s2, 1, 64); s2 += __shfl_xor(s2, 2, 64);
    s2 += __shfl_xor(s2, 4, 64); s2 += __shfl_xor(s2, 8, 64);
    if (li == 0) { redS[wc][lr] = s1; redQ[wc][lr] = s2; }
  }
  __syncthreads();
  if (lng) {
    #pragma unroll
    for (int r = 0; r < 4; ++r) {
      int lr = wr * 16 + lg * 4 + r;
      int row = bm + lr;
      float s1 = redS[0][lr] + redS[1][lr];
      float s2 = redQ[0][lr] + redQ[1][lr];
      float mu = s1 * (1.f / 256.f);
      float var = s2 * (1.f / 256.f) - mu * mu;
      float rs = rsqrtf(var + 1e-5f);
      #pragma unroll
      for (int ni = 0; ni < 8; ++ni) {
        int col = wc * 128 + ni * 16 + li;
        hn[(size_t)row * 256 + col] = (__bf16)((acc[ni][r] - mu) * rs * lng[col] + lnb[col]);
      }
    }
  } else if ((bm & 1023) == 992) {
    if (wr == 1 && lg == 3) {
      float s1 = redS[0][31] + redS[1][31];
      float s2 = redQ[0][31] + redQ[1][31];
      float mu = s1 * (1.f / 256.f);
      float var = s2 * (1.f / 256.f) - mu * mu;
      float rs = rsqrtf(var + 1e-5f);
      float p = 0.f;
      #pragma unroll
      for (int ni = 0; ni < 8; ++ni) {
        int col = wc * 128 + ni * 16 + li;
        float ln = (acc[ni][3] - mu) * rs * lnfg[col] + lnfb[col];
        p += ln * Wf[col];
      }
      p += __shfl_xor(p, 1, 64); p += __shfl_xor(p, 2, 64);
      p += __shfl_xor(p, 4, 64); p += __shfl_xor(p, 8, 64);
      if (li == 0) redS[wc][0] = p;
    }
    __syncthreads();
    if (tid == 0) out[bm >> 10] = redS[0][0] + redS[1][0] + bf[0];
  }
}

// ---------------- causal conv (K=4) + SiLU + fused gate projection ----------------
__global__ __launch_bounds__(256) void conv_silu_kernel(
    const __bf16* __restrict__ up, const float* __restrict__ cw,
    const float* __restrict__ cb, const float* __restrict__ wg,
    const float* __restrict__ bif, __bf16* __restrict__ xc,
    float* __restrict__ gates) {
  int tid = threadIdx.x;
  int wv = tid >> 6, lane = tid & 63;
  int row = blockIdx.x * 4 + wv;
  int c8 = lane * 8;
  int t = row & (S - 1);
  float acc[8];
  *(float4*)&acc[0] = *(const float4*)(cb + c8);
  *(float4*)&acc[4] = *(const float4*)(cb + c8 + 4);
  float xm[8];
  #pragma unroll
  for (int j = 0; j < 4; ++j) {
    int tt = t - 3 + j;
    if (tt >= 0) {
      bf16x8 xv = *(const bf16x8*)(up + (size_t)(row - 3 + j) * 1024 + c8);
      float4 w0 = *(const float4*)(cw + j * 512 + c8);
      float4 w1 = *(const float4*)(cw + j * 512 + c8 + 4);
      acc[0] += w0.x * (float)xv[0]; acc[1] += w0.y * (float)xv[1];
      acc[2] += w0.z * (float)xv[2]; acc[3] += w0.w * (float)xv[3];
      acc[4] += w1.x * (float)xv[4]; acc[5] += w1.y * (float)xv[5];
      acc[6] += w1.z * (float)xv[6]; acc[7] += w1.w * (float)xv[7];
      if (j == 3) {
        #pragma unroll
        for (int m = 0; m < 8; ++m) xm[m] = (float)xv[m];
      }
    }
  }
  bf16x8 o;
  float xcs[8];
  #pragma unroll
  for (int m = 0; m < 8; ++m) {
    float sg = 1.f / (1.f + __expf(-acc[m]));
    xcs[m] = acc[m] * sg;
    o[m] = (__bf16)xcs[m];
  }
  *(bf16x8*)(xc + (size_t)row * 512 + c8) = o;
  const float* w1 = wg + (size_t)c8 * 8;
  const float* w2 = wg + 4096 + (size_t)c8 * 8;
  float part[8] = {0, 0, 0, 0, 0, 0, 0, 0};
  #pragma unroll
  for (int m = 0; m < 8; ++m) {
    const float* a = w1 + m * 8;
    const float* b = w2 + m * 8;
    #pragma unroll
    for (int j = 0; j < 8; ++j) part[j] += xcs[m] * a[j] + xm[m] * b[j];
  }
  #pragma unroll
  for (int j = 0; j < 8; ++j) part[j] = wave_sum(part[j]);
  if (lane < 8) gates[(size_t)row * 8 + lane] = part[lane] + bif[lane];
}

// ---------------- MFMA mLSTM attention: 256-thr block, one q-tile, heavy-first ----------
// q/k from head-compact qkh (q at 0, k at KQOFF): contiguous 256B rows, 16KB/tile L2 span.
__global__ __launch_bounds__(256, 1) void attn_kernel(
    const __bf16* __restrict__ qkh, const __bf16* __restrict__ vT,
    const float* __restrict__ gbuf, const float* __restrict__ Mbuf,
    const float* __restrict__ NFbuf,
    const float* __restrict__ gn_g, const float* __restrict__ gn_b,
    const float* __restrict__ skip,
    const __bf16* __restrict__ xc, const __bf16* __restrict__ up,
    __bf16* __restrict__ hd) {
  __shared__ __bf16 Ks[64][136];
  __shared__ __bf16 Vs[128][72];
  __shared__ __bf16 plds[4][16][72];
  __shared__ float gls[64];
  __shared__ float glds[128], blds[128], slds[128];
  int bh = blockIdx.x;
  int tq = 15 - blockIdx.y;   // heavy-first
  int bb = bh >> 2, hh = bh & 3;
  int tid = threadIdx.x;
  int wv = tid >> 6, lane = tid & 63;
  int lg = lane >> 4, li = lane & 15;
  int tb = tq * 64 + wv * 16;
  const float scale = 0.08838834764831845f;

  if (tid < 128) {
    glds[tid] = gn_g[hh * 128 + tid];
    blds[tid] = gn_b[hh * 128 + tid];
    slds[tid] = skip[hh * 128 + tid];
  }

  bf16x8 aq[4];
  {
    const __bf16* qp = qkh + ((size_t)bh * 1024 + tb + li) * 128 + lg * 8;
    #pragma unroll
    for (int cd = 0; cd < 4; ++cd) aq[cd] = *(const bf16x8*)(qp + cd * 32);
  }
  float ml[4], nf[4];
  #pragma unroll
  for (int r = 0; r < 4; ++r) {
    ml[r] = Mbuf[(size_t)bh * S + tb + lg * 4 + r];
    nf[r] = NFbuf[(size_t)bh * S + tb + lg * 4 + r];
  }

  floatx4 oacc[8];
  #pragma unroll
  for (int df = 0; df < 8; ++df) oacc[df] = (floatx4)(0.f);
  float rs[4] = {0, 0, 0, 0};

  int krow = tid >> 3, kcol = tid & 7;
  bf16x8 kreg[4], vreg[4];
  float greg = 0.f;
  auto preload = [&](int st) {
    int s0 = st * 64;
    const __bf16* kp = qkh + KQOFF + ((size_t)bh * 1024 + s0 + krow) * 128;
    kreg[0] = *(const bf16x8*)(kp + kcol * 8);
    kreg[1] = *(const bf16x8*)(kp + (size_t)32 * 128 + kcol * 8);
    kreg[2] = *(const bf16x8*)(kp + 64 + kcol * 8);
    kreg[3] = *(const bf16x8*)(kp + (size_t)32 * 128 + 64 + kcol * 8);
    #pragma unroll
    for (int i = 0; i < 4; ++i)
      vreg[i] = *(const bf16x8*)(vT + ((size_t)(bh * 128 + krow + i * 32)) * 1024 + s0 + kcol * 8);
    if (tid < 64) greg = gbuf[(size_t)bh * S + s0 + tid];
  };
  preload(0);

  for (int st = 0; st <= tq; ++st) {
    __syncthreads();
    *(bf16x8*)&Ks[krow][kcol * 8] = kreg[0];
    *(bf16x8*)&Ks[krow + 32][kcol * 8] = kreg[1];
    *(bf16x8*)&Ks[krow][64 + kcol * 8] = kreg[2];
    *(bf16x8*)&Ks[krow + 32][64 + kcol * 8] = kreg[3];
    #pragma unroll
    for (int i = 0; i < 4; ++i) *(bf16x8*)&Vs[krow + i * 32][kcol * 8] = vreg[i];
    if (tid < 64) gls[tid] = greg;
    __syncthreads();
    if (st < tq) preload(st + 1);

    int s0 = st * 64;
    #pragma unroll
    for (int ns = 0; ns < 4; ++ns) {
      bf16x8 bk0 = *(const bf16x8*)&Ks[ns * 16 + li][lg * 8];
      bf16x8 bk1 = *(const bf16x8*)&Ks[ns * 16 + li][32 + lg * 8];
      bf16x8 bk2 = *(const bf16x8*)&Ks[ns * 16 + li][64 + lg * 8];
      bf16x8 bk3 = *(const bf16x8*)&Ks[ns * 16 + li][96 + lg * 8];
      int s = s0 + ns * 16 + li;
      float gv = gls[ns * 16 + li];
      floatx4 pa = (floatx4)(0.f);
      pa = __builtin_amdgcn_mfma_f32_16x16x32_bf16(aq[0], bk0, pa, 0, 0, 0);
      pa = __builtin_amdgcn_mfma_f32_16x16x32_bf16(aq[1], bk1, pa, 0, 0, 0);
      pa = __builtin_amdgcn_mfma_f32_16x16x32_bf16(aq[2], bk2, pa, 0, 0, 0);
      pa = __builtin_amdgcn_mfma_f32_16x16x32_bf16(aq[3], bk3, pa, 0, 0, 0);
      #pragma unroll
      for (int r = 0; r < 4; ++r) {
        int t = tb + lg * 4 + r;
        float val = pa[r] * scale * __expf(gv - ml[r]);
        float w = (s <= t) ? val : 0.f;
        rs[r] += w;
        plds[wv][lg * 4 + r][ns * 16 + li] = (__bf16)w;
      }
    }
    bf16x8 ap0 = *(const bf16x8*)&plds[wv][li][lg * 8];
    bf16x8 ap1 = *(const bf16x8*)&plds[wv][li][32 + lg * 8];
    #pragma unroll
    for (int df = 0; df < 8; ++df) {
      bf16x8 bv0 = *(const bf16x8*)&Vs[df * 16 + li][lg * 8];
      bf16x8 bv1 = *(const bf16x8*)&Vs[df * 16 + li][32 + lg * 8];
      oacc[df] = __builtin_amdgcn_mfma_f32_16x16x32_bf16(ap0, bv0, oacc[df], 0, 0, 0);
      oacc[df] = __builtin_amdgcn_mfma_f32_16x16x32_bf16(ap1, bv1, oacc[df], 0, 0, 0);
    }
  }
  #pragma unroll
  for (int r = 0; r < 4; ++r) {
    float a = rs[r];
    a += __shfl_xor(a, 1, 64); a += __shfl_xor(a, 2, 64);
    a += __shfl_xor(a, 4, 64); a += __shfl_xor(a, 8, 64);
    rs[r] = a;
  }
  #pragma unroll
  for (int r = 0; r < 4; ++r) {
    float inv = 1.f / (fmaxf(fabsf(rs[r]), nf[r]) + 1e-6f);
    float v8[8], s1 = 0.f, s2 = 0.f;
    #pragma unroll
    for (int df = 0; df < 8; ++df) {
      float v = oacc[df][r] * inv;
      v8[df] = v;
      s1 += v;
      s2 += v * v;
    }
    s1 += __shfl_xor(s1, 1, 64); s1 += __shfl_xor(s1, 2, 64);
    s1 += __shfl_xor(s1, 4, 64); s1 += __shfl_xor(s1, 8, 64);
    s2 += __shfl_xor(s2, 1, 64); s2 += __shfl_xor(s2, 2, 64);
    s2 += __shfl_xor(s2, 4, 64); s2 += __shfl_xor(s2, 8, 64);
    float mu = s1 * (1.f / 128.f);
    float var = s2 * (1.f / 128.f) - mu * mu;
    float rq = rsqrtf(var + 1e-5f);
    int t = tb + lg * 4 + r;
    const __bf16* xr = xc + ((size_t)(bb * S + t)) * 512 + hh * 128 + li;
    const __bf16* zr = up + ((size_t)(bb * S + t)) * 1024 + 512 + hh * 128 + li;
    __bf16* od = hd + ((size_t)(bb * S + t)) * 512 + hh * 128 + li;
    #pragma unroll
    for (int df = 0; df < 8; ++df) {
      int c = df * 16 + li;
      float ln = (v8[df] - mu) * rq * glds[c] + blds[c];
      float val = ln + slds[c] * (float)xr[df * 16];
      float z = (float)zr[df * 16];
      float sg = 1.f / (1.f + __expf(-z));
      od[df * 16] = (__bf16)(val * (z * sg));
    }
  }
}

extern "C" void kernel_launch(void* const* d_in, const int* in_sizes, int n_in,
                              void* d_out, int out_size, void* d_ws, size_t ws_size,
                              hipStream_t stream) {
  const float* x      = (const float*)d_in[0];
  const float* tf     = (const float*)d_in[1];
  const float* Wp     = (const float*)d_in[2];
  const float* bp     = (const float*)d_in[3];
  const float* ln_g   = (const float*)d_in[4];
  const float* ln_b   = (const float*)d_in[5];
  const float* Wup    = (const float*)d_in[6];
  const float* bup    = (const float*)d_in[7];
  const float* conv_w = (const float*)d_in[8];
  const float* conv_b = (const float*)d_in[9];
  const float* Wq     = (const float*)d_in[10];
  const float* Wk     = (const float*)d_in[11];
  const float* Wv     = (const float*)d_in[12];
  const float* Wif    = (const float*)d_in[13];
  const float* bif    = (const float*)d_in[14];
  const float* gn_g   = (const float*)d_in[15];
  const float* gn_b   = (const float*)d_in[16];
  const float* skip   = (const float*)d_in[17];
  const float* Wdown  = (const float*)d_in[18];
  const float* bdown  = (const float*)d_in[19];
  const float* lnf_g  = (const float*)d_in[20];
  const float* lnf_b  = (const float*)d_in[21];
  const float* Wf     = (const float*)d_in[22];
  const float* bf     = (const float*)d_in[23];
  float* out = (float*)d_out;

  float* h     = (float*)d_ws;              // 2,097,152 f32
  float* gates = h + 2097152;               // 65,536 f32
  float* gbuf  = gates + 65536;             // 32,768
  float* Mbuf  = gbuf + 32768;              // 32,768
  float* NFbuf = Mbuf + 32768;              // 32,768
  float* wgbuf = NFbuf + 32768;             // 32,768
  __bf16* hn   = (__bf16*)(wgbuf + 32768);  // 2,097,152 bf16
  __bf16* up   = hn + 2097152;              // 8,388,608
  __bf16* xc   = up + 8388608;              // 4,194,304
  __bf16* qkh  = xc + 4194304;              // 8,388,608 (q at 0, k at KQOFF)
  __bf16* vT   = qkh + 8388608;             // 4,194,304
  __bf16* hd   = vT + 4194304;              // 4,194,304
  __bf16* WupT   = hd + 4194304;            // 1,048,576
  __bf16* WqkT   = WupT + 1048576;          // 2,097,152
  __bf16* WvT    = WqkT + 2097152;          // 1,048,576
  __bf16* WdownT = WvT + 1048576;           // 524,288

  prep_kernel<<<13824, 256, 0, stream>>>(
      x, tf, Wp, bp, ln_g, ln_b, Wup, Wq, Wk, Wv, Wdown, Wif,
      WupT, WqkT, WvT, WdownT, wgbuf, h, hn);
  for (int l = 0; l < NLAYER; ++l) {
    hgemm<128, 1, 0><<<dim3(64, 8), 256, 40960, stream>>>(
        hn, 256, WupT + (size_t)l * 262144, 256, bup + l * 1024, up, 1024);
    conv_silu_kernel<<<2048, 256, 0, stream>>>(up, conv_w + l * 2048, conv_b + l * 512,
                                               wgbuf + l * 8192, bif + l * 8, xc, gates);
    qkv_kernel<<<dim3(64, 17), 256, 40960, stream>>>(
        xc, WqkT + (size_t)l * 524288, qkh, up, WvT + (size_t)l * 262144, vT,
        gates, gbuf, Mbuf, NFbuf);
    attn_kernel<<<dim3(32, 16), 256, 0, stream>>>(
        qkh, vT, gbuf, Mbuf, NFbuf, gn_g + l * 512, gn_b + l * 512, skip + l * 512,
        xc, up, hd);
    const float* lng = (l + 1 < NLAYER) ? (ln_g + (l + 1) * 256) : nullptr;
    const float* lnb = (l + 1 < NLAYER) ? (ln_b + (l + 1) * 256) : nullptr;
    dgemm_ln_kernel<<<256, 256, 0, stream>>>(
        hd, WdownT + (size_t)l * 131072, bdown + l * 256, h, lng, lnb, hn,
        lnf_g, lnf_b, Wf, bf, out);
  }
}